// Round 1
// baseline (2938.510 us; speedup 1.0000x reference)
//
#include <hip/hip_runtime.h>

#define N_NODES   50000
#define N_EDGES   800000
#define DIM       128
#define NUM_GRAPHS 512
#define BN_EPS    1e-5f

// ---------------- fill (avoid hipMemsetAsync, be graph-capture safe) ----------
__global__ __launch_bounds__(256)
void fill_zero_kernel(float* __restrict__ p, long long n)
{
    long long stride = (long long)gridDim.x * blockDim.x;
    for (long long i = blockIdx.x * 256LL + threadIdx.x; i < n; i += stride)
        p[i] = 0.f;
}

// ------------- scatter: pooled[dst] += w * h[src]  (atomics baseline) --------
__global__ __launch_bounds__(256)
void scatter_kernel(const float* __restrict__ h, const int* __restrict__ src,
                    const int* __restrict__ dst, const float* __restrict__ ew,
                    float* __restrict__ pooled)
{
    const long long total = (long long)N_EDGES * 32;   // one float4 per thread-unit
    long long stride = (long long)gridDim.x * blockDim.x;
    for (long long idx = blockIdx.x * 256LL + threadIdx.x; idx < total; idx += stride) {
        int e = (int)(idx >> 5);
        int q = (int)(idx & 31);
        int s = src[e], d = dst[e];
        float w = ew[e];
        float4 v = *((const float4*)(h + (long long)s * DIM) + q);
        float* p = pooled + (long long)d * DIM + q * 4;
        atomicAdd(p + 0, w * v.x);
        atomicAdd(p + 1, w * v.y);
        atomicAdd(p + 2, w * v.z);
        atomicAdd(p + 3, w * v.w);
    }
}

// -------- GEMM: C[n,128] = act(A[n,128] @ W[128,128] + b), opt. BN stats -----
template<bool RELU, bool STATS>
__global__ __launch_bounds__(256)
void gemm128(const float* __restrict__ A, const float* __restrict__ W,
             const float* __restrict__ bias, float* __restrict__ C,
             float* __restrict__ stats, int nrows)
{
    __shared__ float As[64][36];     // 64 rows x 32 k (pad 36 for banks)
    __shared__ float Ws[32][132];    // 32 k x 128 cols (pad 132)

    const int tid = threadIdx.x;
    const int tm  = tid >> 4;        // 0..15
    const int tn  = tid & 15;        // 0..15
    const int row0 = blockIdx.x * 64;
    const int col  = tn * 8;

    float acc[4][8];
    {
        float4 b0 = *(const float4*)(bias + col);
        float4 b1 = *(const float4*)(bias + col + 4);
        #pragma unroll
        for (int i = 0; i < 4; ++i) {
            acc[i][0] = b0.x; acc[i][1] = b0.y; acc[i][2] = b0.z; acc[i][3] = b0.w;
            acc[i][4] = b1.x; acc[i][5] = b1.y; acc[i][6] = b1.z; acc[i][7] = b1.w;
        }
    }

    for (int kc = 0; kc < 4; ++kc) {
        // stage A chunk: 64 x 32
        {
            int r  = tid >> 3;       // 0..31
            int c4 = tid & 7;        // 0..7
            #pragma unroll
            for (int rr = 0; rr < 2; ++rr) {
                int r2 = r + rr * 32;
                int grow = row0 + r2;
                float4 v = make_float4(0.f, 0.f, 0.f, 0.f);
                if (grow < nrows)
                    v = *(const float4*)(A + (long long)grow * DIM + kc * 32 + c4 * 4);
                *(float4*)&As[r2][c4 * 4] = v;
            }
        }
        // stage W chunk: 32 x 128
        {
            int wk  = tid >> 5;      // 0..7
            int wc4 = tid & 31;      // 0..31
            #pragma unroll
            for (int kk = 0; kk < 4; ++kk) {
                int k2 = wk + kk * 8;
                float4 v = *(const float4*)(W + (long long)(kc * 32 + k2) * DIM + wc4 * 4);
                *(float4*)&Ws[k2][wc4 * 4] = v;
            }
        }
        __syncthreads();
        #pragma unroll
        for (int k = 0; k < 32; ++k) {
            float4 w0 = *(const float4*)&Ws[k][col];
            float4 w1 = *(const float4*)&Ws[k][col + 4];
            #pragma unroll
            for (int i = 0; i < 4; ++i) {
                float a = As[tm * 4 + i][k];
                acc[i][0] += a * w0.x; acc[i][1] += a * w0.y;
                acc[i][2] += a * w0.z; acc[i][3] += a * w0.w;
                acc[i][4] += a * w1.x; acc[i][5] += a * w1.y;
                acc[i][6] += a * w1.z; acc[i][7] += a * w1.w;
            }
        }
        __syncthreads();
    }

    float s[8], sq[8];
    if (STATS) {
        #pragma unroll
        for (int j = 0; j < 8; ++j) { s[j] = 0.f; sq[j] = 0.f; }
    }
    #pragma unroll
    for (int i = 0; i < 4; ++i) {
        int r = row0 + tm * 4 + i;
        if (r < nrows) {
            #pragma unroll
            for (int j = 0; j < 8; ++j) {
                float v = acc[i][j];
                if (RELU) v = fmaxf(v, 0.f);
                acc[i][j] = v;
                if (STATS) { s[j] += v; sq[j] += v * v; }
            }
            *(float4*)(C + (long long)r * DIM + col) =
                make_float4(acc[i][0], acc[i][1], acc[i][2], acc[i][3]);
            *(float4*)(C + (long long)r * DIM + col + 4) =
                make_float4(acc[i][4], acc[i][5], acc[i][6], acc[i][7]);
        }
    }

    if (STATS) {
        __shared__ float ssum[128];
        __shared__ float ssq[128];
        if (tid < 128) { ssum[tid] = 0.f; ssq[tid] = 0.f; }
        __syncthreads();
        #pragma unroll
        for (int j = 0; j < 8; ++j) {
            atomicAdd(&ssum[col + j], s[j]);
            atomicAdd(&ssq[col + j], sq[j]);
        }
        __syncthreads();
        if (tid < 128) {
            atomicAdd(&stats[tid], ssum[tid]);
            atomicAdd(&stats[128 + tid], ssq[tid]);
        }
    }
}

// --------- BN finalize: stats -> (scale, shift) in place ---------------------
__global__ void bn_finalize(float* stats, const float* __restrict__ gamma,
                            const float* __restrict__ beta)
{
    int c = threadIdx.x;
    float mu  = stats[c] * (1.f / N_NODES);
    float var = stats[128 + c] * (1.f / N_NODES) - mu * mu;
    float sc  = gamma[c] * rsqrtf(var + BN_EPS);
    stats[c]       = sc;
    stats[128 + c] = beta[c] - mu * sc;
}

// --------- BN apply + relu ----------------------------------------------------
__global__ __launch_bounds__(256)
void bn_apply_relu(const float* __restrict__ z, const float* __restrict__ stats,
                   float* __restrict__ out)
{
    __shared__ float sc[128];
    __shared__ float sh[128];
    if (threadIdx.x < 128) {
        sc[threadIdx.x] = stats[threadIdx.x];
        sh[threadIdx.x] = stats[128 + threadIdx.x];
    }
    __syncthreads();
    const long long total = (long long)N_NODES * 32;  // float4 units
    long long stride = (long long)gridDim.x * blockDim.x;
    for (long long idx = blockIdx.x * 256LL + threadIdx.x; idx < total; idx += stride) {
        int c4 = (int)(idx & 31);
        float4 v = ((const float4*)z)[idx];
        float4 a = *(const float4*)&sc[c4 * 4];
        float4 b = *(const float4*)&sh[c4 * 4];
        float4 o;
        o.x = fmaxf(v.x * a.x + b.x, 0.f);
        o.y = fmaxf(v.y * a.y + b.y, 0.f);
        o.z = fmaxf(v.z * a.z + b.z, 0.f);
        o.w = fmaxf(v.w * a.w + b.w, 0.f);
        ((float4*)out)[idx] = o;
    }
}

// --------- graph pooling: per-graph block, binary search on sorted ids --------
__global__ __launch_bounds__(128)
void graph_pool(const float* __restrict__ h, const int* __restrict__ gid,
                const float* __restrict__ pw, float* __restrict__ out)
{
    int g = blockIdx.x;
    int lo = 0, hi = N_NODES;
    while (lo < hi) { int m = (lo + hi) >> 1; if (gid[m] < g) lo = m + 1; else hi = m; }
    int start = lo;
    hi = N_NODES;
    while (lo < hi) { int m = (lo + hi) >> 1; if (gid[m] < g + 1) lo = m + 1; else hi = m; }
    int end = lo;
    int c = threadIdx.x;
    float acc = 0.f;
    for (int n = start; n < end; ++n)
        acc += pw[n] * h[(long long)n * DIM + c];
    out[g * DIM + c] = acc;
}

extern "C" void kernel_launch(void* const* d_in, const int* in_sizes, int n_in,
                              void* d_out, int out_size, void* d_ws, size_t ws_size,
                              hipStream_t stream)
{
    const float* x   = (const float*)d_in[0];
    const int*   esrc = (const int*)d_in[1];
    const int*   edst = (const int*)d_in[2];
    const float* ew  = (const float*)d_in[3];
    const int*   gid = (const int*)d_in[4];
    const float* pw  = (const float*)d_in[5];
    const float* W1  = (const float*)d_in[6];
    const float* b1  = (const float*)d_in[7];
    const float* W2  = (const float*)d_in[8];
    const float* b2  = (const float*)d_in[9];
    const float* gam = (const float*)d_in[10];
    const float* bet = (const float*)d_in[11];

    float* out_pool  = (float*)d_out;                      // [512,128]
    float* out_nodes = (float*)d_out + NUM_GRAPHS * DIM;   // [50000,128]

    const size_t NF = (size_t)N_NODES * DIM;
    float* bufP   = (float*)d_ws;     // pooled / z(l1)
    float* bufH   = bufP + NF;        // hid(l0) / h(l0)
    float* bufZ   = bufH + NF;        // z(l0) / hid(l1)
    float* stats0 = bufZ + NF;        // 256 floats
    float* stats1 = stats0 + 256;     // 256 floats

    const int gemmGrid    = (N_NODES + 63) / 64;  // 782
    const int scatterGrid = 4096;
    const int elemGrid    = 2048;
    const int fillGrid    = 2048;

    // ---- layer 0 ----
    fill_zero_kernel<<<fillGrid, 256, 0, stream>>>(bufP, (long long)NF);
    fill_zero_kernel<<<1, 256, 0, stream>>>(stats0, 512); // stats0+stats1
    scatter_kernel<<<scatterGrid, 256, 0, stream>>>(x, esrc, edst, ew, bufP);
    gemm128<true, false><<<gemmGrid, 256, 0, stream>>>(bufP, W1, b1, bufH, nullptr, N_NODES);
    gemm128<false, true><<<gemmGrid, 256, 0, stream>>>(bufH, W2, b2, bufZ, stats0, N_NODES);
    bn_finalize<<<1, 128, 0, stream>>>(stats0, gam, bet);
    bn_apply_relu<<<elemGrid, 256, 0, stream>>>(bufZ, stats0, bufH);   // h0 -> bufH

    // ---- layer 1 ----
    fill_zero_kernel<<<fillGrid, 256, 0, stream>>>(bufP, (long long)NF);
    scatter_kernel<<<scatterGrid, 256, 0, stream>>>(bufH, esrc, edst, ew, bufP);
    gemm128<true, false><<<gemmGrid, 256, 0, stream>>>(bufP, W1 + DIM * DIM, b1 + DIM, bufZ, nullptr, N_NODES);
    gemm128<false, true><<<gemmGrid, 256, 0, stream>>>(bufZ, W2 + DIM * DIM, b2 + DIM, bufP, stats1, N_NODES);
    bn_finalize<<<1, 128, 0, stream>>>(stats1, gam + DIM, bet + DIM);
    bn_apply_relu<<<elemGrid, 256, 0, stream>>>(bufP, stats1, out_nodes); // h1 -> out

    // ---- graph pooling ----
    graph_pool<<<NUM_GRAPHS, 128, 0, stream>>>(out_nodes, gid, pw, out_pool);
}

// Round 2
// 448.847 us; speedup vs baseline: 6.5468x; 6.5468x over previous
//
#include <hip/hip_runtime.h>

#define N_NODES    50000
#define N_EDGES    800000
#define DIM        128
#define NUM_GRAPHS 512
#define BN_EPS     1e-5f

#define N_PAD      50176              // 196 chunks * 256
#define N_CHUNKS   196

// ---------------- zero fill (graph-capture safe) ------------------------------
__global__ __launch_bounds__(256)
void fill_zero_kernel(float* __restrict__ p, long long n)
{
    long long stride = (long long)gridDim.x * blockDim.x;
    for (long long i = blockIdx.x * 256LL + threadIdx.x; i < n; i += stride)
        p[i] = 0.f;
}

// ---------------- CSR build ---------------------------------------------------
__global__ __launch_bounds__(256)
void hist_kernel(const int* __restrict__ dst, int* __restrict__ deg)
{
    int stride = gridDim.x * blockDim.x;
    for (int e = blockIdx.x * 256 + threadIdx.x; e < N_EDGES; e += stride)
        atomicAdd(&deg[dst[e]], 1);
}

// chunk sums: block b sums deg[b*256 .. b*256+255]
__global__ __launch_bounds__(256)
void scan_chunk_sums(const int* __restrict__ deg, int* __restrict__ chunkSum)
{
    __shared__ int s[256];
    int t = threadIdx.x;
    s[t] = deg[blockIdx.x * 256 + t];
    __syncthreads();
    for (int off = 128; off > 0; off >>= 1) {
        if (t < off) s[t] += s[t + off];
        __syncthreads();
    }
    if (t == 0) chunkSum[blockIdx.x] = s[0];
}

// single block: exclusive scan of chunk sums
__global__ __launch_bounds__(256)
void scan_chunk_base(const int* __restrict__ chunkSum, int* __restrict__ chunkBase)
{
    __shared__ int s[256];
    int t = threadIdx.x;
    int v = (t < N_CHUNKS) ? chunkSum[t] : 0;
    s[t] = v;
    __syncthreads();
    for (int off = 1; off < 256; off <<= 1) {
        int x = (t >= off) ? s[t - off] : 0;
        __syncthreads();
        s[t] += x;
        __syncthreads();
    }
    chunkBase[t] = s[t] - v;   // exclusive
}

// per-chunk exclusive scan + base -> rowptr
__global__ __launch_bounds__(256)
void scan_rowptr(const int* __restrict__ deg, const int* __restrict__ chunkBase,
                 int* __restrict__ rowptr, int* __restrict__ cursor)
{
    __shared__ int s[256];
    int t = threadIdx.x;
    int i = blockIdx.x * 256 + t;
    int v = deg[i];
    s[t] = v;
    __syncthreads();
    for (int off = 1; off < 256; off <<= 1) {
        int x = (t >= off) ? s[t - off] : 0;
        __syncthreads();
        s[t] += x;
        __syncthreads();
    }
    int excl = s[t] - v + chunkBase[blockIdx.x];
    rowptr[i] = excl;
    cursor[i] = excl;
}

__global__ __launch_bounds__(256)
void csr_fill(const int* __restrict__ src, const int* __restrict__ dst,
              const float* __restrict__ ew, int* __restrict__ cursor,
              int2* __restrict__ ed)
{
    int stride = gridDim.x * blockDim.x;
    for (int e = blockIdx.x * 256 + threadIdx.x; e < N_EDGES; e += stride) {
        int d = dst[e];
        int p = atomicAdd(&cursor[d], 1);
        ed[p] = make_int2(src[e], __float_as_int(ew[e]));
    }
}

// ------------- pull-gather SpMM: pooled[n] = sum_e w_e * h[src_e] ------------
__global__ __launch_bounds__(256)
void gather_spmm(const float* __restrict__ h, const int2* __restrict__ ed,
                 const int* __restrict__ rowptr, float* __restrict__ pooled)
{
    int node = blockIdx.x * 8 + (threadIdx.x >> 5);   // 8 nodes per block
    int lane = threadIdx.x & 31;                      // 32 threads per node
    int beg = rowptr[node];
    int end = rowptr[node + 1];
    float4 acc = make_float4(0.f, 0.f, 0.f, 0.f);
    for (int base = beg; base < end; base += 32) {
        int e = base + lane;
        int2 sw = (e < end) ? ed[e] : make_int2(0, 0);
        int cnt = min(32, end - base);
        #pragma unroll 4
        for (int i = 0; i < cnt; ++i) {
            int   s = __shfl(sw.x, i, 32);
            float w = __int_as_float(__shfl(sw.y, i, 32));
            float4 v = *((const float4*)(h + (long long)s * DIM) + lane);
            acc.x += w * v.x; acc.y += w * v.y;
            acc.z += w * v.z; acc.w += w * v.w;
        }
    }
    *((float4*)(pooled + (long long)node * DIM) + lane) = acc;
}

// -------- GEMM: C[n,128] = act(A[n,128] @ W[128,128] + b), opt. BN stats -----
template<bool RELU, bool STATS>
__global__ __launch_bounds__(256)
void gemm128(const float* __restrict__ A, const float* __restrict__ W,
             const float* __restrict__ bias, float* __restrict__ C,
             float* __restrict__ stats, int nrows)
{
    __shared__ float As[64][36];
    __shared__ float Ws[32][132];

    const int tid = threadIdx.x;
    const int tm  = tid >> 4;
    const int tn  = tid & 15;
    const int row0 = blockIdx.x * 64;
    const int col  = tn * 8;

    float acc[4][8];
    {
        float4 b0 = *(const float4*)(bias + col);
        float4 b1 = *(const float4*)(bias + col + 4);
        #pragma unroll
        for (int i = 0; i < 4; ++i) {
            acc[i][0] = b0.x; acc[i][1] = b0.y; acc[i][2] = b0.z; acc[i][3] = b0.w;
            acc[i][4] = b1.x; acc[i][5] = b1.y; acc[i][6] = b1.z; acc[i][7] = b1.w;
        }
    }

    for (int kc = 0; kc < 4; ++kc) {
        {
            int r  = tid >> 3;
            int c4 = tid & 7;
            #pragma unroll
            for (int rr = 0; rr < 2; ++rr) {
                int r2 = r + rr * 32;
                int grow = row0 + r2;
                float4 v = make_float4(0.f, 0.f, 0.f, 0.f);
                if (grow < nrows)
                    v = *(const float4*)(A + (long long)grow * DIM + kc * 32 + c4 * 4);
                *(float4*)&As[r2][c4 * 4] = v;
            }
        }
        {
            int wk  = tid >> 5;
            int wc4 = tid & 31;
            #pragma unroll
            for (int kk = 0; kk < 4; ++kk) {
                int k2 = wk + kk * 8;
                float4 v = *(const float4*)(W + (long long)(kc * 32 + k2) * DIM + wc4 * 4);
                *(float4*)&Ws[k2][wc4 * 4] = v;
            }
        }
        __syncthreads();
        #pragma unroll
        for (int k = 0; k < 32; ++k) {
            float4 w0 = *(const float4*)&Ws[k][col];
            float4 w1 = *(const float4*)&Ws[k][col + 4];
            #pragma unroll
            for (int i = 0; i < 4; ++i) {
                float a = As[tm * 4 + i][k];
                acc[i][0] += a * w0.x; acc[i][1] += a * w0.y;
                acc[i][2] += a * w0.z; acc[i][3] += a * w0.w;
                acc[i][4] += a * w1.x; acc[i][5] += a * w1.y;
                acc[i][6] += a * w1.z; acc[i][7] += a * w1.w;
            }
        }
        __syncthreads();
    }

    float s[8], sq[8];
    if (STATS) {
        #pragma unroll
        for (int j = 0; j < 8; ++j) { s[j] = 0.f; sq[j] = 0.f; }
    }
    #pragma unroll
    for (int i = 0; i < 4; ++i) {
        int r = row0 + tm * 4 + i;
        if (r < nrows) {
            #pragma unroll
            for (int j = 0; j < 8; ++j) {
                float v = acc[i][j];
                if (RELU) v = fmaxf(v, 0.f);
                acc[i][j] = v;
                if (STATS) { s[j] += v; sq[j] += v * v; }
            }
            *(float4*)(C + (long long)r * DIM + col) =
                make_float4(acc[i][0], acc[i][1], acc[i][2], acc[i][3]);
            *(float4*)(C + (long long)r * DIM + col + 4) =
                make_float4(acc[i][4], acc[i][5], acc[i][6], acc[i][7]);
        }
    }

    if (STATS) {
        __shared__ float ssum[128];
        __shared__ float ssq[128];
        if (tid < 128) { ssum[tid] = 0.f; ssq[tid] = 0.f; }
        __syncthreads();
        #pragma unroll
        for (int j = 0; j < 8; ++j) {
            atomicAdd(&ssum[col + j], s[j]);
            atomicAdd(&ssq[col + j], sq[j]);
        }
        __syncthreads();
        if (tid < 128) {
            atomicAdd(&stats[tid], ssum[tid]);
            atomicAdd(&stats[128 + tid], ssq[tid]);
        }
    }
}

// --------- BN finalize: stats -> (scale, shift) in place ---------------------
__global__ void bn_finalize(float* stats, const float* __restrict__ gamma,
                            const float* __restrict__ beta)
{
    int c = threadIdx.x;
    float mu  = stats[c] * (1.f / N_NODES);
    float var = stats[128 + c] * (1.f / N_NODES) - mu * mu;
    float sc  = gamma[c] * rsqrtf(var + BN_EPS);
    stats[c]       = sc;
    stats[128 + c] = beta[c] - mu * sc;
}

// --------- BN apply + relu ----------------------------------------------------
__global__ __launch_bounds__(256)
void bn_apply_relu(const float* __restrict__ z, const float* __restrict__ stats,
                   float* __restrict__ out)
{
    __shared__ float sc[128];
    __shared__ float sh[128];
    if (threadIdx.x < 128) {
        sc[threadIdx.x] = stats[threadIdx.x];
        sh[threadIdx.x] = stats[128 + threadIdx.x];
    }
    __syncthreads();
    const long long total = (long long)N_NODES * 32;
    long long stride = (long long)gridDim.x * blockDim.x;
    for (long long idx = blockIdx.x * 256LL + threadIdx.x; idx < total; idx += stride) {
        int c4 = (int)(idx & 31);
        float4 v = ((const float4*)z)[idx];
        float4 a = *(const float4*)&sc[c4 * 4];
        float4 b = *(const float4*)&sh[c4 * 4];
        float4 o;
        o.x = fmaxf(v.x * a.x + b.x, 0.f);
        o.y = fmaxf(v.y * a.y + b.y, 0.f);
        o.z = fmaxf(v.z * a.z + b.z, 0.f);
        o.w = fmaxf(v.w * a.w + b.w, 0.f);
        ((float4*)out)[idx] = o;
    }
}

// --------- graph pooling: per-graph block, binary search on sorted ids --------
__global__ __launch_bounds__(128)
void graph_pool(const float* __restrict__ h, const int* __restrict__ gid,
                const float* __restrict__ pw, float* __restrict__ out)
{
    int g = blockIdx.x;
    int lo = 0, hi = N_NODES;
    while (lo < hi) { int m = (lo + hi) >> 1; if (gid[m] < g) lo = m + 1; else hi = m; }
    int start = lo;
    hi = N_NODES;
    while (lo < hi) { int m = (lo + hi) >> 1; if (gid[m] < g + 1) lo = m + 1; else hi = m; }
    int end = lo;
    int c = threadIdx.x;
    float acc = 0.f;
    for (int n = start; n < end; ++n)
        acc += pw[n] * h[(long long)n * DIM + c];
    out[g * DIM + c] = acc;
}

extern "C" void kernel_launch(void* const* d_in, const int* in_sizes, int n_in,
                              void* d_out, int out_size, void* d_ws, size_t ws_size,
                              hipStream_t stream)
{
    const float* x    = (const float*)d_in[0];
    const int*   esrc = (const int*)d_in[1];
    const int*   edst = (const int*)d_in[2];
    const float* ew   = (const float*)d_in[3];
    const int*   gid  = (const int*)d_in[4];
    const float* pw   = (const float*)d_in[5];
    const float* W1   = (const float*)d_in[6];
    const float* b1   = (const float*)d_in[7];
    const float* W2   = (const float*)d_in[8];
    const float* b2   = (const float*)d_in[9];
    const float* gam  = (const float*)d_in[10];
    const float* bet  = (const float*)d_in[11];

    float* out_pool  = (float*)d_out;                      // [512,128]
    float* out_nodes = (float*)d_out + NUM_GRAPHS * DIM;   // [50000,128]

    // ---- workspace layout (bytes are all 8-aligned) ----
    const size_t NF = (size_t)N_NODES * DIM;
    char* w = (char*)d_ws;
    int2*  ed       = (int2*)w;                 w += (size_t)N_EDGES * sizeof(int2);
    float* bufP     = (float*)w;                w += NF * sizeof(float);
    float* bufH     = (float*)w;                w += NF * sizeof(float);
    float* bufZ     = (float*)w;                w += NF * sizeof(float);
    float* stats0   = (float*)w;                w += 256 * sizeof(float);
    float* stats1   = (float*)w;                w += 256 * sizeof(float);
    int*   deg      = (int*)w;                  w += (N_PAD + 64) * sizeof(int);
    int*   rowptr   = (int*)w;                  w += (N_PAD + 64) * sizeof(int);
    int*   cursor   = (int*)w;                  w += (N_PAD + 64) * sizeof(int);
    int*   chunkSum = (int*)w;                  w += 256 * sizeof(int);
    int*   chunkBase= (int*)w;                  w += 256 * sizeof(int);

    const int gemmGrid   = (N_NODES + 63) / 64;   // 782
    const int edgeGrid   = 2048;
    const int elemGrid   = 2048;
    const int gatherGrid = N_NODES / 8;           // 6250

    // ---- CSR build (once, reused by both layers) ----
    fill_zero_kernel<<<64, 256, 0, stream>>>((float*)deg, N_PAD);
    fill_zero_kernel<<<1, 256, 0, stream>>>(stats0, 512);    // stats0 + stats1
    hist_kernel<<<edgeGrid, 256, 0, stream>>>(edst, deg);
    scan_chunk_sums<<<N_CHUNKS, 256, 0, stream>>>(deg, chunkSum);
    scan_chunk_base<<<1, 256, 0, stream>>>(chunkSum, chunkBase);
    scan_rowptr<<<N_CHUNKS, 256, 0, stream>>>(deg, chunkBase, rowptr, cursor);
    csr_fill<<<edgeGrid, 256, 0, stream>>>(esrc, edst, ew, cursor, ed);

    // ---- layer 0 ----
    gather_spmm<<<gatherGrid, 256, 0, stream>>>(x, ed, rowptr, bufP);
    gemm128<true,  false><<<gemmGrid, 256, 0, stream>>>(bufP, W1, b1, bufH, nullptr, N_NODES);
    gemm128<false, true ><<<gemmGrid, 256, 0, stream>>>(bufH, W2, b2, bufZ, stats0, N_NODES);
    bn_finalize<<<1, 128, 0, stream>>>(stats0, gam, bet);
    bn_apply_relu<<<elemGrid, 256, 0, stream>>>(bufZ, stats0, bufH);   // h0 -> bufH

    // ---- layer 1 ----
    gather_spmm<<<gatherGrid, 256, 0, stream>>>(bufH, ed, rowptr, bufP);
    gemm128<true,  false><<<gemmGrid, 256, 0, stream>>>(bufP, W1 + DIM * DIM, b1 + DIM, bufZ, nullptr, N_NODES);
    gemm128<false, true ><<<gemmGrid, 256, 0, stream>>>(bufZ, W2 + DIM * DIM, b2 + DIM, bufP, stats1, N_NODES);
    bn_finalize<<<1, 128, 0, stream>>>(stats1, gam + DIM, bet + DIM);
    bn_apply_relu<<<elemGrid, 256, 0, stream>>>(bufP, stats1, out_nodes); // h1 -> out

    // ---- graph pooling ----
    graph_pool<<<NUM_GRAPHS, 128, 0, stream>>>(out_nodes, gid, pw, out_pool);
}

// Round 3
// 403.079 us; speedup vs baseline: 7.2902x; 1.1135x over previous
//
#include <hip/hip_runtime.h>

#define N_NODES    50000
#define N_EDGES    800000
#define DIM        128
#define NUM_GRAPHS 512
#define BN_EPS     1e-5f

#define N_PAD      50176              // 196 chunks * 256
#define N_CHUNKS   196

typedef unsigned int u32;
typedef unsigned short u16;

__device__ __forceinline__ u16 f2bf(float f) {
    u32 u = __float_as_uint(f);
    u += 0x7FFF + ((u >> 16) & 1);    // round-to-nearest-even
    return (u16)(u >> 16);
}
__device__ __forceinline__ float bf2f(u16 h) {
    return __uint_as_float((u32)h << 16);
}

// ---------------- zero fill (graph-capture safe) ------------------------------
__global__ __launch_bounds__(256)
void fill_zero_kernel(float* __restrict__ p, long long n)
{
    long long stride = (long long)gridDim.x * blockDim.x;
    for (long long i = blockIdx.x * 256LL + threadIdx.x; i < n; i += stride)
        p[i] = 0.f;
}

// ---------------- f32 -> bf16 convert ----------------------------------------
__global__ __launch_bounds__(256)
void cvt_bf16_kernel(const float* __restrict__ in, u16* __restrict__ out, long long n4)
{
    long long stride = (long long)gridDim.x * blockDim.x;
    for (long long i = blockIdx.x * 256LL + threadIdx.x; i < n4; i += stride) {
        float4 v = ((const float4*)in)[i];
        ushort4 o;
        o.x = f2bf(v.x); o.y = f2bf(v.y); o.z = f2bf(v.z); o.w = f2bf(v.w);
        ((ushort4*)out)[i] = o;
    }
}

// ---------------- CSR build ---------------------------------------------------
__global__ __launch_bounds__(256)
void hist_kernel(const int* __restrict__ dst, int* __restrict__ deg)
{
    int stride = gridDim.x * blockDim.x;
    for (int e = blockIdx.x * 256 + threadIdx.x; e < N_EDGES; e += stride)
        atomicAdd(&deg[dst[e]], 1);
}

__global__ __launch_bounds__(256)
void scan_chunk_sums(const int* __restrict__ deg, int* __restrict__ chunkSum)
{
    __shared__ int s[256];
    int t = threadIdx.x;
    s[t] = deg[blockIdx.x * 256 + t];
    __syncthreads();
    for (int off = 128; off > 0; off >>= 1) {
        if (t < off) s[t] += s[t + off];
        __syncthreads();
    }
    if (t == 0) chunkSum[blockIdx.x] = s[0];
}

__global__ __launch_bounds__(256)
void scan_chunk_base(const int* __restrict__ chunkSum, int* __restrict__ chunkBase)
{
    __shared__ int s[256];
    int t = threadIdx.x;
    int v = (t < N_CHUNKS) ? chunkSum[t] : 0;
    s[t] = v;
    __syncthreads();
    for (int off = 1; off < 256; off <<= 1) {
        int x = (t >= off) ? s[t - off] : 0;
        __syncthreads();
        s[t] += x;
        __syncthreads();
    }
    chunkBase[t] = s[t] - v;   // exclusive
}

__global__ __launch_bounds__(256)
void scan_rowptr(const int* __restrict__ deg, const int* __restrict__ chunkBase,
                 int* __restrict__ rowptr, int* __restrict__ cursor)
{
    __shared__ int s[256];
    int t = threadIdx.x;
    int i = blockIdx.x * 256 + t;
    int v = deg[i];
    s[t] = v;
    __syncthreads();
    for (int off = 1; off < 256; off <<= 1) {
        int x = (t >= off) ? s[t - off] : 0;
        __syncthreads();
        s[t] += x;
        __syncthreads();
    }
    int excl = s[t] - v + chunkBase[blockIdx.x];
    rowptr[i] = excl;
    cursor[i] = excl;
}

// edge record: (bf16 weight << 16) | src   (src < 65536)
__global__ __launch_bounds__(256)
void csr_fill(const int* __restrict__ src, const int* __restrict__ dst,
              const float* __restrict__ ew, int* __restrict__ cursor,
              u32* __restrict__ ed)
{
    int stride = gridDim.x * blockDim.x;
    for (int e = blockIdx.x * 256 + threadIdx.x; e < N_EDGES; e += stride) {
        int d = dst[e];
        int p = atomicAdd(&cursor[d], 1);
        ed[p] = ((u32)f2bf(ew[e]) << 16) | (u32)src[e];
    }
}

// ------------- pull-gather SpMM from bf16 table ------------------------------
__global__ __launch_bounds__(256)
void gather_spmm(const u16* __restrict__ h, const u32* __restrict__ ed,
                 const int* __restrict__ rowptr, float* __restrict__ pooled)
{
    int node = blockIdx.x * 8 + (threadIdx.x >> 5);   // 8 nodes per block
    int lane = threadIdx.x & 31;                      // 32 threads per node
    int beg = rowptr[node];
    int end = rowptr[node + 1];
    float4 acc = make_float4(0.f, 0.f, 0.f, 0.f);
    for (int base = beg; base < end; base += 32) {
        int e = base + lane;
        u32 sw = (e < end) ? ed[e] : 0u;
        int cnt = min(32, end - base);
        #pragma unroll 4
        for (int i = 0; i < cnt; ++i) {
            u32 rec = __shfl(sw, i, 32);
            int   s = (int)(rec & 0xFFFFu);
            float w = bf2f((u16)(rec >> 16));
            ushort4 hv = *((const ushort4*)(h + (long long)s * DIM) + lane);
            acc.x += w * bf2f(hv.x);
            acc.y += w * bf2f(hv.y);
            acc.z += w * bf2f(hv.z);
            acc.w += w * bf2f(hv.w);
        }
    }
    *((float4*)(pooled + (long long)node * DIM) + lane) = acc;
}

// -------- GEMM: C[n,128] = act(A[n,128] @ W[128,128] + b), opt. BN stats -----
template<bool RELU, bool STATS>
__global__ __launch_bounds__(256)
void gemm128(const float* __restrict__ A, const float* __restrict__ W,
             const float* __restrict__ bias, float* __restrict__ C,
             float* __restrict__ stats, int nrows)
{
    __shared__ float As[64][36];
    __shared__ float Ws[32][132];

    const int tid = threadIdx.x;
    const int tm  = tid >> 4;
    const int tn  = tid & 15;
    const int row0 = blockIdx.x * 64;
    const int col  = tn * 8;

    float acc[4][8];
    {
        float4 b0 = *(const float4*)(bias + col);
        float4 b1 = *(const float4*)(bias + col + 4);
        #pragma unroll
        for (int i = 0; i < 4; ++i) {
            acc[i][0] = b0.x; acc[i][1] = b0.y; acc[i][2] = b0.z; acc[i][3] = b0.w;
            acc[i][4] = b1.x; acc[i][5] = b1.y; acc[i][6] = b1.z; acc[i][7] = b1.w;
        }
    }

    for (int kc = 0; kc < 4; ++kc) {
        {
            int r  = tid >> 3;
            int c4 = tid & 7;
            #pragma unroll
            for (int rr = 0; rr < 2; ++rr) {
                int r2 = r + rr * 32;
                int grow = row0 + r2;
                float4 v = make_float4(0.f, 0.f, 0.f, 0.f);
                if (grow < nrows)
                    v = *(const float4*)(A + (long long)grow * DIM + kc * 32 + c4 * 4);
                *(float4*)&As[r2][c4 * 4] = v;
            }
        }
        {
            int wk  = tid >> 5;
            int wc4 = tid & 31;
            #pragma unroll
            for (int kk = 0; kk < 4; ++kk) {
                int k2 = wk + kk * 8;
                float4 v = *(const float4*)(W + (long long)(kc * 32 + k2) * DIM + wc4 * 4);
                *(float4*)&Ws[k2][wc4 * 4] = v;
            }
        }
        __syncthreads();
        #pragma unroll
        for (int k = 0; k < 32; ++k) {
            float4 w0 = *(const float4*)&Ws[k][col];
            float4 w1 = *(const float4*)&Ws[k][col + 4];
            #pragma unroll
            for (int i = 0; i < 4; ++i) {
                float a = As[tm * 4 + i][k];
                acc[i][0] += a * w0.x; acc[i][1] += a * w0.y;
                acc[i][2] += a * w0.z; acc[i][3] += a * w0.w;
                acc[i][4] += a * w1.x; acc[i][5] += a * w1.y;
                acc[i][6] += a * w1.z; acc[i][7] += a * w1.w;
            }
        }
        __syncthreads();
    }

    float s[8], sq[8];
    if (STATS) {
        #pragma unroll
        for (int j = 0; j < 8; ++j) { s[j] = 0.f; sq[j] = 0.f; }
    }
    #pragma unroll
    for (int i = 0; i < 4; ++i) {
        int r = row0 + tm * 4 + i;
        if (r < nrows) {
            #pragma unroll
            for (int j = 0; j < 8; ++j) {
                float v = acc[i][j];
                if (RELU) v = fmaxf(v, 0.f);
                acc[i][j] = v;
                if (STATS) { s[j] += v; sq[j] += v * v; }
            }
            *(float4*)(C + (long long)r * DIM + col) =
                make_float4(acc[i][0], acc[i][1], acc[i][2], acc[i][3]);
            *(float4*)(C + (long long)r * DIM + col + 4) =
                make_float4(acc[i][4], acc[i][5], acc[i][6], acc[i][7]);
        }
    }

    if (STATS) {
        __shared__ float ssum[128];
        __shared__ float ssq[128];
        if (tid < 128) { ssum[tid] = 0.f; ssq[tid] = 0.f; }
        __syncthreads();
        #pragma unroll
        for (int j = 0; j < 8; ++j) {
            atomicAdd(&ssum[col + j], s[j]);
            atomicAdd(&ssq[col + j], sq[j]);
        }
        __syncthreads();
        if (tid < 128) {
            atomicAdd(&stats[tid], ssum[tid]);
            atomicAdd(&stats[128 + tid], ssq[tid]);
        }
    }
}

// --------- BN finalize: stats -> (scale, shift) in place ---------------------
__global__ void bn_finalize(float* stats, const float* __restrict__ gamma,
                            const float* __restrict__ beta)
{
    int c = threadIdx.x;
    float mu  = stats[c] * (1.f / N_NODES);
    float var = stats[128 + c] * (1.f / N_NODES) - mu * mu;
    float sc  = gamma[c] * rsqrtf(var + BN_EPS);
    stats[c]       = sc;
    stats[128 + c] = beta[c] - mu * sc;
}

// --------- BN apply + relu, f32 or bf16 output -------------------------------
template<bool BF16OUT>
__global__ __launch_bounds__(256)
void bn_apply_relu(const float* __restrict__ z, const float* __restrict__ stats,
                   void* __restrict__ out)
{
    __shared__ float sc[128];
    __shared__ float sh[128];
    if (threadIdx.x < 128) {
        sc[threadIdx.x] = stats[threadIdx.x];
        sh[threadIdx.x] = stats[128 + threadIdx.x];
    }
    __syncthreads();
    const long long total = (long long)N_NODES * 32;
    long long stride = (long long)gridDim.x * blockDim.x;
    for (long long idx = blockIdx.x * 256LL + threadIdx.x; idx < total; idx += stride) {
        int c4 = (int)(idx & 31);
        float4 v = ((const float4*)z)[idx];
        float4 a = *(const float4*)&sc[c4 * 4];
        float4 b = *(const float4*)&sh[c4 * 4];
        float4 o;
        o.x = fmaxf(v.x * a.x + b.x, 0.f);
        o.y = fmaxf(v.y * a.y + b.y, 0.f);
        o.z = fmaxf(v.z * a.z + b.z, 0.f);
        o.w = fmaxf(v.w * a.w + b.w, 0.f);
        if (BF16OUT) {
            ushort4 ob;
            ob.x = f2bf(o.x); ob.y = f2bf(o.y); ob.z = f2bf(o.z); ob.w = f2bf(o.w);
            ((ushort4*)out)[idx] = ob;
        } else {
            ((float4*)out)[idx] = o;
        }
    }
}

// --------- graph pooling: per-graph block, binary search on sorted ids --------
__global__ __launch_bounds__(128)
void graph_pool(const float* __restrict__ h, const int* __restrict__ gid,
                const float* __restrict__ pw, float* __restrict__ out)
{
    int g = blockIdx.x;
    int lo = 0, hi = N_NODES;
    while (lo < hi) { int m = (lo + hi) >> 1; if (gid[m] < g) lo = m + 1; else hi = m; }
    int start = lo;
    hi = N_NODES;
    while (lo < hi) { int m = (lo + hi) >> 1; if (gid[m] < g + 1) lo = m + 1; else hi = m; }
    int end = lo;
    int c = threadIdx.x;
    float acc = 0.f;
    for (int n = start; n < end; ++n)
        acc += pw[n] * h[(long long)n * DIM + c];
    out[g * DIM + c] = acc;
}

extern "C" void kernel_launch(void* const* d_in, const int* in_sizes, int n_in,
                              void* d_out, int out_size, void* d_ws, size_t ws_size,
                              hipStream_t stream)
{
    const float* x    = (const float*)d_in[0];
    const int*   esrc = (const int*)d_in[1];
    const int*   edst = (const int*)d_in[2];
    const float* ew   = (const float*)d_in[3];
    const int*   gid  = (const int*)d_in[4];
    const float* pw   = (const float*)d_in[5];
    const float* W1   = (const float*)d_in[6];
    const float* b1   = (const float*)d_in[7];
    const float* W2   = (const float*)d_in[8];
    const float* b2   = (const float*)d_in[9];
    const float* gam  = (const float*)d_in[10];
    const float* bet  = (const float*)d_in[11];

    float* out_pool  = (float*)d_out;                      // [512,128]
    float* out_nodes = (float*)d_out + NUM_GRAPHS * DIM;   // [50000,128]

    // ---- workspace layout ----
    const size_t NF = (size_t)N_NODES * DIM;
    char* w = (char*)d_ws;
    u32*   ed       = (u32*)w;        w += (size_t)N_EDGES * sizeof(u32);
    float* bufP     = (float*)w;      w += NF * sizeof(float);
    float* bufH     = (float*)w;      w += NF * sizeof(float);
    float* bufZ     = (float*)w;      w += NF * sizeof(float);
    u16*   hx       = (u16*)w;        w += NF * sizeof(u16);
    // contiguous zero region: stats0 | stats1 | deg
    float* stats0   = (float*)w;      w += 256 * sizeof(float);
    float* stats1   = (float*)w;      w += 256 * sizeof(float);
    int*   deg      = (int*)w;        w += N_PAD * sizeof(int);
    int*   rowptr   = (int*)w;        w += (N_PAD + 64) * sizeof(int);
    int*   cursor   = (int*)w;        w += (N_PAD + 64) * sizeof(int);
    int*   chunkSum = (int*)w;        w += 256 * sizeof(int);
    int*   chunkBase= (int*)w;        w += 256 * sizeof(int);

    const int gemmGrid   = (N_NODES + 63) / 64;   // 782
    const int edgeGrid   = 2048;
    const int elemGrid   = 2048;
    const int gatherGrid = N_NODES / 8;           // 6250

    // ---- CSR build (once, reused by both layers) + zero stats ----
    fill_zero_kernel<<<64, 256, 0, stream>>>(stats0, 512 + N_PAD);
    hist_kernel<<<edgeGrid, 256, 0, stream>>>(edst, deg);
    cvt_bf16_kernel<<<1024, 256, 0, stream>>>(x, hx, (long long)(NF / 4));
    scan_chunk_sums<<<N_CHUNKS, 256, 0, stream>>>(deg, chunkSum);
    scan_chunk_base<<<1, 256, 0, stream>>>(chunkSum, chunkBase);
    scan_rowptr<<<N_CHUNKS, 256, 0, stream>>>(deg, chunkBase, rowptr, cursor);
    csr_fill<<<edgeGrid, 256, 0, stream>>>(esrc, edst, ew, cursor, ed);

    // ---- layer 0 ----
    gather_spmm<<<gatherGrid, 256, 0, stream>>>(hx, ed, rowptr, bufP);
    gemm128<true,  false><<<gemmGrid, 256, 0, stream>>>(bufP, W1, b1, bufH, nullptr, N_NODES);
    gemm128<false, true ><<<gemmGrid, 256, 0, stream>>>(bufH, W2, b2, bufZ, stats0, N_NODES);
    bn_finalize<<<1, 128, 0, stream>>>(stats0, gam, bet);
    bn_apply_relu<true><<<elemGrid, 256, 0, stream>>>(bufZ, stats0, hx);   // h0 -> hx (bf16)

    // ---- layer 1 ----
    gather_spmm<<<gatherGrid, 256, 0, stream>>>(hx, ed, rowptr, bufP);
    gemm128<true,  false><<<gemmGrid, 256, 0, stream>>>(bufP, W1 + DIM * DIM, b1 + DIM, bufZ, nullptr, N_NODES);
    gemm128<false, true ><<<gemmGrid, 256, 0, stream>>>(bufZ, W2 + DIM * DIM, b2 + DIM, bufP, stats1, N_NODES);
    bn_finalize<<<1, 128, 0, stream>>>(stats1, gam + DIM, bet + DIM);
    bn_apply_relu<false><<<elemGrid, 256, 0, stream>>>(bufP, stats1, out_nodes); // h1 -> out (f32)

    // ---- graph pooling ----
    graph_pool<<<NUM_GRAPHS, 128, 0, stream>>>(out_nodes, gid, pw, out_pool);
}

// Round 4
// 318.276 us; speedup vs baseline: 9.2326x; 1.2664x over previous
//
#include <hip/hip_runtime.h>

#define N_NODES    50000
#define N_EDGES    800000
#define DIM        128
#define NUM_GRAPHS 512
#define BN_EPS     1e-5f

#define N_PAD      50176              // 196 chunks * 256
#define N_CHUNKS   196
#define WT_LD      136                // LDS row stride (elems): 272B = 17 x 16B -> conflict-free

typedef unsigned int u32;
typedef unsigned short u16;
typedef __attribute__((ext_vector_type(8))) short bf16x8;
typedef __attribute__((ext_vector_type(4))) float f32x4;

__device__ __forceinline__ u16 f2bf(float f) {
    u32 u = __float_as_uint(f);
    u += 0x7FFF + ((u >> 16) & 1);    // round-to-nearest-even
    return (u16)(u >> 16);
}
__device__ __forceinline__ float bf2f(u16 h) {
    return __uint_as_float((u32)h << 16);
}

// ---------------- zero fill (graph-capture safe) ------------------------------
__global__ __launch_bounds__(256)
void fill_zero_kernel(float* __restrict__ p, long long n)
{
    long long stride = (long long)gridDim.x * blockDim.x;
    for (long long i = blockIdx.x * 256LL + threadIdx.x; i < n; i += stride)
        p[i] = 0.f;
}

// ---------------- f32 -> bf16 convert (x table) -------------------------------
__global__ __launch_bounds__(256)
void cvt_bf16_kernel(const float* __restrict__ in, u16* __restrict__ out, long long n4)
{
    long long stride = (long long)gridDim.x * blockDim.x;
    for (long long i = blockIdx.x * 256LL + threadIdx.x; i < n4; i += stride) {
        float4 v = ((const float4*)in)[i];
        ushort4 o;
        o.x = f2bf(v.x); o.y = f2bf(v.y); o.z = f2bf(v.z); o.w = f2bf(v.w);
        ((ushort4*)out)[i] = o;
    }
}

// -------- convert W1,W2 (both layers) f32 -> bf16 TRANSPOSED  -----------------
// wt[m][j][k] = W_m[k][j],  m = {l0W1, l0W2, l1W1, l1W2}
__global__ __launch_bounds__(256)
void cvt_wt_kernel(const float* __restrict__ W1, const float* __restrict__ W2,
                   u16* __restrict__ wt)
{
    int idx = blockIdx.x * 256 + threadIdx.x;
    if (idx >= 4 * 128 * 128) return;
    int m = idx >> 14;
    int j = (idx >> 7) & 127;
    int k = idx & 127;
    const float* src = (m & 1) ? W2 : W1;
    src += (m >> 1) * 128 * 128;
    wt[idx] = f2bf(src[k * 128 + j]);
}

// ---------------- CSR build ---------------------------------------------------
__global__ __launch_bounds__(256)
void hist_kernel(const int* __restrict__ dst, int* __restrict__ deg)
{
    int stride = gridDim.x * blockDim.x;
    for (int e = blockIdx.x * 256 + threadIdx.x; e < N_EDGES; e += stride)
        atomicAdd(&deg[dst[e]], 1);
}

__global__ __launch_bounds__(256)
void scan_chunk_sums(const int* __restrict__ deg, int* __restrict__ chunkSum)
{
    __shared__ int s[256];
    int t = threadIdx.x;
    s[t] = deg[blockIdx.x * 256 + t];
    __syncthreads();
    for (int off = 128; off > 0; off >>= 1) {
        if (t < off) s[t] += s[t + off];
        __syncthreads();
    }
    if (t == 0) chunkSum[blockIdx.x] = s[0];
}

__global__ __launch_bounds__(256)
void scan_chunk_base(const int* __restrict__ chunkSum, int* __restrict__ chunkBase)
{
    __shared__ int s[256];
    int t = threadIdx.x;
    int v = (t < N_CHUNKS) ? chunkSum[t] : 0;
    s[t] = v;
    __syncthreads();
    for (int off = 1; off < 256; off <<= 1) {
        int x = (t >= off) ? s[t - off] : 0;
        __syncthreads();
        s[t] += x;
        __syncthreads();
    }
    chunkBase[t] = s[t] - v;   // exclusive
}

__global__ __launch_bounds__(256)
void scan_rowptr(const int* __restrict__ deg, const int* __restrict__ chunkBase,
                 int* __restrict__ rowptr, int* __restrict__ cursor)
{
    __shared__ int s[256];
    int t = threadIdx.x;
    int i = blockIdx.x * 256 + t;
    int v = deg[i];
    s[t] = v;
    __syncthreads();
    for (int off = 1; off < 256; off <<= 1) {
        int x = (t >= off) ? s[t - off] : 0;
        __syncthreads();
        s[t] += x;
        __syncthreads();
    }
    int excl = s[t] - v + chunkBase[blockIdx.x];
    rowptr[i] = excl;
    cursor[i] = excl;
}

// edge record: (bf16 weight << 16) | src   (src < 65536)
__global__ __launch_bounds__(256)
void csr_fill(const int* __restrict__ src, const int* __restrict__ dst,
              const float* __restrict__ ew, int* __restrict__ cursor,
              u32* __restrict__ ed)
{
    int stride = gridDim.x * blockDim.x;
    for (int e = blockIdx.x * 256 + threadIdx.x; e < N_EDGES; e += stride) {
        int d = dst[e];
        int p = atomicAdd(&cursor[d], 1);
        ed[p] = ((u32)f2bf(ew[e]) << 16) | (u32)src[e];
    }
}

// ------------- pull-gather SpMM from bf16 table, bf16 output ------------------
__global__ __launch_bounds__(256)
void gather_spmm(const u16* __restrict__ h, const u32* __restrict__ ed,
                 const int* __restrict__ rowptr, u16* __restrict__ pooled)
{
    int node = blockIdx.x * 8 + (threadIdx.x >> 5);   // 8 nodes per block
    int lane = threadIdx.x & 31;                      // 32 threads per node
    int beg = rowptr[node];
    int end = rowptr[node + 1];
    float4 acc = make_float4(0.f, 0.f, 0.f, 0.f);
    for (int base = beg; base < end; base += 32) {
        int e = base + lane;
        u32 sw = (e < end) ? ed[e] : 0u;
        int cnt = min(32, end - base);
        #pragma unroll 4
        for (int i = 0; i < cnt; ++i) {
            u32 rec = __shfl(sw, i, 32);
            int   s = (int)(rec & 0xFFFFu);
            float w = bf2f((u16)(rec >> 16));
            ushort4 hv = *((const ushort4*)(h + (long long)s * DIM) + lane);
            acc.x += w * bf2f(hv.x);
            acc.y += w * bf2f(hv.y);
            acc.z += w * bf2f(hv.z);
            acc.w += w * bf2f(hv.w);
        }
    }
    ushort4 o;
    o.x = f2bf(acc.x); o.y = f2bf(acc.y); o.z = f2bf(acc.z); o.w = f2bf(acc.w);
    *((ushort4*)(pooled + (long long)node * DIM) + lane) = o;
}

// ---------------- fused MFMA MLP: z = (relu(A@W1+b1))@W2 + b2, + BN stats ----
// A [N,128] bf16, wt1/wt2 = W^T [128][128] bf16, Z [N,128] bf16, stats f32[256]
__global__ __launch_bounds__(256)
void fused_mlp(const u16* __restrict__ A, const u16* __restrict__ wt1,
               const u16* __restrict__ wt2, const float* __restrict__ b1,
               const float* __restrict__ b2, u16* __restrict__ Z,
               float* __restrict__ stats)
{
    __shared__ __align__(16) u16 wlds[128 * WT_LD];   // 34816 B
    __shared__ __align__(16) u16 hid[64 * WT_LD];     // 17408 B
    __shared__ float ssum[128];
    __shared__ float ssq[128];

    const int tid  = threadIdx.x;
    const int wave = tid >> 6;
    const int lane = tid & 63;
    const int l15  = lane & 15;
    const int lk   = lane >> 4;            // 0..3
    const int row0 = blockIdx.x * 64;
    const int wrow = wave * 16;            // wave's local base row

    // stage wt1 -> LDS (2048 16B chunks, 8/thread), init stat accumulators
    #pragma unroll
    for (int i = 0; i < 8; ++i) {
        int idx = tid + i * 256;
        int r = idx >> 4, c = idx & 15;
        *(bf16x8*)&wlds[r * WT_LD + c * 8] = *(const bf16x8*)(wt1 + r * 128 + c * 8);
    }
    if (tid < 128) { ssum[tid] = 0.f; ssq[tid] = 0.f; }

    // A-fragments (GEMM1) straight from global
    bf16x8 afr[4];
    {
        int rg = row0 + wrow + l15;
        bool ok = rg < N_NODES;
        const u16* ap = A + (long long)rg * 128 + lk * 8;
        bf16x8 zero = {};
        #pragma unroll
        for (int kk = 0; kk < 4; ++kk)
            afr[kk] = ok ? *(const bf16x8*)(ap + kk * 32) : zero;
    }
    __syncthreads();

    // GEMM1 + bias + relu -> hid (LDS)
    #pragma unroll
    for (int c = 0; c < 8; ++c) {
        float bv = b1[c * 16 + l15];
        f32x4 acc = {bv, bv, bv, bv};
        #pragma unroll
        for (int kk = 0; kk < 4; ++kk) {
            bf16x8 w = *(bf16x8*)&wlds[(c * 16 + l15) * WT_LD + kk * 32 + lk * 8];
            acc = __builtin_amdgcn_mfma_f32_16x16x32_bf16(afr[kk], w, acc, 0, 0, 0);
        }
        #pragma unroll
        for (int i = 0; i < 4; ++i) {
            int rl = wrow + lk * 4 + i;
            hid[rl * WT_LD + c * 16 + l15] = f2bf(fmaxf(acc[i], 0.f));
        }
    }
    __syncthreads();

    // stage wt2 over wt1
    #pragma unroll
    for (int i = 0; i < 8; ++i) {
        int idx = tid + i * 256;
        int r = idx >> 4, c = idx & 15;
        *(bf16x8*)&wlds[r * WT_LD + c * 8] = *(const bf16x8*)(wt2 + r * 128 + c * 8);
    }
    __syncthreads();

    // GEMM2 A-fragments from hid
    bf16x8 afr2[4];
    #pragma unroll
    for (int kk = 0; kk < 4; ++kk)
        afr2[kk] = *(bf16x8*)&hid[(wrow + l15) * WT_LD + kk * 32 + lk * 8];
    __syncthreads();   // hid now reusable as z staging

    // GEMM2 + bias -> z (bf16 in hid region) + f32 stats
    #pragma unroll
    for (int c = 0; c < 8; ++c) {
        float bv = b2[c * 16 + l15];
        f32x4 acc = {bv, bv, bv, bv};
        #pragma unroll
        for (int kk = 0; kk < 4; ++kk) {
            bf16x8 w = *(bf16x8*)&wlds[(c * 16 + l15) * WT_LD + kk * 32 + lk * 8];
            acc = __builtin_amdgcn_mfma_f32_16x16x32_bf16(afr2[kk], w, acc, 0, 0, 0);
        }
        float s = 0.f, sq = 0.f;
        #pragma unroll
        for (int i = 0; i < 4; ++i) {
            int rl = wrow + lk * 4 + i;
            int rg = row0 + rl;
            float v = acc[i];
            if (rg < N_NODES) { s += v; sq += v * v; }
            hid[rl * WT_LD + c * 16 + l15] = (rg < N_NODES) ? f2bf(v) : (u16)0;
        }
        atomicAdd(&ssum[c * 16 + l15], s);
        atomicAdd(&ssq[c * 16 + l15], sq);
    }
    __syncthreads();

    // cooperative vectorized z store
    #pragma unroll
    for (int j = 0; j < 4; ++j) {
        int idx = tid + j * 256;       // 0..1023
        int r = idx >> 4, c16 = idx & 15;
        int rg = row0 + r;
        if (rg < N_NODES) {
            bf16x8 v = *(bf16x8*)&hid[r * WT_LD + c16 * 8];
            *(bf16x8*)(Z + (long long)rg * 128 + c16 * 8) = v;
        }
    }
    if (tid < 128) {
        atomicAdd(&stats[tid], ssum[tid]);
        atomicAdd(&stats[128 + tid], ssq[tid]);
    }
}

// --------- BN finalize: stats -> (scale, shift) in place ---------------------
__global__ void bn_finalize(float* stats, const float* __restrict__ gamma,
                            const float* __restrict__ beta)
{
    int c = threadIdx.x;
    float mu  = stats[c] * (1.f / N_NODES);
    float var = stats[128 + c] * (1.f / N_NODES) - mu * mu;
    float sc  = gamma[c] * rsqrtf(var + BN_EPS);
    stats[c]       = sc;
    stats[128 + c] = beta[c] - mu * sc;
}

// --------- BN apply + relu: bf16 in, bf16 or f32 out -------------------------
template<bool BF16OUT>
__global__ __launch_bounds__(256)
void bn_apply(const u16* __restrict__ z, const float* __restrict__ stats,
              void* __restrict__ out)
{
    __shared__ float sc[128];
    __shared__ float sh[128];
    if (threadIdx.x < 128) {
        sc[threadIdx.x] = stats[threadIdx.x];
        sh[threadIdx.x] = stats[128 + threadIdx.x];
    }
    __syncthreads();
    const long long total = (long long)N_NODES * 16;   // 8-elem units
    long long stride = (long long)gridDim.x * blockDim.x;
    for (long long idx = blockIdx.x * 256LL + threadIdx.x; idx < total; idx += stride) {
        int c8 = (int)(idx & 15);
        bf16x8 v = *((const bf16x8*)z + idx);
        float o[8];
        #pragma unroll
        for (int q = 0; q < 8; ++q)
            o[q] = fmaxf(bf2f((u16)v[q]) * sc[c8 * 8 + q] + sh[c8 * 8 + q], 0.f);
        if (BF16OUT) {
            bf16x8 ob;
            #pragma unroll
            for (int q = 0; q < 8; ++q) ob[q] = (short)f2bf(o[q]);
            *((bf16x8*)out + idx) = ob;
        } else {
            float4 f0 = make_float4(o[0], o[1], o[2], o[3]);
            float4 f1 = make_float4(o[4], o[5], o[6], o[7]);
            ((float4*)out)[idx * 2]     = f0;
            ((float4*)out)[idx * 2 + 1] = f1;
        }
    }
}

// --------- graph pooling: per-graph block, binary search on sorted ids --------
__global__ __launch_bounds__(128)
void graph_pool(const float* __restrict__ h, const int* __restrict__ gid,
                const float* __restrict__ pw, float* __restrict__ out)
{
    int g = blockIdx.x;
    int lo = 0, hi = N_NODES;
    while (lo < hi) { int m = (lo + hi) >> 1; if (gid[m] < g) lo = m + 1; else hi = m; }
    int start = lo;
    hi = N_NODES;
    while (lo < hi) { int m = (lo + hi) >> 1; if (gid[m] < g + 1) lo = m + 1; else hi = m; }
    int end = lo;
    int c = threadIdx.x;
    float acc = 0.f;
    for (int n = start; n < end; ++n)
        acc += pw[n] * h[(long long)n * DIM + c];
    out[g * DIM + c] = acc;
}

extern "C" void kernel_launch(void* const* d_in, const int* in_sizes, int n_in,
                              void* d_out, int out_size, void* d_ws, size_t ws_size,
                              hipStream_t stream)
{
    const float* x    = (const float*)d_in[0];
    const int*   esrc = (const int*)d_in[1];
    const int*   edst = (const int*)d_in[2];
    const float* ew   = (const float*)d_in[3];
    const int*   gid  = (const int*)d_in[4];
    const float* pw   = (const float*)d_in[5];
    const float* W1   = (const float*)d_in[6];
    const float* b1   = (const float*)d_in[7];
    const float* W2   = (const float*)d_in[8];
    const float* b2   = (const float*)d_in[9];
    const float* gam  = (const float*)d_in[10];
    const float* bet  = (const float*)d_in[11];

    float* out_pool  = (float*)d_out;                      // [512,128]
    float* out_nodes = (float*)d_out + NUM_GRAPHS * DIM;   // [50000,128]

    // ---- workspace layout ----
    const size_t NF = (size_t)N_NODES * DIM;
    char* w = (char*)d_ws;
    u32*   ed       = (u32*)w;        w += (size_t)N_EDGES * sizeof(u32);
    u16*   pooledBf = (u16*)w;        w += NF * sizeof(u16);
    u16*   zBf      = (u16*)w;        w += NF * sizeof(u16);
    u16*   hx       = (u16*)w;        w += NF * sizeof(u16);
    u16*   wt       = (u16*)w;        w += (size_t)4 * 128 * 128 * sizeof(u16);
    // contiguous zero region: stats0 | stats1 | deg
    float* stats0   = (float*)w;      w += 256 * sizeof(float);
    float* stats1   = (float*)w;      w += 256 * sizeof(float);
    int*   deg      = (int*)w;        w += N_PAD * sizeof(int);
    int*   rowptr   = (int*)w;        w += (N_PAD + 64) * sizeof(int);
    int*   cursor   = (int*)w;        w += (N_PAD + 64) * sizeof(int);
    int*   chunkSum = (int*)w;        w += 256 * sizeof(int);
    int*   chunkBase= (int*)w;        w += 256 * sizeof(int);

    const int mlpGrid    = (N_NODES + 63) / 64;   // 782
    const int edgeGrid   = 2048;
    const int elemGrid   = 1024;
    const int gatherGrid = N_NODES / 8;           // 6250

    // ---- CSR build + converts ----
    fill_zero_kernel<<<64, 256, 0, stream>>>(stats0, 512 + N_PAD);
    hist_kernel<<<edgeGrid, 256, 0, stream>>>(edst, deg);
    cvt_bf16_kernel<<<1024, 256, 0, stream>>>(x, hx, (long long)(NF / 4));
    cvt_wt_kernel<<<256, 256, 0, stream>>>(W1, W2, wt);
    scan_chunk_sums<<<N_CHUNKS, 256, 0, stream>>>(deg, chunkSum);
    scan_chunk_base<<<1, 256, 0, stream>>>(chunkSum, chunkBase);
    scan_rowptr<<<N_CHUNKS, 256, 0, stream>>>(deg, chunkBase, rowptr, cursor);
    csr_fill<<<edgeGrid, 256, 0, stream>>>(esrc, edst, ew, cursor, ed);

    // ---- layer 0 ----
    gather_spmm<<<gatherGrid, 256, 0, stream>>>(hx, ed, rowptr, pooledBf);
    fused_mlp<<<mlpGrid, 256, 0, stream>>>(pooledBf, wt, wt + 16384, b1, b2, zBf, stats0);
    bn_finalize<<<1, 128, 0, stream>>>(stats0, gam, bet);
    bn_apply<true><<<elemGrid, 256, 0, stream>>>(zBf, stats0, hx);        // h0 -> hx bf16

    // ---- layer 1 ----
    gather_spmm<<<gatherGrid, 256, 0, stream>>>(hx, ed, rowptr, pooledBf);
    fused_mlp<<<mlpGrid, 256, 0, stream>>>(pooledBf, wt + 32768, wt + 49152,
                                           b1 + DIM, b2 + DIM, zBf, stats1);
    bn_finalize<<<1, 128, 0, stream>>>(stats1, gam + DIM, bet + DIM);
    bn_apply<false><<<elemGrid, 256, 0, stream>>>(zBf, stats1, out_nodes); // h1 -> f32 out

    // ---- graph pooling ----
    graph_pool<<<NUM_GRAPHS, 128, 0, stream>>>(out_nodes, gid, pw, out_pool);
}

// Round 5
// 271.496 us; speedup vs baseline: 10.8234x; 1.1723x over previous
//
#include <hip/hip_runtime.h>

#define N_NODES    50000
#define N_EDGES    800000
#define DIM        128
#define NUM_GRAPHS 512
#define BN_EPS     1e-5f

#define NBUCK      196                // buckets of 256 nodes: dst >> 8
#define TILE       2048               // edges per partitionA block
#define WT_LD      136                // LDS row stride (elems): 272B = 17 x 16B -> conflict-free

typedef unsigned int u32;
typedef unsigned short u16;
typedef __attribute__((ext_vector_type(8))) short bf16x8;
typedef __attribute__((ext_vector_type(4))) float f32x4;

__device__ __forceinline__ u16 f2bf(float f) {
    u32 u = __float_as_uint(f);
    u += 0x7FFF + ((u >> 16) & 1);    // round-to-nearest-even
    return (u16)(u >> 16);
}
__device__ __forceinline__ float bf2f(u16 h) {
    return __uint_as_float((u32)h << 16);
}

// ---------------- zero fill (graph-capture safe) ------------------------------
__global__ __launch_bounds__(256)
void fill_zero_kernel(float* __restrict__ p, long long n)
{
    long long stride = (long long)gridDim.x * blockDim.x;
    for (long long i = blockIdx.x * 256LL + threadIdx.x; i < n; i += stride)
        p[i] = 0.f;
}

// ---------------- f32 -> bf16 convert (x table) -------------------------------
__global__ __launch_bounds__(256)
void cvt_bf16_kernel(const float* __restrict__ in, u16* __restrict__ out, long long n4)
{
    long long stride = (long long)gridDim.x * blockDim.x;
    for (long long i = blockIdx.x * 256LL + threadIdx.x; i < n4; i += stride) {
        float4 v = ((const float4*)in)[i];
        ushort4 o;
        o.x = f2bf(v.x); o.y = f2bf(v.y); o.z = f2bf(v.z); o.w = f2bf(v.w);
        ((ushort4*)out)[i] = o;
    }
}

// -------- convert W1,W2 (both layers) f32 -> bf16 TRANSPOSED  -----------------
__global__ __launch_bounds__(256)
void cvt_wt_kernel(const float* __restrict__ W1, const float* __restrict__ W2,
                   u16* __restrict__ wt)
{
    int idx = blockIdx.x * 256 + threadIdx.x;
    if (idx >= 4 * 128 * 128) return;
    int m = idx >> 14;
    int j = (idx >> 7) & 127;
    int k = idx & 127;
    const float* src = (m & 1) ? W2 : W1;
    src += (m >> 1) * 128 * 128;
    wt[idx] = f2bf(src[k * 128 + j]);
}

// ---------------- bucket histogram (LDS-staged) -------------------------------
__global__ __launch_bounds__(256)
void bucket_hist(const int* __restrict__ dst, int* __restrict__ bucketCnt)
{
    __shared__ int cnt[NBUCK];
    int t = threadIdx.x;
    if (t < NBUCK) cnt[t] = 0;
    __syncthreads();
    int stride = gridDim.x * blockDim.x;
    for (int e = blockIdx.x * 256 + t; e < N_EDGES; e += stride)
        atomicAdd(&cnt[dst[e] >> 8], 1);
    __syncthreads();
    if (t < NBUCK && cnt[t] > 0) atomicAdd(&bucketCnt[t], cnt[t]);
}

// ---------------- bucket scan: exclusive -> bucketStart, gCursor --------------
__global__ __launch_bounds__(256)
void bucket_scan(const int* __restrict__ bucketCnt, int* __restrict__ bucketStart,
                 int* __restrict__ gCursor)
{
    __shared__ int s[256];
    int t = threadIdx.x;
    int v = (t < NBUCK) ? bucketCnt[t] : 0;
    s[t] = v;
    __syncthreads();
    for (int off = 1; off < 256; off <<= 1) {
        int x = (t >= off) ? s[t - off] : 0;
        __syncthreads();
        s[t] += x;
        __syncthreads();
    }
    int excl = s[t] - v;
    if (t <= NBUCK) bucketStart[t] = excl;     // bucketStart[NBUCK] = total
    if (t < NBUCK)  gCursor[t] = excl;
}

// ------- partition A: tile-compacted scatter into bucket regions (8B recs) ----
__global__ __launch_bounds__(256)
void partitionA(const int* __restrict__ src, const int* __restrict__ dst,
                const float* __restrict__ ew, int* __restrict__ gCursor,
                uint2* __restrict__ ed2)
{
    __shared__ int cnt[NBUCK];
    __shared__ int off[NBUCK];
    __shared__ int gb[NBUCK];
    __shared__ u32 stg_sw[TILE];
    __shared__ u32 stg_d[TILE];
    __shared__ int scanb[256];

    const int t = threadIdx.x;
    const int base = blockIdx.x * TILE;
    const int tcnt = min(TILE, N_EDGES - base);

    if (t < NBUCK) cnt[t] = 0;
    __syncthreads();

    u32 swv[8], dv[8];
    int rk[8], bk[8];
    #pragma unroll
    for (int j = 0; j < 8; ++j) {
        int e = base + j * 256 + t;
        if (e < N_EDGES) {
            int d = dst[e];
            swv[j] = ((u32)f2bf(ew[e]) << 16) | (u32)src[e];
            dv[j]  = (u32)d;
            bk[j]  = d >> 8;
            rk[j]  = atomicAdd(&cnt[bk[j]], 1);
        } else bk[j] = -1;
    }
    __syncthreads();

    // exclusive scan of cnt -> off
    {
        int v = (t < NBUCK) ? cnt[t] : 0;
        scanb[t] = v;
        __syncthreads();
        for (int o = 1; o < 256; o <<= 1) {
            int x = (t >= o) ? scanb[t - o] : 0;
            __syncthreads();
            scanb[t] += x;
            __syncthreads();
        }
        if (t < NBUCK) off[t] = scanb[t] - v;
    }
    __syncthreads();

    #pragma unroll
    for (int j = 0; j < 8; ++j) {
        if (bk[j] >= 0) {
            int idx = off[bk[j]] + rk[j];
            stg_sw[idx] = swv[j];
            stg_d[idx]  = dv[j];
        }
    }
    if (t < NBUCK && cnt[t] > 0) gb[t] = atomicAdd(&gCursor[t], cnt[t]);
    __syncthreads();

    for (int j = t; j < tcnt; j += 256) {
        u32 d = stg_d[j];
        int b = (int)(d >> 8);
        int pos = gb[b] + (j - off[b]);
        ed2[pos] = make_uint2(stg_sw[j], d);
    }
}

// ------- partition B: exact CSR within bucket (windowed writes) + rowptr ------
__global__ __launch_bounds__(256)
void partitionB(const uint2* __restrict__ ed2, const int* __restrict__ bucketStart,
                int* __restrict__ rowptr, u32* __restrict__ ed)
{
    __shared__ int hist[256];
    __shared__ int sc[256];
    __shared__ int cur[256];

    const int b = blockIdx.x;
    const int t = threadIdx.x;
    const int s = bucketStart[b];
    const int n = bucketStart[b + 1] - s;

    hist[t] = 0;
    __syncthreads();
    for (int j = t; j < n; j += 256)
        atomicAdd(&hist[ed2[s + j].y & 255u], 1);
    __syncthreads();

    int v = hist[t];
    sc[t] = v;
    __syncthreads();
    for (int o = 1; o < 256; o <<= 1) {
        int x = (t >= o) ? sc[t - o] : 0;
        __syncthreads();
        sc[t] += x;
        __syncthreads();
    }
    int excl = sc[t] - v;
    rowptr[b * 256 + t] = s + excl;
    cur[t] = s + excl;
    __syncthreads();

    for (int j = t; j < n; j += 256) {
        uint2 r = ed2[s + j];
        int d = (int)(r.y & 255u);
        int p = atomicAdd(&cur[d], 1);
        ed[p] = r.x;
    }
}

// ------------- pull-gather SpMM from bf16 table, bf16 output ------------------
__global__ __launch_bounds__(256)
void gather_spmm(const u16* __restrict__ h, const u32* __restrict__ ed,
                 const int* __restrict__ rowptr, u16* __restrict__ pooled)
{
    int node = blockIdx.x * 8 + (threadIdx.x >> 5);   // 8 nodes per block
    int lane = threadIdx.x & 31;                      // 32 threads per node
    int beg = rowptr[node];
    int end = rowptr[node + 1];
    float4 acc = make_float4(0.f, 0.f, 0.f, 0.f);
    for (int base = beg; base < end; base += 32) {
        int e = base + lane;
        u32 sw = (e < end) ? ed[e] : 0u;
        int cnt = min(32, end - base);
        #pragma unroll 4
        for (int i = 0; i < cnt; ++i) {
            u32 rec = __shfl(sw, i, 32);
            int   s = (int)(rec & 0xFFFFu);
            float w = bf2f((u16)(rec >> 16));
            ushort4 hv = *((const ushort4*)(h + (long long)s * DIM) + lane);
            acc.x += w * bf2f(hv.x);
            acc.y += w * bf2f(hv.y);
            acc.z += w * bf2f(hv.z);
            acc.w += w * bf2f(hv.w);
        }
    }
    ushort4 o;
    o.x = f2bf(acc.x); o.y = f2bf(acc.y); o.z = f2bf(acc.z); o.w = f2bf(acc.w);
    *((ushort4*)(pooled + (long long)node * DIM) + lane) = o;
}

// ---------------- fused MFMA MLP: z = (relu(A@W1+b1))@W2 + b2, + BN stats ----
__global__ __launch_bounds__(256)
void fused_mlp(const u16* __restrict__ A, const u16* __restrict__ wt1,
               const u16* __restrict__ wt2, const float* __restrict__ b1,
               const float* __restrict__ b2, u16* __restrict__ Z,
               float* __restrict__ stats)
{
    __shared__ __align__(16) u16 wlds[128 * WT_LD];
    __shared__ __align__(16) u16 hid[64 * WT_LD];
    __shared__ float ssum[128];
    __shared__ float ssq[128];

    const int tid  = threadIdx.x;
    const int wave = tid >> 6;
    const int lane = tid & 63;
    const int l15  = lane & 15;
    const int lk   = lane >> 4;
    const int row0 = blockIdx.x * 64;
    const int wrow = wave * 16;

    #pragma unroll
    for (int i = 0; i < 8; ++i) {
        int idx = tid + i * 256;
        int r = idx >> 4, c = idx & 15;
        *(bf16x8*)&wlds[r * WT_LD + c * 8] = *(const bf16x8*)(wt1 + r * 128 + c * 8);
    }
    if (tid < 128) { ssum[tid] = 0.f; ssq[tid] = 0.f; }

    bf16x8 afr[4];
    {
        int rg = row0 + wrow + l15;
        bool ok = rg < N_NODES;
        const u16* ap = A + (long long)rg * 128 + lk * 8;
        bf16x8 zero = {};
        #pragma unroll
        for (int kk = 0; kk < 4; ++kk)
            afr[kk] = ok ? *(const bf16x8*)(ap + kk * 32) : zero;
    }
    __syncthreads();

    #pragma unroll
    for (int c = 0; c < 8; ++c) {
        float bv = b1[c * 16 + l15];
        f32x4 acc = {bv, bv, bv, bv};
        #pragma unroll
        for (int kk = 0; kk < 4; ++kk) {
            bf16x8 w = *(bf16x8*)&wlds[(c * 16 + l15) * WT_LD + kk * 32 + lk * 8];
            acc = __builtin_amdgcn_mfma_f32_16x16x32_bf16(afr[kk], w, acc, 0, 0, 0);
        }
        #pragma unroll
        for (int i = 0; i < 4; ++i) {
            int rl = wrow + lk * 4 + i;
            hid[rl * WT_LD + c * 16 + l15] = f2bf(fmaxf(acc[i], 0.f));
        }
    }
    __syncthreads();

    #pragma unroll
    for (int i = 0; i < 8; ++i) {
        int idx = tid + i * 256;
        int r = idx >> 4, c = idx & 15;
        *(bf16x8*)&wlds[r * WT_LD + c * 8] = *(const bf16x8*)(wt2 + r * 128 + c * 8);
    }
    __syncthreads();

    bf16x8 afr2[4];
    #pragma unroll
    for (int kk = 0; kk < 4; ++kk)
        afr2[kk] = *(bf16x8*)&hid[(wrow + l15) * WT_LD + kk * 32 + lk * 8];
    __syncthreads();

    #pragma unroll
    for (int c = 0; c < 8; ++c) {
        float bv = b2[c * 16 + l15];
        f32x4 acc = {bv, bv, bv, bv};
        #pragma unroll
        for (int kk = 0; kk < 4; ++kk) {
            bf16x8 w = *(bf16x8*)&wlds[(c * 16 + l15) * WT_LD + kk * 32 + lk * 8];
            acc = __builtin_amdgcn_mfma_f32_16x16x32_bf16(afr2[kk], w, acc, 0, 0, 0);
        }
        float s = 0.f, sq = 0.f;
        #pragma unroll
        for (int i = 0; i < 4; ++i) {
            int rl = wrow + lk * 4 + i;
            int rg = row0 + rl;
            float v = acc[i];
            if (rg < N_NODES) { s += v; sq += v * v; }
            hid[rl * WT_LD + c * 16 + l15] = (rg < N_NODES) ? f2bf(v) : (u16)0;
        }
        atomicAdd(&ssum[c * 16 + l15], s);
        atomicAdd(&ssq[c * 16 + l15], sq);
    }
    __syncthreads();

    #pragma unroll
    for (int j = 0; j < 4; ++j) {
        int idx = tid + j * 256;
        int r = idx >> 4, c16 = idx & 15;
        int rg = row0 + r;
        if (rg < N_NODES) {
            bf16x8 v = *(bf16x8*)&hid[r * WT_LD + c16 * 8];
            *(bf16x8*)(Z + (long long)rg * 128 + c16 * 8) = v;
        }
    }
    if (tid < 128) {
        atomicAdd(&stats[tid], ssum[tid]);
        atomicAdd(&stats[128 + tid], ssq[tid]);
    }
}

// --------- BN finalize ---------------------------------------------------------
__global__ void bn_finalize(float* stats, const float* __restrict__ gamma,
                            const float* __restrict__ beta)
{
    int c = threadIdx.x;
    float mu  = stats[c] * (1.f / N_NODES);
    float var = stats[128 + c] * (1.f / N_NODES) - mu * mu;
    float sc  = gamma[c] * rsqrtf(var + BN_EPS);
    stats[c]       = sc;
    stats[128 + c] = beta[c] - mu * sc;
}

// --------- BN apply + relu: bf16 in, bf16 or f32 out -------------------------
template<bool BF16OUT>
__global__ __launch_bounds__(256)
void bn_apply(const u16* __restrict__ z, const float* __restrict__ stats,
              void* __restrict__ out)
{
    __shared__ float sc[128];
    __shared__ float sh[128];
    if (threadIdx.x < 128) {
        sc[threadIdx.x] = stats[threadIdx.x];
        sh[threadIdx.x] = stats[128 + threadIdx.x];
    }
    __syncthreads();
    const long long total = (long long)N_NODES * 16;
    long long stride = (long long)gridDim.x * blockDim.x;
    for (long long idx = blockIdx.x * 256LL + threadIdx.x; idx < total; idx += stride) {
        int c8 = (int)(idx & 15);
        bf16x8 v = *((const bf16x8*)z + idx);
        float o[8];
        #pragma unroll
        for (int q = 0; q < 8; ++q)
            o[q] = fmaxf(bf2f((u16)v[q]) * sc[c8 * 8 + q] + sh[c8 * 8 + q], 0.f);
        if (BF16OUT) {
            bf16x8 ob;
            #pragma unroll
            for (int q = 0; q < 8; ++q) ob[q] = (short)f2bf(o[q]);
            *((bf16x8*)out + idx) = ob;
        } else {
            float4 f0 = make_float4(o[0], o[1], o[2], o[3]);
            float4 f1 = make_float4(o[4], o[5], o[6], o[7]);
            ((float4*)out)[idx * 2]     = f0;
            ((float4*)out)[idx * 2 + 1] = f1;
        }
    }
}

// --------- graph pooling --------------------------------------------------------
__global__ __launch_bounds__(128)
void graph_pool(const float* __restrict__ h, const int* __restrict__ gid,
                const float* __restrict__ pw, float* __restrict__ out)
{
    int g = blockIdx.x;
    int lo = 0, hi = N_NODES;
    while (lo < hi) { int m = (lo + hi) >> 1; if (gid[m] < g) lo = m + 1; else hi = m; }
    int start = lo;
    hi = N_NODES;
    while (lo < hi) { int m = (lo + hi) >> 1; if (gid[m] < g + 1) lo = m + 1; else hi = m; }
    int end = lo;
    int c = threadIdx.x;
    float acc = 0.f;
    for (int n = start; n < end; ++n)
        acc += pw[n] * h[(long long)n * DIM + c];
    out[g * DIM + c] = acc;
}

extern "C" void kernel_launch(void* const* d_in, const int* in_sizes, int n_in,
                              void* d_out, int out_size, void* d_ws, size_t ws_size,
                              hipStream_t stream)
{
    const float* x    = (const float*)d_in[0];
    const int*   esrc = (const int*)d_in[1];
    const int*   edst = (const int*)d_in[2];
    const float* ew   = (const float*)d_in[3];
    const int*   gid  = (const int*)d_in[4];
    const float* pw   = (const float*)d_in[5];
    const float* W1   = (const float*)d_in[6];
    const float* b1   = (const float*)d_in[7];
    const float* W2   = (const float*)d_in[8];
    const float* b2   = (const float*)d_in[9];
    const float* gam  = (const float*)d_in[10];
    const float* bet  = (const float*)d_in[11];

    float* out_pool  = (float*)d_out;                      // [512,128]
    float* out_nodes = (float*)d_out + NUM_GRAPHS * DIM;   // [50000,128]

    // ---- workspace layout ----
    const size_t NF = (size_t)N_NODES * DIM;
    char* w = (char*)d_ws;
    uint2* ed2      = (uint2*)w;      w += (size_t)N_EDGES * sizeof(uint2);
    u32*   ed       = (u32*)w;        w += (size_t)N_EDGES * sizeof(u32);
    u16*   pooledBf = (u16*)w;        w += NF * sizeof(u16);
    u16*   zBf      = (u16*)w;        w += NF * sizeof(u16);
    u16*   hx       = (u16*)w;        w += NF * sizeof(u16);
    u16*   wt       = (u16*)w;        w += (size_t)4 * 128 * 128 * sizeof(u16);
    // contiguous zero region: stats0 | stats1 | bucketCnt
    float* stats0   = (float*)w;      w += 256 * sizeof(float);
    float* stats1   = (float*)w;      w += 256 * sizeof(float);
    int*   bucketCnt= (int*)w;        w += 256 * sizeof(int);
    int*   bucketStart=(int*)w;       w += 256 * sizeof(int);
    int*   gCursor  = (int*)w;        w += 256 * sizeof(int);
    int*   rowptr   = (int*)w;        w += (NBUCK * 256 + 64) * sizeof(int);

    const int mlpGrid    = (N_NODES + 63) / 64;          // 782
    const int elemGrid   = 1024;
    const int gatherGrid = N_NODES / 8;                  // 6250
    const int partGrid   = (N_EDGES + TILE - 1) / TILE;  // 391

    // ---- CSR build via bucketed counting sort + converts ----
    fill_zero_kernel<<<1, 256, 0, stream>>>(stats0, 768);   // stats0|stats1|bucketCnt
    bucket_hist<<<512, 256, 0, stream>>>(edst, bucketCnt);
    cvt_bf16_kernel<<<1024, 256, 0, stream>>>(x, hx, (long long)(NF / 4));
    cvt_wt_kernel<<<256, 256, 0, stream>>>(W1, W2, wt);
    bucket_scan<<<1, 256, 0, stream>>>(bucketCnt, bucketStart, gCursor);
    partitionA<<<partGrid, 256, 0, stream>>>(esrc, edst, ew, gCursor, ed2);
    partitionB<<<NBUCK, 256, 0, stream>>>(ed2, bucketStart, rowptr, ed);

    // ---- layer 0 ----
    gather_spmm<<<gatherGrid, 256, 0, stream>>>(hx, ed, rowptr, pooledBf);
    fused_mlp<<<mlpGrid, 256, 0, stream>>>(pooledBf, wt, wt + 16384, b1, b2, zBf, stats0);
    bn_finalize<<<1, 128, 0, stream>>>(stats0, gam, bet);
    bn_apply<true><<<elemGrid, 256, 0, stream>>>(zBf, stats0, hx);        // h0 -> hx bf16

    // ---- layer 1 ----
    gather_spmm<<<gatherGrid, 256, 0, stream>>>(hx, ed, rowptr, pooledBf);
    fused_mlp<<<mlpGrid, 256, 0, stream>>>(pooledBf, wt + 32768, wt + 49152,
                                           b1 + DIM, b2 + DIM, zBf, stats1);
    bn_finalize<<<1, 128, 0, stream>>>(stats1, gam + DIM, bet + DIM);
    bn_apply<false><<<elemGrid, 256, 0, stream>>>(zBf, stats1, out_nodes); // h1 -> f32 out

    // ---- graph pooling ----
    graph_pool<<<NUM_GRAPHS, 128, 0, stream>>>(out_nodes, gid, pw, out_pool);
}

// Round 6
// 260.621 us; speedup vs baseline: 11.2750x; 1.0417x over previous
//
#include <hip/hip_runtime.h>

#define N_NODES    50000
#define N_EDGES    800000
#define DIM        128
#define NUM_GRAPHS 512
#define BN_EPS     1e-5f

#define NBUCK      196                // buckets of 256 nodes: dst >> 8
#define TILE       2048               // edges per partitionA block
#define WT_LD      136                // LDS row stride (elems): 272B = 17 x 16B -> conflict-free
#define MLP_ROWS   128                // rows per fused_mlp block (512 threads, 8 waves)

typedef unsigned int u32;
typedef unsigned short u16;
typedef __attribute__((ext_vector_type(8))) short bf16x8;
typedef __attribute__((ext_vector_type(4))) float f32x4;

__device__ __forceinline__ u16 f2bf(float f) {
    u32 u = __float_as_uint(f);
    u += 0x7FFF + ((u >> 16) & 1);    // round-to-nearest-even
    return (u16)(u >> 16);
}
__device__ __forceinline__ float bf2f(u16 h) {
    return __uint_as_float((u32)h << 16);
}

// ---------------- zero fill (graph-capture safe) ------------------------------
__global__ __launch_bounds__(256)
void fill_zero_kernel(float* __restrict__ p, long long n)
{
    long long stride = (long long)gridDim.x * blockDim.x;
    for (long long i = blockIdx.x * 256LL + threadIdx.x; i < n; i += stride)
        p[i] = 0.f;
}

// ---------------- f32 -> bf16 convert (x table) -------------------------------
__global__ __launch_bounds__(256)
void cvt_bf16_kernel(const float* __restrict__ in, u16* __restrict__ out, long long n4)
{
    long long stride = (long long)gridDim.x * blockDim.x;
    for (long long i = blockIdx.x * 256LL + threadIdx.x; i < n4; i += stride) {
        float4 v = ((const float4*)in)[i];
        ushort4 o;
        o.x = f2bf(v.x); o.y = f2bf(v.y); o.z = f2bf(v.z); o.w = f2bf(v.w);
        ((ushort4*)out)[i] = o;
    }
}

// -------- convert W1,W2 (both layers) f32 -> bf16 TRANSPOSED  -----------------
__global__ __launch_bounds__(256)
void cvt_wt_kernel(const float* __restrict__ W1, const float* __restrict__ W2,
                   u16* __restrict__ wt)
{
    int idx = blockIdx.x * 256 + threadIdx.x;
    if (idx >= 4 * 128 * 128) return;
    int m = idx >> 14;
    int j = (idx >> 7) & 127;
    int k = idx & 127;
    const float* src = (m & 1) ? W2 : W1;
    src += (m >> 1) * 128 * 128;
    wt[idx] = f2bf(src[k * 128 + j]);
}

// ---------------- bucket histogram (LDS-staged) -------------------------------
__global__ __launch_bounds__(256)
void bucket_hist(const int* __restrict__ dst, int* __restrict__ bucketCnt)
{
    __shared__ int cnt[NBUCK];
    int t = threadIdx.x;
    if (t < NBUCK) cnt[t] = 0;
    __syncthreads();
    int stride = gridDim.x * blockDim.x;
    for (int e = blockIdx.x * 256 + t; e < N_EDGES; e += stride)
        atomicAdd(&cnt[dst[e] >> 8], 1);
    __syncthreads();
    if (t < NBUCK && cnt[t] > 0) atomicAdd(&bucketCnt[t], cnt[t]);
}

// ---------------- bucket scan: exclusive -> bucketStart, gCursor --------------
__global__ __launch_bounds__(256)
void bucket_scan(const int* __restrict__ bucketCnt, int* __restrict__ bucketStart,
                 int* __restrict__ gCursor)
{
    __shared__ int s[256];
    int t = threadIdx.x;
    int v = (t < NBUCK) ? bucketCnt[t] : 0;
    s[t] = v;
    __syncthreads();
    for (int off = 1; off < 256; off <<= 1) {
        int x = (t >= off) ? s[t - off] : 0;
        __syncthreads();
        s[t] += x;
        __syncthreads();
    }
    int excl = s[t] - v;
    if (t <= NBUCK) bucketStart[t] = excl;     // bucketStart[NBUCK] = total
    if (t < NBUCK)  gCursor[t] = excl;
}

// ------- partition A: tile-compacted scatter into bucket regions (8B recs) ----
__global__ __launch_bounds__(256)
void partitionA(const int* __restrict__ src, const int* __restrict__ dst,
                const float* __restrict__ ew, int* __restrict__ gCursor,
                uint2* __restrict__ ed2)
{
    __shared__ int cnt[NBUCK];
    __shared__ int off[NBUCK];
    __shared__ int gb[NBUCK];
    __shared__ u32 stg_sw[TILE];
    __shared__ u32 stg_d[TILE];
    __shared__ int scanb[256];

    const int t = threadIdx.x;
    const int base = blockIdx.x * TILE;
    const int tcnt = min(TILE, N_EDGES - base);

    if (t < NBUCK) cnt[t] = 0;
    __syncthreads();

    u32 swv[8], dv[8];
    int rk[8], bk[8];
    #pragma unroll
    for (int j = 0; j < 8; ++j) {
        int e = base + j * 256 + t;
        if (e < N_EDGES) {
            int d = dst[e];
            swv[j] = ((u32)f2bf(ew[e]) << 16) | (u32)src[e];
            dv[j]  = (u32)d;
            bk[j]  = d >> 8;
            rk[j]  = atomicAdd(&cnt[bk[j]], 1);
        } else bk[j] = -1;
    }
    __syncthreads();

    // exclusive scan of cnt -> off
    {
        int v = (t < NBUCK) ? cnt[t] : 0;
        scanb[t] = v;
        __syncthreads();
        for (int o = 1; o < 256; o <<= 1) {
            int x = (t >= o) ? scanb[t - o] : 0;
            __syncthreads();
            scanb[t] += x;
            __syncthreads();
        }
        if (t < NBUCK) off[t] = scanb[t] - v;
    }
    __syncthreads();

    #pragma unroll
    for (int j = 0; j < 8; ++j) {
        if (bk[j] >= 0) {
            int idx = off[bk[j]] + rk[j];
            stg_sw[idx] = swv[j];
            stg_d[idx]  = dv[j];
        }
    }
    if (t < NBUCK && cnt[t] > 0) gb[t] = atomicAdd(&gCursor[t], cnt[t]);
    __syncthreads();

    for (int j = t; j < tcnt; j += 256) {
        u32 d = stg_d[j];
        int b = (int)(d >> 8);
        int pos = gb[b] + (j - off[b]);
        ed2[pos] = make_uint2(stg_sw[j], d);
    }
}

// ------- partition B: exact CSR within bucket (windowed writes) + rowptr ------
__global__ __launch_bounds__(256)
void partitionB(const uint2* __restrict__ ed2, const int* __restrict__ bucketStart,
                int* __restrict__ rowptr, u32* __restrict__ ed)
{
    __shared__ int hist[256];
    __shared__ int sc[256];
    __shared__ int cur[256];

    const int b = blockIdx.x;
    const int t = threadIdx.x;
    const int s = bucketStart[b];
    const int n = bucketStart[b + 1] - s;

    hist[t] = 0;
    __syncthreads();
    for (int j = t; j < n; j += 256)
        atomicAdd(&hist[ed2[s + j].y & 255u], 1);
    __syncthreads();

    int v = hist[t];
    sc[t] = v;
    __syncthreads();
    for (int o = 1; o < 256; o <<= 1) {
        int x = (t >= o) ? sc[t - o] : 0;
        __syncthreads();
        sc[t] += x;
        __syncthreads();
    }
    int excl = sc[t] - v;
    rowptr[b * 256 + t] = s + excl;
    cur[t] = s + excl;
    __syncthreads();

    for (int j = t; j < n; j += 256) {
        uint2 r = ed2[s + j];
        int d = (int)(r.y & 255u);
        int p = atomicAdd(&cur[d], 1);
        ed[p] = r.x;
    }
}

// ------------- pull-gather SpMM from bf16 table, bf16 output ------------------
__global__ __launch_bounds__(256)
void gather_spmm(const u16* __restrict__ h, const u32* __restrict__ ed,
                 const int* __restrict__ rowptr, u16* __restrict__ pooled)
{
    int node = blockIdx.x * 8 + (threadIdx.x >> 5);   // 8 nodes per block
    int lane = threadIdx.x & 31;                      // 32 threads per node
    int beg = rowptr[node];
    int end = rowptr[node + 1];
    float4 acc = make_float4(0.f, 0.f, 0.f, 0.f);
    for (int base = beg; base < end; base += 32) {
        int e = base + lane;
        u32 sw = (e < end) ? ed[e] : 0u;
        int cnt = min(32, end - base);
        #pragma unroll 4
        for (int i = 0; i < cnt; ++i) {
            u32 rec = __shfl(sw, i, 32);
            int   s = (int)(rec & 0xFFFFu);
            float w = bf2f((u16)(rec >> 16));
            ushort4 hv = *((const ushort4*)(h + (long long)s * DIM) + lane);
            acc.x += w * bf2f(hv.x);
            acc.y += w * bf2f(hv.y);
            acc.z += w * bf2f(hv.z);
            acc.w += w * bf2f(hv.w);
        }
    }
    ushort4 o;
    o.x = f2bf(acc.x); o.y = f2bf(acc.y); o.z = f2bf(acc.z); o.w = f2bf(acc.w);
    *((ushort4*)(pooled + (long long)node * DIM) + lane) = o;
}

// ---------------- fused MFMA MLP: z = (relu(A@W1+b1))@W2 + b2, + BN stats ----
// 512 threads, 128 rows/block; wt2 prefetched to regs (no mid-kernel global stall)
__global__ __launch_bounds__(512)
void fused_mlp(const u16* __restrict__ A, const u16* __restrict__ wt1,
               const u16* __restrict__ wt2, const float* __restrict__ b1,
               const float* __restrict__ b2, u16* __restrict__ Z,
               float* __restrict__ stats)
{
    __shared__ __align__(16) u16 wlds[128 * WT_LD];        // 34816 B
    __shared__ __align__(16) u16 hid[MLP_ROWS * WT_LD];    // 34816 B
    __shared__ float ssum[128];
    __shared__ float ssq[128];

    const int tid  = threadIdx.x;
    const int wave = tid >> 6;             // 0..7
    const int lane = tid & 63;
    const int l15  = lane & 15;
    const int lk   = lane >> 4;            // 0..3
    const int row0 = blockIdx.x * MLP_ROWS;
    const int wrow = wave * 16;            // wave's local base row

    // prefetch wt2 into registers (written to LDS after GEMM1)
    bf16x8 w2r[4];
    #pragma unroll
    for (int i = 0; i < 4; ++i) {
        int idx = tid + i * 512;           // 0..2047
        int r = idx >> 4, c = idx & 15;
        w2r[i] = *(const bf16x8*)(wt2 + r * 128 + c * 8);
    }
    // stage wt1 -> LDS
    #pragma unroll
    for (int i = 0; i < 4; ++i) {
        int idx = tid + i * 512;
        int r = idx >> 4, c = idx & 15;
        *(bf16x8*)&wlds[r * WT_LD + c * 8] = *(const bf16x8*)(wt1 + r * 128 + c * 8);
    }
    if (tid < 128) { ssum[tid] = 0.f; ssq[tid] = 0.f; }

    // A-fragments (GEMM1) straight from global
    bf16x8 afr[4];
    {
        int rg = row0 + wrow + l15;
        bool ok = rg < N_NODES;
        const u16* ap = A + (long long)rg * 128 + lk * 8;
        bf16x8 zero = {};
        #pragma unroll
        for (int kk = 0; kk < 4; ++kk)
            afr[kk] = ok ? *(const bf16x8*)(ap + kk * 32) : zero;
    }
    __syncthreads();                       // (1) wt1 staged

    // GEMM1 + bias + relu -> hid (LDS)
    #pragma unroll
    for (int c = 0; c < 8; ++c) {
        float bv = b1[c * 16 + l15];
        f32x4 acc = {bv, bv, bv, bv};
        #pragma unroll
        for (int kk = 0; kk < 4; ++kk) {
            bf16x8 w = *(bf16x8*)&wlds[(c * 16 + l15) * WT_LD + kk * 32 + lk * 8];
            acc = __builtin_amdgcn_mfma_f32_16x16x32_bf16(afr[kk], w, acc, 0, 0, 0);
        }
        #pragma unroll
        for (int i = 0; i < 4; ++i) {
            int rl = wrow + lk * 4 + i;
            hid[rl * WT_LD + c * 16 + l15] = f2bf(fmaxf(acc[i], 0.f));
        }
    }
    __syncthreads();                       // (2) hid complete, wlds free

    // stage wt2 from regs + read GEMM2 A-fragments from hid
    #pragma unroll
    for (int i = 0; i < 4; ++i) {
        int idx = tid + i * 512;
        int r = idx >> 4, c = idx & 15;
        *(bf16x8*)&wlds[r * WT_LD + c * 8] = w2r[i];
    }
    bf16x8 afr2[4];
    #pragma unroll
    for (int kk = 0; kk < 4; ++kk)
        afr2[kk] = *(bf16x8*)&hid[(wrow + l15) * WT_LD + kk * 32 + lk * 8];
    __syncthreads();                       // (3) wt2 staged, hid consumed -> reusable

    // GEMM2 + bias -> z (bf16 in hid region) + f32 stats
    #pragma unroll
    for (int c = 0; c < 8; ++c) {
        float bv = b2[c * 16 + l15];
        f32x4 acc = {bv, bv, bv, bv};
        #pragma unroll
        for (int kk = 0; kk < 4; ++kk) {
            bf16x8 w = *(bf16x8*)&wlds[(c * 16 + l15) * WT_LD + kk * 32 + lk * 8];
            acc = __builtin_amdgcn_mfma_f32_16x16x32_bf16(afr2[kk], w, acc, 0, 0, 0);
        }
        float s = 0.f, sq = 0.f;
        #pragma unroll
        for (int i = 0; i < 4; ++i) {
            int rl = wrow + lk * 4 + i;
            int rg = row0 + rl;
            float v = acc[i];
            if (rg < N_NODES) { s += v; sq += v * v; }
            hid[rl * WT_LD + c * 16 + l15] = (rg < N_NODES) ? f2bf(v) : (u16)0;
        }
        atomicAdd(&ssum[c * 16 + l15], s);
        atomicAdd(&ssq[c * 16 + l15], sq);
    }
    __syncthreads();                       // (4) z complete

    // cooperative vectorized z store
    #pragma unroll
    for (int j = 0; j < 4; ++j) {
        int idx = tid + j * 512;           // 0..2047
        int r = idx >> 4, c16 = idx & 15;
        int rg = row0 + r;
        if (rg < N_NODES) {
            bf16x8 v = *(bf16x8*)&hid[r * WT_LD + c16 * 8];
            *(bf16x8*)(Z + (long long)rg * 128 + c16 * 8) = v;
        }
    }
    if (tid < 128) {
        atomicAdd(&stats[tid], ssum[tid]);
        atomicAdd(&stats[128 + tid], ssq[tid]);
    }
}

// --------- BN finalize ---------------------------------------------------------
__global__ void bn_finalize(float* stats, const float* __restrict__ gamma,
                            const float* __restrict__ beta)
{
    int c = threadIdx.x;
    float mu  = stats[c] * (1.f / N_NODES);
    float var = stats[128 + c] * (1.f / N_NODES) - mu * mu;
    float sc  = gamma[c] * rsqrtf(var + BN_EPS);
    stats[c]       = sc;
    stats[128 + c] = beta[c] - mu * sc;
}

// --------- BN apply + relu: bf16 in, bf16 or f32 out -------------------------
template<bool BF16OUT>
__global__ __launch_bounds__(256)
void bn_apply(const u16* __restrict__ z, const float* __restrict__ stats,
              void* __restrict__ out)
{
    __shared__ float sc[128];
    __shared__ float sh[128];
    if (threadIdx.x < 128) {
        sc[threadIdx.x] = stats[threadIdx.x];
        sh[threadIdx.x] = stats[128 + threadIdx.x];
    }
    __syncthreads();
    const long long total = (long long)N_NODES * 16;
    long long stride = (long long)gridDim.x * blockDim.x;
    for (long long idx = blockIdx.x * 256LL + threadIdx.x; idx < total; idx += stride) {
        int c8 = (int)(idx & 15);
        bf16x8 v = *((const bf16x8*)z + idx);
        float o[8];
        #pragma unroll
        for (int q = 0; q < 8; ++q)
            o[q] = fmaxf(bf2f((u16)v[q]) * sc[c8 * 8 + q] + sh[c8 * 8 + q], 0.f);
        if (BF16OUT) {
            bf16x8 ob;
            #pragma unroll
            for (int q = 0; q < 8; ++q) ob[q] = (short)f2bf(o[q]);
            *((bf16x8*)out + idx) = ob;
        } else {
            float4 f0 = make_float4(o[0], o[1], o[2], o[3]);
            float4 f1 = make_float4(o[4], o[5], o[6], o[7]);
            ((float4*)out)[idx * 2]     = f0;
            ((float4*)out)[idx * 2 + 1] = f1;
        }
    }
}

// --------- graph pooling --------------------------------------------------------
__global__ __launch_bounds__(128)
void graph_pool(const float* __restrict__ h, const int* __restrict__ gid,
                const float* __restrict__ pw, float* __restrict__ out)
{
    int g = blockIdx.x;
    int lo = 0, hi = N_NODES;
    while (lo < hi) { int m = (lo + hi) >> 1; if (gid[m] < g) lo = m + 1; else hi = m; }
    int start = lo;
    hi = N_NODES;
    while (lo < hi) { int m = (lo + hi) >> 1; if (gid[m] < g + 1) lo = m + 1; else hi = m; }
    int end = lo;
    int c = threadIdx.x;
    float acc = 0.f;
    for (int n = start; n < end; ++n)
        acc += pw[n] * h[(long long)n * DIM + c];
    out[g * DIM + c] = acc;
}

extern "C" void kernel_launch(void* const* d_in, const int* in_sizes, int n_in,
                              void* d_out, int out_size, void* d_ws, size_t ws_size,
                              hipStream_t stream)
{
    const float* x    = (const float*)d_in[0];
    const int*   esrc = (const int*)d_in[1];
    const int*   edst = (const int*)d_in[2];
    const float* ew   = (const float*)d_in[3];
    const int*   gid  = (const int*)d_in[4];
    const float* pw   = (const float*)d_in[5];
    const float* W1   = (const float*)d_in[6];
    const float* b1   = (const float*)d_in[7];
    const float* W2   = (const float*)d_in[8];
    const float* b2   = (const float*)d_in[9];
    const float* gam  = (const float*)d_in[10];
    const float* bet  = (const float*)d_in[11];

    float* out_pool  = (float*)d_out;                      // [512,128]
    float* out_nodes = (float*)d_out + NUM_GRAPHS * DIM;   // [50000,128]

    // ---- workspace layout ----
    const size_t NF = (size_t)N_NODES * DIM;
    char* w = (char*)d_ws;
    uint2* ed2      = (uint2*)w;      w += (size_t)N_EDGES * sizeof(uint2);
    u32*   ed       = (u32*)w;        w += (size_t)N_EDGES * sizeof(u32);
    u16*   pooledBf = (u16*)w;        w += NF * sizeof(u16);
    u16*   zBf      = (u16*)w;        w += NF * sizeof(u16);
    u16*   hx       = (u16*)w;        w += NF * sizeof(u16);
    u16*   wt       = (u16*)w;        w += (size_t)4 * 128 * 128 * sizeof(u16);
    // contiguous zero region: stats0 | stats1 | bucketCnt
    float* stats0   = (float*)w;      w += 256 * sizeof(float);
    float* stats1   = (float*)w;      w += 256 * sizeof(float);
    int*   bucketCnt= (int*)w;        w += 256 * sizeof(int);
    int*   bucketStart=(int*)w;       w += 256 * sizeof(int);
    int*   gCursor  = (int*)w;        w += 256 * sizeof(int);
    int*   rowptr   = (int*)w;        w += (NBUCK * 256 + 64) * sizeof(int);

    const int mlpGrid    = (N_NODES + MLP_ROWS - 1) / MLP_ROWS;  // 391
    const int elemGrid   = 1024;
    const int gatherGrid = N_NODES / 8;                  // 6250
    const int partGrid   = (N_EDGES + TILE - 1) / TILE;  // 391

    // ---- CSR build via bucketed counting sort + converts ----
    fill_zero_kernel<<<1, 256, 0, stream>>>(stats0, 768);   // stats0|stats1|bucketCnt
    bucket_hist<<<512, 256, 0, stream>>>(edst, bucketCnt);
    cvt_bf16_kernel<<<1024, 256, 0, stream>>>(x, hx, (long long)(NF / 4));
    cvt_wt_kernel<<<256, 256, 0, stream>>>(W1, W2, wt);
    bucket_scan<<<1, 256, 0, stream>>>(bucketCnt, bucketStart, gCursor);
    partitionA<<<partGrid, 256, 0, stream>>>(esrc, edst, ew, gCursor, ed2);
    partitionB<<<NBUCK, 256, 0, stream>>>(ed2, bucketStart, rowptr, ed);

    // ---- layer 0 ----
    gather_spmm<<<gatherGrid, 256, 0, stream>>>(hx, ed, rowptr, pooledBf);
    fused_mlp<<<mlpGrid, 512, 0, stream>>>(pooledBf, wt, wt + 16384, b1, b2, zBf, stats0);
    bn_finalize<<<1, 128, 0, stream>>>(stats0, gam, bet);
    bn_apply<true><<<elemGrid, 256, 0, stream>>>(zBf, stats0, hx);        // h0 -> hx bf16

    // ---- layer 1 ----
    gather_spmm<<<gatherGrid, 256, 0, stream>>>(hx, ed, rowptr, pooledBf);
    fused_mlp<<<mlpGrid, 512, 0, stream>>>(pooledBf, wt + 32768, wt + 49152,
                                           b1 + DIM, b2 + DIM, zBf, stats1);
    bn_finalize<<<1, 128, 0, stream>>>(stats1, gam + DIM, bet + DIM);
    bn_apply<false><<<elemGrid, 256, 0, stream>>>(zBf, stats1, out_nodes); // h1 -> f32 out

    // ---- graph pooling ----
    graph_pool<<<NUM_GRAPHS, 128, 0, stream>>>(out_nodes, gid, pw, out_pool);
}

// Round 7
// 235.741 us; speedup vs baseline: 12.4650x; 1.1055x over previous
//
#include <hip/hip_runtime.h>

#define N_NODES    50000
#define N_EDGES    800000
#define DIM        128
#define NUM_GRAPHS 512
#define BN_EPS     1e-5f

#define NBUCK      196                // buckets of 256 nodes: dst >> 8
#define TILE       2048               // edges per partitionA block
#define WT_LD      136                // LDS row stride (elems): 272B = 17 x 16B -> conflict-free
#define MLP_ROWS   128                // rows per fused_mlp block (512 threads, 8 waves)
#define POOL_SPLIT 2                  // blocks per graph in graph_pool

typedef unsigned int u32;
typedef unsigned short u16;
typedef __attribute__((ext_vector_type(8))) short bf16x8;
typedef __attribute__((ext_vector_type(4))) float f32x4;

__device__ __forceinline__ u16 f2bf(float f) {
    u32 u = __float_as_uint(f);
    u += 0x7FFF + ((u >> 16) & 1);    // round-to-nearest-even
    return (u16)(u >> 16);
}
__device__ __forceinline__ float bf2f(u16 h) {
    return __uint_as_float((u32)h << 16);
}

// ---------------- zero fill (graph-capture safe) ------------------------------
__global__ __launch_bounds__(256)
void fill_zero_kernel(float* __restrict__ p, long long n)
{
    long long stride = (long long)gridDim.x * blockDim.x;
    for (long long i = blockIdx.x * 256LL + threadIdx.x; i < n; i += stride)
        p[i] = 0.f;
}

// ---------------- f32 -> bf16 convert (x table) -------------------------------
__global__ __launch_bounds__(256)
void cvt_bf16_kernel(const float* __restrict__ in, u16* __restrict__ out, long long n4)
{
    long long stride = (long long)gridDim.x * blockDim.x;
    for (long long i = blockIdx.x * 256LL + threadIdx.x; i < n4; i += stride) {
        float4 v = ((const float4*)in)[i];
        ushort4 o;
        o.x = f2bf(v.x); o.y = f2bf(v.y); o.z = f2bf(v.z); o.w = f2bf(v.w);
        ((ushort4*)out)[i] = o;
    }
}

// -------- convert W1,W2 (both layers) f32 -> bf16 TRANSPOSED  -----------------
__global__ __launch_bounds__(256)
void cvt_wt_kernel(const float* __restrict__ W1, const float* __restrict__ W2,
                   u16* __restrict__ wt)
{
    int idx = blockIdx.x * 256 + threadIdx.x;
    if (idx >= 4 * 128 * 128) return;
    int m = idx >> 14;
    int j = (idx >> 7) & 127;
    int k = idx & 127;
    const float* src = (m & 1) ? W2 : W1;
    src += (m >> 1) * 128 * 128;
    wt[idx] = f2bf(src[k * 128 + j]);
}

// ---------------- bucket histogram (LDS-staged) -------------------------------
__global__ __launch_bounds__(256)
void bucket_hist(const int* __restrict__ dst, int* __restrict__ bucketCnt)
{
    __shared__ int cnt[NBUCK];
    int t = threadIdx.x;
    if (t < NBUCK) cnt[t] = 0;
    __syncthreads();
    int stride = gridDim.x * blockDim.x;
    for (int e = blockIdx.x * 256 + t; e < N_EDGES; e += stride)
        atomicAdd(&cnt[dst[e] >> 8], 1);
    __syncthreads();
    if (t < NBUCK && cnt[t] > 0) atomicAdd(&bucketCnt[t], cnt[t]);
}

// ---------------- bucket scan: exclusive -> bucketStart, gCursor --------------
__global__ __launch_bounds__(256)
void bucket_scan(const int* __restrict__ bucketCnt, int* __restrict__ bucketStart,
                 int* __restrict__ gCursor)
{
    __shared__ int s[256];
    int t = threadIdx.x;
    int v = (t < NBUCK) ? bucketCnt[t] : 0;
    s[t] = v;
    __syncthreads();
    for (int off = 1; off < 256; off <<= 1) {
        int x = (t >= off) ? s[t - off] : 0;
        __syncthreads();
        s[t] += x;
        __syncthreads();
    }
    int excl = s[t] - v;
    if (t <= NBUCK) bucketStart[t] = excl;     // bucketStart[NBUCK] = total
    if (t < NBUCK)  gCursor[t] = excl;
}

// ------- partition A: tile-compacted scatter into bucket regions (8B recs) ----
__global__ __launch_bounds__(256)
void partitionA(const int* __restrict__ src, const int* __restrict__ dst,
                const float* __restrict__ ew, int* __restrict__ gCursor,
                uint2* __restrict__ ed2)
{
    __shared__ int cnt[NBUCK];
    __shared__ int off[NBUCK];
    __shared__ int gb[NBUCK];
    __shared__ u32 stg_sw[TILE];
    __shared__ u32 stg_d[TILE];
    __shared__ int scanb[256];

    const int t = threadIdx.x;
    const int base = blockIdx.x * TILE;
    const int tcnt = min(TILE, N_EDGES - base);

    if (t < NBUCK) cnt[t] = 0;
    __syncthreads();

    u32 swv[8], dv[8];
    int rk[8], bk[8];
    #pragma unroll
    for (int j = 0; j < 8; ++j) {
        int e = base + j * 256 + t;
        if (e < N_EDGES) {
            int d = dst[e];
            swv[j] = ((u32)f2bf(ew[e]) << 16) | (u32)src[e];
            dv[j]  = (u32)d;
            bk[j]  = d >> 8;
            rk[j]  = atomicAdd(&cnt[bk[j]], 1);
        } else bk[j] = -1;
    }
    __syncthreads();

    // exclusive scan of cnt -> off
    {
        int v = (t < NBUCK) ? cnt[t] : 0;
        scanb[t] = v;
        __syncthreads();
        for (int o = 1; o < 256; o <<= 1) {
            int x = (t >= o) ? scanb[t - o] : 0;
            __syncthreads();
            scanb[t] += x;
            __syncthreads();
        }
        if (t < NBUCK) off[t] = scanb[t] - v;
    }
    __syncthreads();

    #pragma unroll
    for (int j = 0; j < 8; ++j) {
        if (bk[j] >= 0) {
            int idx = off[bk[j]] + rk[j];
            stg_sw[idx] = swv[j];
            stg_d[idx]  = dv[j];
        }
    }
    if (t < NBUCK && cnt[t] > 0) gb[t] = atomicAdd(&gCursor[t], cnt[t]);
    __syncthreads();

    for (int j = t; j < tcnt; j += 256) {
        u32 d = stg_d[j];
        int b = (int)(d >> 8);
        int pos = gb[b] + (j - off[b]);
        ed2[pos] = make_uint2(stg_sw[j], d);
    }
}

// ------- partition B: exact CSR within bucket (windowed writes) + rowptr ------
__global__ __launch_bounds__(256)
void partitionB(const uint2* __restrict__ ed2, const int* __restrict__ bucketStart,
                int* __restrict__ rowptr, u32* __restrict__ ed)
{
    __shared__ int hist[256];
    __shared__ int sc[256];
    __shared__ int cur[256];

    const int b = blockIdx.x;
    const int t = threadIdx.x;
    const int s = bucketStart[b];
    const int n = bucketStart[b + 1] - s;

    hist[t] = 0;
    __syncthreads();
    for (int j = t; j < n; j += 256)
        atomicAdd(&hist[ed2[s + j].y & 255u], 1);
    __syncthreads();

    int v = hist[t];
    sc[t] = v;
    __syncthreads();
    for (int o = 1; o < 256; o <<= 1) {
        int x = (t >= o) ? sc[t - o] : 0;
        __syncthreads();
        sc[t] += x;
        __syncthreads();
    }
    int excl = sc[t] - v;
    rowptr[b * 256 + t] = s + excl;
    cur[t] = s + excl;
    __syncthreads();

    for (int j = t; j < n; j += 256) {
        uint2 r = ed2[s + j];
        int d = (int)(r.y & 255u);
        int p = atomicAdd(&cur[d], 1);
        ed[p] = r.x;
    }
}

// ------------- pull-gather SpMM from bf16 table, bf16 output ------------------
__global__ __launch_bounds__(256)
void gather_spmm(const u16* __restrict__ h, const u32* __restrict__ ed,
                 const int* __restrict__ rowptr, u16* __restrict__ pooled)
{
    int node = blockIdx.x * 8 + (threadIdx.x >> 5);   // 8 nodes per block
    int lane = threadIdx.x & 31;                      // 32 threads per node
    int beg = rowptr[node];
    int end = rowptr[node + 1];
    float4 acc = make_float4(0.f, 0.f, 0.f, 0.f);
    for (int base = beg; base < end; base += 32) {
        int e = base + lane;
        u32 sw = (e < end) ? ed[e] : 0u;
        int cnt = min(32, end - base);
        #pragma unroll 4
        for (int i = 0; i < cnt; ++i) {
            u32 rec = __shfl(sw, i, 32);
            int   s = (int)(rec & 0xFFFFu);
            float w = bf2f((u16)(rec >> 16));
            ushort4 hv = *((const ushort4*)(h + (long long)s * DIM) + lane);
            acc.x += w * bf2f(hv.x);
            acc.y += w * bf2f(hv.y);
            acc.z += w * bf2f(hv.z);
            acc.w += w * bf2f(hv.w);
        }
    }
    ushort4 o;
    o.x = f2bf(acc.x); o.y = f2bf(acc.y); o.z = f2bf(acc.z); o.w = f2bf(acc.w);
    *((ushort4*)(pooled + (long long)node * DIM) + lane) = o;
}

// ---------------- fused MFMA MLP: z = (relu(A@W1+b1))@W2 + b2, + BN stats ----
// 512 threads, 128 rows/block; wt2 prefetched to regs (no mid-kernel global stall)
__global__ __launch_bounds__(512)
void fused_mlp(const u16* __restrict__ A, const u16* __restrict__ wt1,
               const u16* __restrict__ wt2, const float* __restrict__ b1,
               const float* __restrict__ b2, u16* __restrict__ Z,
               float* __restrict__ stats)
{
    __shared__ __align__(16) u16 wlds[128 * WT_LD];        // 34816 B
    __shared__ __align__(16) u16 hid[MLP_ROWS * WT_LD];    // 34816 B
    __shared__ float ssum[128];
    __shared__ float ssq[128];

    const int tid  = threadIdx.x;
    const int wave = tid >> 6;             // 0..7
    const int lane = tid & 63;
    const int l15  = lane & 15;
    const int lk   = lane >> 4;            // 0..3
    const int row0 = blockIdx.x * MLP_ROWS;
    const int wrow = wave * 16;            // wave's local base row

    // prefetch wt2 into registers (written to LDS after GEMM1)
    bf16x8 w2r[4];
    #pragma unroll
    for (int i = 0; i < 4; ++i) {
        int idx = tid + i * 512;           // 0..2047
        int r = idx >> 4, c = idx & 15;
        w2r[i] = *(const bf16x8*)(wt2 + r * 128 + c * 8);
    }
    // stage wt1 -> LDS
    #pragma unroll
    for (int i = 0; i < 4; ++i) {
        int idx = tid + i * 512;
        int r = idx >> 4, c = idx & 15;
        *(bf16x8*)&wlds[r * WT_LD + c * 8] = *(const bf16x8*)(wt1 + r * 128 + c * 8);
    }
    if (tid < 128) { ssum[tid] = 0.f; ssq[tid] = 0.f; }

    // A-fragments (GEMM1) straight from global
    bf16x8 afr[4];
    {
        int rg = row0 + wrow + l15;
        bool ok = rg < N_NODES;
        const u16* ap = A + (long long)rg * 128 + lk * 8;
        bf16x8 zero = {};
        #pragma unroll
        for (int kk = 0; kk < 4; ++kk)
            afr[kk] = ok ? *(const bf16x8*)(ap + kk * 32) : zero;
    }
    __syncthreads();                       // (1) wt1 staged

    // GEMM1 + bias + relu -> hid (LDS)
    #pragma unroll
    for (int c = 0; c < 8; ++c) {
        float bv = b1[c * 16 + l15];
        f32x4 acc = {bv, bv, bv, bv};
        #pragma unroll
        for (int kk = 0; kk < 4; ++kk) {
            bf16x8 w = *(bf16x8*)&wlds[(c * 16 + l15) * WT_LD + kk * 32 + lk * 8];
            acc = __builtin_amdgcn_mfma_f32_16x16x32_bf16(afr[kk], w, acc, 0, 0, 0);
        }
        #pragma unroll
        for (int i = 0; i < 4; ++i) {
            int rl = wrow + lk * 4 + i;
            hid[rl * WT_LD + c * 16 + l15] = f2bf(fmaxf(acc[i], 0.f));
        }
    }
    __syncthreads();                       // (2) hid complete, wlds free

    // stage wt2 from regs + read GEMM2 A-fragments from hid
    #pragma unroll
    for (int i = 0; i < 4; ++i) {
        int idx = tid + i * 512;
        int r = idx >> 4, c = idx & 15;
        *(bf16x8*)&wlds[r * WT_LD + c * 8] = w2r[i];
    }
    bf16x8 afr2[4];
    #pragma unroll
    for (int kk = 0; kk < 4; ++kk)
        afr2[kk] = *(bf16x8*)&hid[(wrow + l15) * WT_LD + kk * 32 + lk * 8];
    __syncthreads();                       // (3) wt2 staged, hid consumed -> reusable

    // GEMM2 + bias -> z (bf16 in hid region) + f32 stats
    #pragma unroll
    for (int c = 0; c < 8; ++c) {
        float bv = b2[c * 16 + l15];
        f32x4 acc = {bv, bv, bv, bv};
        #pragma unroll
        for (int kk = 0; kk < 4; ++kk) {
            bf16x8 w = *(bf16x8*)&wlds[(c * 16 + l15) * WT_LD + kk * 32 + lk * 8];
            acc = __builtin_amdgcn_mfma_f32_16x16x32_bf16(afr2[kk], w, acc, 0, 0, 0);
        }
        float s = 0.f, sq = 0.f;
        #pragma unroll
        for (int i = 0; i < 4; ++i) {
            int rl = wrow + lk * 4 + i;
            int rg = row0 + rl;
            float v = acc[i];
            if (rg < N_NODES) { s += v; sq += v * v; }
            hid[rl * WT_LD + c * 16 + l15] = (rg < N_NODES) ? f2bf(v) : (u16)0;
        }
        atomicAdd(&ssum[c * 16 + l15], s);
        atomicAdd(&ssq[c * 16 + l15], sq);
    }
    __syncthreads();                       // (4) z complete

    // cooperative vectorized z store
    #pragma unroll
    for (int j = 0; j < 4; ++j) {
        int idx = tid + j * 512;           // 0..2047
        int r = idx >> 4, c16 = idx & 15;
        int rg = row0 + r;
        if (rg < N_NODES) {
            bf16x8 v = *(bf16x8*)&hid[r * WT_LD + c16 * 8];
            *(bf16x8*)(Z + (long long)rg * 128 + c16 * 8) = v;
        }
    }
    if (tid < 128) {
        atomicAdd(&stats[tid], ssum[tid]);
        atomicAdd(&stats[128 + tid], ssq[tid]);
    }
}

// --------- BN finalize ---------------------------------------------------------
__global__ void bn_finalize(float* stats, const float* __restrict__ gamma,
                            const float* __restrict__ beta)
{
    int c = threadIdx.x;
    float mu  = stats[c] * (1.f / N_NODES);
    float var = stats[128 + c] * (1.f / N_NODES) - mu * mu;
    float sc  = gamma[c] * rsqrtf(var + BN_EPS);
    stats[c]       = sc;
    stats[128 + c] = beta[c] - mu * sc;
}

// --------- BN apply + relu: bf16 in, bf16 or f32 out -------------------------
template<bool BF16OUT>
__global__ __launch_bounds__(256)
void bn_apply(const u16* __restrict__ z, const float* __restrict__ stats,
              void* __restrict__ out)
{
    __shared__ float sc[128];
    __shared__ float sh[128];
    if (threadIdx.x < 128) {
        sc[threadIdx.x] = stats[threadIdx.x];
        sh[threadIdx.x] = stats[128 + threadIdx.x];
    }
    __syncthreads();
    const long long total = (long long)N_NODES * 16;
    long long stride = (long long)gridDim.x * blockDim.x;
    for (long long idx = blockIdx.x * 256LL + threadIdx.x; idx < total; idx += stride) {
        int c8 = (int)(idx & 15);
        bf16x8 v = *((const bf16x8*)z + idx);
        float o[8];
        #pragma unroll
        for (int q = 0; q < 8; ++q)
            o[q] = fmaxf(bf2f((u16)v[q]) * sc[c8 * 8 + q] + sh[c8 * 8 + q], 0.f);
        if (BF16OUT) {
            bf16x8 ob;
            #pragma unroll
            for (int q = 0; q < 8; ++q) ob[q] = (short)f2bf(o[q]);
            *((bf16x8*)out + idx) = ob;
        } else {
            float4 f0 = make_float4(o[0], o[1], o[2], o[3]);
            float4 f1 = make_float4(o[4], o[5], o[6], o[7]);
            ((float4*)out)[idx * 2]     = f0;
            ((float4*)out)[idx * 2 + 1] = f1;
        }
    }
}

// --------- graph pooling: POOL_SPLIT blocks/graph, float4 lanes, LDS reduce ---
__global__ __launch_bounds__(256)
void graph_pool(const float* __restrict__ h, const int* __restrict__ gid,
                const float* __restrict__ pw, float* __restrict__ out)
{
    int g    = blockIdx.x >> 1;            // POOL_SPLIT = 2
    int half = blockIdx.x & 1;

    int lo = 0, hi = N_NODES;
    while (lo < hi) { int m = (lo + hi) >> 1; if (gid[m] < g) lo = m + 1; else hi = m; }
    int start = lo;
    hi = N_NODES;
    while (lo < hi) { int m = (lo + hi) >> 1; if (gid[m] < g + 1) lo = m + 1; else hi = m; }
    int end = lo;

    int len = end - start;
    int hlen = (len + 1) >> 1;
    int s = start + half * hlen;
    int e = min(end, s + hlen);

    const int t  = threadIdx.x;
    const int rg = t >> 5;                 // 0..7: row group
    const int c4 = t & 31;                 // float4 column
    float4 acc = make_float4(0.f, 0.f, 0.f, 0.f);
    for (int r = s + rg; r < e; r += 8) {
        float w = pw[r];
        float4 v = *((const float4*)(h + (long long)r * DIM) + c4);
        acc.x += w * v.x; acc.y += w * v.y;
        acc.z += w * v.z; acc.w += w * v.w;
    }

    __shared__ float4 sd[256];
    sd[t] = acc;
    __syncthreads();
    if (t < 32) {
        float4 tot = sd[t];
        #pragma unroll
        for (int i = 1; i < 8; ++i) {
            float4 v = sd[i * 32 + t];
            tot.x += v.x; tot.y += v.y; tot.z += v.z; tot.w += v.w;
        }
        float* op = out + g * DIM + t * 4;
        atomicAdd(op + 0, tot.x);
        atomicAdd(op + 1, tot.y);
        atomicAdd(op + 2, tot.z);
        atomicAdd(op + 3, tot.w);
    }
}

extern "C" void kernel_launch(void* const* d_in, const int* in_sizes, int n_in,
                              void* d_out, int out_size, void* d_ws, size_t ws_size,
                              hipStream_t stream)
{
    const float* x    = (const float*)d_in[0];
    const int*   esrc = (const int*)d_in[1];
    const int*   edst = (const int*)d_in[2];
    const float* ew   = (const float*)d_in[3];
    const int*   gid  = (const int*)d_in[4];
    const float* pw   = (const float*)d_in[5];
    const float* W1   = (const float*)d_in[6];
    const float* b1   = (const float*)d_in[7];
    const float* W2   = (const float*)d_in[8];
    const float* b2   = (const float*)d_in[9];
    const float* gam  = (const float*)d_in[10];
    const float* bet  = (const float*)d_in[11];

    float* out_pool  = (float*)d_out;                      // [512,128]
    float* out_nodes = (float*)d_out + NUM_GRAPHS * DIM;   // [50000,128]

    // ---- workspace layout ----
    const size_t NF = (size_t)N_NODES * DIM;
    char* w = (char*)d_ws;
    uint2* ed2      = (uint2*)w;      w += (size_t)N_EDGES * sizeof(uint2);
    u32*   ed       = (u32*)w;        w += (size_t)N_EDGES * sizeof(u32);
    u16*   pooledBf = (u16*)w;        w += NF * sizeof(u16);
    u16*   zBf      = (u16*)w;        w += NF * sizeof(u16);
    u16*   hx       = (u16*)w;        w += NF * sizeof(u16);
    u16*   wt       = (u16*)w;        w += (size_t)4 * 128 * 128 * sizeof(u16);
    // contiguous zero region: stats0 | stats1 | bucketCnt
    float* stats0   = (float*)w;      w += 256 * sizeof(float);
    float* stats1   = (float*)w;      w += 256 * sizeof(float);
    int*   bucketCnt= (int*)w;        w += 256 * sizeof(int);
    int*   bucketStart=(int*)w;       w += 256 * sizeof(int);
    int*   gCursor  = (int*)w;        w += 256 * sizeof(int);
    int*   rowptr   = (int*)w;        w += (NBUCK * 256 + 64) * sizeof(int);

    const int mlpGrid    = (N_NODES + MLP_ROWS - 1) / MLP_ROWS;  // 391
    const int elemGrid   = 1024;
    const int gatherGrid = N_NODES / 8;                  // 6250
    const int partGrid   = (N_EDGES + TILE - 1) / TILE;  // 391

    // ---- CSR build via bucketed counting sort + converts ----
    fill_zero_kernel<<<1, 256, 0, stream>>>(stats0, 768);   // stats0|stats1|bucketCnt
    fill_zero_kernel<<<64, 256, 0, stream>>>(out_pool, NUM_GRAPHS * DIM); // atomic target
    bucket_hist<<<512, 256, 0, stream>>>(edst, bucketCnt);
    cvt_bf16_kernel<<<1024, 256, 0, stream>>>(x, hx, (long long)(NF / 4));
    cvt_wt_kernel<<<256, 256, 0, stream>>>(W1, W2, wt);
    bucket_scan<<<1, 256, 0, stream>>>(bucketCnt, bucketStart, gCursor);
    partitionA<<<partGrid, 256, 0, stream>>>(esrc, edst, ew, gCursor, ed2);
    partitionB<<<NBUCK, 256, 0, stream>>>(ed2, bucketStart, rowptr, ed);

    // ---- layer 0 ----
    gather_spmm<<<gatherGrid, 256, 0, stream>>>(hx, ed, rowptr, pooledBf);
    fused_mlp<<<mlpGrid, 512, 0, stream>>>(pooledBf, wt, wt + 16384, b1, b2, zBf, stats0);
    bn_finalize<<<1, 128, 0, stream>>>(stats0, gam, bet);
    bn_apply<true><<<elemGrid, 256, 0, stream>>>(zBf, stats0, hx);        // h0 -> hx bf16

    // ---- layer 1 ----
    gather_spmm<<<gatherGrid, 256, 0, stream>>>(hx, ed, rowptr, pooledBf);
    fused_mlp<<<mlpGrid, 512, 0, stream>>>(pooledBf, wt + 32768, wt + 49152,
                                           b1 + DIM, b2 + DIM, zBf, stats1);
    bn_finalize<<<1, 128, 0, stream>>>(stats1, gam + DIM, bet + DIM);
    bn_apply<false><<<elemGrid, 256, 0, stream>>>(zBf, stats1, out_nodes); // h1 -> f32 out

    // ---- graph pooling (POOL_SPLIT blocks per graph, atomic combine) ----
    graph_pool<<<NUM_GRAPHS * POOL_SPLIT, 256, 0, stream>>>(out_nodes, gid, pw, out_pool);
}

// Round 8
// 224.247 us; speedup vs baseline: 13.1039x; 1.0513x over previous
//
#include <hip/hip_runtime.h>

#define N_NODES    50000
#define N_EDGES    800000
#define DIM        128
#define NUM_GRAPHS 512
#define BN_EPS     1e-5f

#define NBUCK      196                // buckets of 256 nodes: dst >> 8
#define TILE       2048               // edges per partitionA block
#define WT_LD      136                // LDS row stride (elems): 272B = 17 x 16B -> conflict-free
#define MLP_ROWS   128                // rows per fused_mlp block (512 threads, 8 waves)
#define POOL_SPLIT 2                  // blocks per graph in graph_pool

typedef unsigned int u32;
typedef unsigned short u16;
typedef __attribute__((ext_vector_type(8))) short bf16x8;
typedef __attribute__((ext_vector_type(4))) float f32x4;

__device__ __forceinline__ u16 f2bf(float f) {
    u32 u = __float_as_uint(f);
    u += 0x7FFF + ((u >> 16) & 1);    // round-to-nearest-even
    return (u16)(u >> 16);
}
__device__ __forceinline__ float bf2f(u16 h) {
    return __uint_as_float((u32)h << 16);
}

// ---------------- zero fill (graph-capture safe) ------------------------------
__global__ __launch_bounds__(256)
void fill_zero_kernel(float* __restrict__ p, long long n)
{
    long long stride = (long long)gridDim.x * blockDim.x;
    for (long long i = blockIdx.x * 256LL + threadIdx.x; i < n; i += stride)
        p[i] = 0.f;
}

// ---------------- f32 -> bf16 convert (x table) -------------------------------
__global__ __launch_bounds__(256)
void cvt_bf16_kernel(const float* __restrict__ in, u16* __restrict__ out, long long n4)
{
    long long stride = (long long)gridDim.x * blockDim.x;
    for (long long i = blockIdx.x * 256LL + threadIdx.x; i < n4; i += stride) {
        float4 v = ((const float4*)in)[i];
        ushort4 o;
        o.x = f2bf(v.x); o.y = f2bf(v.y); o.z = f2bf(v.z); o.w = f2bf(v.w);
        ((ushort4*)out)[i] = o;
    }
}

// -------- convert W1,W2 (both layers) f32 -> bf16 TRANSPOSED  -----------------
__global__ __launch_bounds__(256)
void cvt_wt_kernel(const float* __restrict__ W1, const float* __restrict__ W2,
                   u16* __restrict__ wt)
{
    int idx = blockIdx.x * 256 + threadIdx.x;
    if (idx >= 4 * 128 * 128) return;
    int m = idx >> 14;
    int j = (idx >> 7) & 127;
    int k = idx & 127;
    const float* src = (m & 1) ? W2 : W1;
    src += (m >> 1) * 128 * 128;
    wt[idx] = f2bf(src[k * 128 + j]);
}

// ---------------- bucket histogram (LDS-staged) -------------------------------
__global__ __launch_bounds__(256)
void bucket_hist(const int* __restrict__ dst, int* __restrict__ bucketCnt)
{
    __shared__ int cnt[NBUCK];
    int t = threadIdx.x;
    if (t < NBUCK) cnt[t] = 0;
    __syncthreads();
    int stride = gridDim.x * blockDim.x;
    for (int e = blockIdx.x * 256 + t; e < N_EDGES; e += stride)
        atomicAdd(&cnt[dst[e] >> 8], 1);
    __syncthreads();
    if (t < NBUCK && cnt[t] > 0) atomicAdd(&bucketCnt[t], cnt[t]);
}

// ---------------- bucket scan: exclusive -> bucketStart, gCursor --------------
__global__ __launch_bounds__(256)
void bucket_scan(const int* __restrict__ bucketCnt, int* __restrict__ bucketStart,
                 int* __restrict__ gCursor)
{
    __shared__ int s[256];
    int t = threadIdx.x;
    int v = (t < NBUCK) ? bucketCnt[t] : 0;
    s[t] = v;
    __syncthreads();
    for (int off = 1; off < 256; off <<= 1) {
        int x = (t >= off) ? s[t - off] : 0;
        __syncthreads();
        s[t] += x;
        __syncthreads();
    }
    int excl = s[t] - v;
    if (t <= NBUCK) bucketStart[t] = excl;     // bucketStart[NBUCK] = total
    if (t < NBUCK)  gCursor[t] = excl;
}

// ------- partition A: tile-compacted scatter into bucket regions (8B recs) ----
__global__ __launch_bounds__(256)
void partitionA(const int* __restrict__ src, const int* __restrict__ dst,
                const float* __restrict__ ew, int* __restrict__ gCursor,
                uint2* __restrict__ ed2)
{
    __shared__ int cnt[NBUCK];
    __shared__ int off[NBUCK];
    __shared__ int gb[NBUCK];
    __shared__ u32 stg_sw[TILE];
    __shared__ u32 stg_d[TILE];
    __shared__ int scanb[256];

    const int t = threadIdx.x;
    const int base = blockIdx.x * TILE;
    const int tcnt = min(TILE, N_EDGES - base);

    if (t < NBUCK) cnt[t] = 0;
    __syncthreads();

    u32 swv[8], dv[8];
    int rk[8], bk[8];
    #pragma unroll
    for (int j = 0; j < 8; ++j) {
        int e = base + j * 256 + t;
        if (e < N_EDGES) {
            int d = dst[e];
            swv[j] = ((u32)f2bf(ew[e]) << 16) | (u32)src[e];
            dv[j]  = (u32)d;
            bk[j]  = d >> 8;
            rk[j]  = atomicAdd(&cnt[bk[j]], 1);
        } else bk[j] = -1;
    }
    __syncthreads();

    // exclusive scan of cnt -> off
    {
        int v = (t < NBUCK) ? cnt[t] : 0;
        scanb[t] = v;
        __syncthreads();
        for (int o = 1; o < 256; o <<= 1) {
            int x = (t >= o) ? scanb[t - o] : 0;
            __syncthreads();
            scanb[t] += x;
            __syncthreads();
        }
        if (t < NBUCK) off[t] = scanb[t] - v;
    }
    __syncthreads();

    #pragma unroll
    for (int j = 0; j < 8; ++j) {
        if (bk[j] >= 0) {
            int idx = off[bk[j]] + rk[j];
            stg_sw[idx] = swv[j];
            stg_d[idx]  = dv[j];
        }
    }
    if (t < NBUCK && cnt[t] > 0) gb[t] = atomicAdd(&gCursor[t], cnt[t]);
    __syncthreads();

    for (int j = t; j < tcnt; j += 256) {
        u32 d = stg_d[j];
        int b = (int)(d >> 8);
        int pos = gb[b] + (j - off[b]);
        ed2[pos] = make_uint2(stg_sw[j], d);
    }
}

// ------- partition B: exact CSR within bucket (windowed writes) + rowptr ------
__global__ __launch_bounds__(256)
void partitionB(const uint2* __restrict__ ed2, const int* __restrict__ bucketStart,
                int* __restrict__ rowptr, u32* __restrict__ ed)
{
    __shared__ int hist[256];
    __shared__ int sc[256];
    __shared__ int cur[256];

    const int b = blockIdx.x;
    const int t = threadIdx.x;
    const int s = bucketStart[b];
    const int n = bucketStart[b + 1] - s;

    hist[t] = 0;
    __syncthreads();
    for (int j = t; j < n; j += 256)
        atomicAdd(&hist[ed2[s + j].y & 255u], 1);
    __syncthreads();

    int v = hist[t];
    sc[t] = v;
    __syncthreads();
    for (int o = 1; o < 256; o <<= 1) {
        int x = (t >= o) ? sc[t - o] : 0;
        __syncthreads();
        sc[t] += x;
        __syncthreads();
    }
    int excl = sc[t] - v;
    rowptr[b * 256 + t] = s + excl;
    cur[t] = s + excl;
    __syncthreads();

    for (int j = t; j < n; j += 256) {
        uint2 r = ed2[s + j];
        int d = (int)(r.y & 255u);
        int p = atomicAdd(&cur[d], 1);
        ed[p] = r.x;
    }
}

// ------------- pull-gather SpMM, optional fused BN+relu on the source --------
// BN=true: source h holds raw z (bf16); apply relu(z*sc+sh) per element,
// with sc/sh derived per-block from raw stats sums (no separate finalize).
template<bool BN>
__global__ __launch_bounds__(256)
void gather_spmm(const u16* __restrict__ h, const u32* __restrict__ ed,
                 const int* __restrict__ rowptr, u16* __restrict__ pooled,
                 const float* __restrict__ stats, const float* __restrict__ gamma,
                 const float* __restrict__ beta)
{
    __shared__ float scs[128];
    __shared__ float shs[128];
    if (BN) {
        if (threadIdx.x < 128) {
            int c = threadIdx.x;
            float mu  = stats[c] * (1.f / N_NODES);
            float var = stats[128 + c] * (1.f / N_NODES) - mu * mu;
            float s   = gamma[c] * rsqrtf(var + BN_EPS);
            scs[c] = s;
            shs[c] = beta[c] - mu * s;
        }
        __syncthreads();
    }

    int node = blockIdx.x * 8 + (threadIdx.x >> 5);   // 8 nodes per block
    int lane = threadIdx.x & 31;                      // 32 threads per node
    int beg = rowptr[node];
    int end = rowptr[node + 1];

    float4 sc4, sh4;
    if (BN) {
        sc4 = *(float4*)&scs[lane * 4];
        sh4 = *(float4*)&shs[lane * 4];
    }

    float4 acc = make_float4(0.f, 0.f, 0.f, 0.f);
    for (int base = beg; base < end; base += 32) {
        int e = base + lane;
        u32 sw = (e < end) ? ed[e] : 0u;
        int cnt = min(32, end - base);
        #pragma unroll 4
        for (int i = 0; i < cnt; ++i) {
            u32 rec = __shfl(sw, i, 32);
            int   s = (int)(rec & 0xFFFFu);
            float w = bf2f((u16)(rec >> 16));
            ushort4 hv = *((const ushort4*)(h + (long long)s * DIM) + lane);
            float4 v = make_float4(bf2f(hv.x), bf2f(hv.y), bf2f(hv.z), bf2f(hv.w));
            if (BN) {
                v.x = fmaxf(v.x * sc4.x + sh4.x, 0.f);
                v.y = fmaxf(v.y * sc4.y + sh4.y, 0.f);
                v.z = fmaxf(v.z * sc4.z + sh4.z, 0.f);
                v.w = fmaxf(v.w * sc4.w + sh4.w, 0.f);
            }
            acc.x += w * v.x; acc.y += w * v.y;
            acc.z += w * v.z; acc.w += w * v.w;
        }
    }
    ushort4 o;
    o.x = f2bf(acc.x); o.y = f2bf(acc.y); o.z = f2bf(acc.z); o.w = f2bf(acc.w);
    *((ushort4*)(pooled + (long long)node * DIM) + lane) = o;
}

// ---------------- fused MFMA MLP: z = (relu(A@W1+b1))@W2 + b2, + BN stats ----
// 512 threads, 128 rows/block; wt2 prefetched to regs (no mid-kernel global stall)
__global__ __launch_bounds__(512)
void fused_mlp(const u16* __restrict__ A, const u16* __restrict__ wt1,
               const u16* __restrict__ wt2, const float* __restrict__ b1,
               const float* __restrict__ b2, u16* __restrict__ Z,
               float* __restrict__ stats)
{
    __shared__ __align__(16) u16 wlds[128 * WT_LD];        // 34816 B
    __shared__ __align__(16) u16 hid[MLP_ROWS * WT_LD];    // 34816 B
    __shared__ float ssum[128];
    __shared__ float ssq[128];

    const int tid  = threadIdx.x;
    const int wave = tid >> 6;             // 0..7
    const int lane = tid & 63;
    const int l15  = lane & 15;
    const int lk   = lane >> 4;            // 0..3
    const int row0 = blockIdx.x * MLP_ROWS;
    const int wrow = wave * 16;            // wave's local base row

    // prefetch wt2 into registers (written to LDS after GEMM1)
    bf16x8 w2r[4];
    #pragma unroll
    for (int i = 0; i < 4; ++i) {
        int idx = tid + i * 512;           // 0..2047
        int r = idx >> 4, c = idx & 15;
        w2r[i] = *(const bf16x8*)(wt2 + r * 128 + c * 8);
    }
    // stage wt1 -> LDS
    #pragma unroll
    for (int i = 0; i < 4; ++i) {
        int idx = tid + i * 512;
        int r = idx >> 4, c = idx & 15;
        *(bf16x8*)&wlds[r * WT_LD + c * 8] = *(const bf16x8*)(wt1 + r * 128 + c * 8);
    }
    if (tid < 128) { ssum[tid] = 0.f; ssq[tid] = 0.f; }

    // A-fragments (GEMM1) straight from global
    bf16x8 afr[4];
    {
        int rg = row0 + wrow + l15;
        bool ok = rg < N_NODES;
        const u16* ap = A + (long long)rg * 128 + lk * 8;
        bf16x8 zero = {};
        #pragma unroll
        for (int kk = 0; kk < 4; ++kk)
            afr[kk] = ok ? *(const bf16x8*)(ap + kk * 32) : zero;
    }
    __syncthreads();                       // (1) wt1 staged

    // GEMM1 + bias + relu -> hid (LDS)
    #pragma unroll
    for (int c = 0; c < 8; ++c) {
        float bv = b1[c * 16 + l15];
        f32x4 acc = {bv, bv, bv, bv};
        #pragma unroll
        for (int kk = 0; kk < 4; ++kk) {
            bf16x8 w = *(bf16x8*)&wlds[(c * 16 + l15) * WT_LD + kk * 32 + lk * 8];
            acc = __builtin_amdgcn_mfma_f32_16x16x32_bf16(afr[kk], w, acc, 0, 0, 0);
        }
        #pragma unroll
        for (int i = 0; i < 4; ++i) {
            int rl = wrow + lk * 4 + i;
            hid[rl * WT_LD + c * 16 + l15] = f2bf(fmaxf(acc[i], 0.f));
        }
    }
    __syncthreads();                       // (2) hid complete, wlds free

    // stage wt2 from regs + read GEMM2 A-fragments from hid
    #pragma unroll
    for (int i = 0; i < 4; ++i) {
        int idx = tid + i * 512;
        int r = idx >> 4, c = idx & 15;
        *(bf16x8*)&wlds[r * WT_LD + c * 8] = w2r[i];
    }
    bf16x8 afr2[4];
    #pragma unroll
    for (int kk = 0; kk < 4; ++kk)
        afr2[kk] = *(bf16x8*)&hid[(wrow + l15) * WT_LD + kk * 32 + lk * 8];
    __syncthreads();                       // (3) wt2 staged, hid consumed -> reusable

    // GEMM2 + bias -> z (bf16 in hid region) + f32 stats
    #pragma unroll
    for (int c = 0; c < 8; ++c) {
        float bv = b2[c * 16 + l15];
        f32x4 acc = {bv, bv, bv, bv};
        #pragma unroll
        for (int kk = 0; kk < 4; ++kk) {
            bf16x8 w = *(bf16x8*)&wlds[(c * 16 + l15) * WT_LD + kk * 32 + lk * 8];
            acc = __builtin_amdgcn_mfma_f32_16x16x32_bf16(afr2[kk], w, acc, 0, 0, 0);
        }
        float s = 0.f, sq = 0.f;
        #pragma unroll
        for (int i = 0; i < 4; ++i) {
            int rl = wrow + lk * 4 + i;
            int rg = row0 + rl;
            float v = acc[i];
            if (rg < N_NODES) { s += v; sq += v * v; }
            hid[rl * WT_LD + c * 16 + l15] = (rg < N_NODES) ? f2bf(v) : (u16)0;
        }
        atomicAdd(&ssum[c * 16 + l15], s);
        atomicAdd(&ssq[c * 16 + l15], sq);
    }
    __syncthreads();                       // (4) z complete

    // cooperative vectorized z store
    #pragma unroll
    for (int j = 0; j < 4; ++j) {
        int idx = tid + j * 512;           // 0..2047
        int r = idx >> 4, c16 = idx & 15;
        int rg = row0 + r;
        if (rg < N_NODES) {
            bf16x8 v = *(bf16x8*)&hid[r * WT_LD + c16 * 8];
            *(bf16x8*)(Z + (long long)rg * 128 + c16 * 8) = v;
        }
    }
    if (tid < 128) {
        atomicAdd(&stats[tid], ssum[tid]);
        atomicAdd(&stats[128 + tid], ssq[tid]);
    }
}

// --------- graph pooling fused with BN+relu of layer-1 z ----------------------
// reads bf16 z, applies BN (derived from raw stats) + relu, writes f32
// out_nodes (each row exactly once) and accumulates out_pool via atomics.
__global__ __launch_bounds__(256)
void graph_pool_bn(const u16* __restrict__ z, const float* __restrict__ stats,
                   const float* __restrict__ gamma, const float* __restrict__ beta,
                   const int* __restrict__ gid, const float* __restrict__ pw,
                   float* __restrict__ out_nodes, float* __restrict__ out_pool)
{
    __shared__ float scs[128];
    __shared__ float shs[128];
    if (threadIdx.x < 128) {
        int c = threadIdx.x;
        float mu  = stats[c] * (1.f / N_NODES);
        float var = stats[128 + c] * (1.f / N_NODES) - mu * mu;
        float s   = gamma[c] * rsqrtf(var + BN_EPS);
        scs[c] = s;
        shs[c] = beta[c] - mu * s;
    }
    __syncthreads();

    int g    = blockIdx.x >> 1;            // POOL_SPLIT = 2
    int half = blockIdx.x & 1;

    int lo = 0, hi = N_NODES;
    while (lo < hi) { int m = (lo + hi) >> 1; if (gid[m] < g) lo = m + 1; else hi = m; }
    int start = lo;
    hi = N_NODES;
    while (lo < hi) { int m = (lo + hi) >> 1; if (gid[m] < g + 1) lo = m + 1; else hi = m; }
    int end = lo;

    int len = end - start;
    int hlen = (len + 1) >> 1;
    int s = start + half * hlen;
    int e = min(end, s + hlen);

    const int t  = threadIdx.x;
    const int rg = t >> 5;                 // 0..7: row group
    const int c4 = t & 31;                 // float4 column
    float4 sc4 = *(float4*)&scs[c4 * 4];
    float4 sh4 = *(float4*)&shs[c4 * 4];

    float4 acc = make_float4(0.f, 0.f, 0.f, 0.f);
    for (int r = s + rg; r < e; r += 8) {
        float w = pw[r];
        ushort4 hv = *((const ushort4*)(z + (long long)r * DIM) + c4);
        float4 v;
        v.x = fmaxf(bf2f(hv.x) * sc4.x + sh4.x, 0.f);
        v.y = fmaxf(bf2f(hv.y) * sc4.y + sh4.y, 0.f);
        v.z = fmaxf(bf2f(hv.z) * sc4.z + sh4.z, 0.f);
        v.w = fmaxf(bf2f(hv.w) * sc4.w + sh4.w, 0.f);
        *((float4*)(out_nodes + (long long)r * DIM) + c4) = v;
        acc.x += w * v.x; acc.y += w * v.y;
        acc.z += w * v.z; acc.w += w * v.w;
    }

    __shared__ float4 sd[256];
    sd[t] = acc;
    __syncthreads();
    if (t < 32) {
        float4 tot = sd[t];
        #pragma unroll
        for (int i = 1; i < 8; ++i) {
            float4 v = sd[i * 32 + t];
            tot.x += v.x; tot.y += v.y; tot.z += v.z; tot.w += v.w;
        }
        float* op = out_pool + g * DIM + t * 4;
        atomicAdd(op + 0, tot.x);
        atomicAdd(op + 1, tot.y);
        atomicAdd(op + 2, tot.z);
        atomicAdd(op + 3, tot.w);
    }
}

extern "C" void kernel_launch(void* const* d_in, const int* in_sizes, int n_in,
                              void* d_out, int out_size, void* d_ws, size_t ws_size,
                              hipStream_t stream)
{
    const float* x    = (const float*)d_in[0];
    const int*   esrc = (const int*)d_in[1];
    const int*   edst = (const int*)d_in[2];
    const float* ew   = (const float*)d_in[3];
    const int*   gid  = (const int*)d_in[4];
    const float* pw   = (const float*)d_in[5];
    const float* W1   = (const float*)d_in[6];
    const float* b1   = (const float*)d_in[7];
    const float* W2   = (const float*)d_in[8];
    const float* b2   = (const float*)d_in[9];
    const float* gam  = (const float*)d_in[10];
    const float* bet  = (const float*)d_in[11];

    float* out_pool  = (float*)d_out;                      // [512,128]
    float* out_nodes = (float*)d_out + NUM_GRAPHS * DIM;   // [50000,128]

    // ---- workspace layout ----
    const size_t NF = (size_t)N_NODES * DIM;
    char* w = (char*)d_ws;
    uint2* ed2      = (uint2*)w;      w += (size_t)N_EDGES * sizeof(uint2);
    u32*   ed       = (u32*)w;        w += (size_t)N_EDGES * sizeof(u32);
    u16*   pooledBf = (u16*)w;        w += NF * sizeof(u16);
    u16*   zBf      = (u16*)w;        w += NF * sizeof(u16);
    u16*   hx       = (u16*)w;        w += NF * sizeof(u16);
    u16*   wt       = (u16*)w;        w += (size_t)4 * 128 * 128 * sizeof(u16);
    // contiguous zero region: stats0 | stats1 | bucketCnt
    float* stats0   = (float*)w;      w += 256 * sizeof(float);
    float* stats1   = (float*)w;      w += 256 * sizeof(float);
    int*   bucketCnt= (int*)w;        w += 256 * sizeof(int);
    int*   bucketStart=(int*)w;       w += 256 * sizeof(int);
    int*   gCursor  = (int*)w;        w += 256 * sizeof(int);
    int*   rowptr   = (int*)w;        w += (NBUCK * 256 + 64) * sizeof(int);

    const int mlpGrid    = (N_NODES + MLP_ROWS - 1) / MLP_ROWS;  // 391
    const int gatherGrid = N_NODES / 8;                  // 6250
    const int partGrid   = (N_EDGES + TILE - 1) / TILE;  // 391

    // ---- CSR build via bucketed counting sort + converts ----
    fill_zero_kernel<<<1, 256, 0, stream>>>(stats0, 768);   // stats0|stats1|bucketCnt
    fill_zero_kernel<<<64, 256, 0, stream>>>(out_pool, NUM_GRAPHS * DIM); // atomic target
    bucket_hist<<<512, 256, 0, stream>>>(edst, bucketCnt);
    cvt_bf16_kernel<<<1024, 256, 0, stream>>>(x, hx, (long long)(NF / 4));
    cvt_wt_kernel<<<256, 256, 0, stream>>>(W1, W2, wt);
    bucket_scan<<<1, 256, 0, stream>>>(bucketCnt, bucketStart, gCursor);
    partitionA<<<partGrid, 256, 0, stream>>>(esrc, edst, ew, gCursor, ed2);
    partitionB<<<NBUCK, 256, 0, stream>>>(ed2, bucketStart, rowptr, ed);

    // ---- layer 0 ----
    gather_spmm<false><<<gatherGrid, 256, 0, stream>>>(hx, ed, rowptr, pooledBf,
                                                       nullptr, nullptr, nullptr);
    fused_mlp<<<mlpGrid, 512, 0, stream>>>(pooledBf, wt, wt + 16384, b1, b2, zBf, stats0);

    // ---- layer 1 (BN of layer-0 z fused into the gather) ----
    gather_spmm<true><<<gatherGrid, 256, 0, stream>>>(zBf, ed, rowptr, pooledBf,
                                                      stats0, gam, bet);
    fused_mlp<<<mlpGrid, 512, 0, stream>>>(pooledBf, wt + 32768, wt + 49152,
                                           b1 + DIM, b2 + DIM, zBf, stats1);

    // ---- BN(layer-1) + node output + graph pooling, all fused ----
    graph_pool_bn<<<NUM_GRAPHS * POOL_SPLIT, 256, 0, stream>>>(
        zBf, stats1, gam + DIM, bet + DIM, gid, pw, out_nodes, out_pool);
}

// Round 9
// 183.640 us; speedup vs baseline: 16.0014x; 1.2211x over previous
//
#include <hip/hip_runtime.h>

#define N_NODES    50000
#define N_EDGES    800000
#define DIM        128
#define NUM_GRAPHS 512
#define BN_EPS     1e-5f

#define NBUCK      196                // buckets of 256 nodes: dst >> 8
#define TILE       2048               // edges per partitionA block
#define MLP_ROWS   128                // rows per fused_mlp block (512 threads, 8 waves)
#define POOL_SPLIT 2                  // blocks per graph in graph_pool

typedef unsigned int u32;
typedef unsigned short u16;
typedef __attribute__((ext_vector_type(8))) short bf16x8;
typedef __attribute__((ext_vector_type(4))) float f32x4;

__device__ __forceinline__ u16 f2bf(float f) {
    u32 u = __float_as_uint(f);
    u += 0x7FFF + ((u >> 16) & 1);    // round-to-nearest-even
    return (u16)(u >> 16);
}
__device__ __forceinline__ float bf2f(u16 h) {
    return __uint_as_float((u32)h << 16);
}

// ---------------- zero fill (graph-capture safe) ------------------------------
__global__ __launch_bounds__(256)
void fill_zero_kernel(float* __restrict__ p, long long n)
{
    long long stride = (long long)gridDim.x * blockDim.x;
    for (long long i = blockIdx.x * 256LL + threadIdx.x; i < n; i += stride)
        p[i] = 0.f;
}

// ---------------- f32 -> bf16 convert (x table) -------------------------------
__global__ __launch_bounds__(256)
void cvt_bf16_kernel(const float* __restrict__ in, u16* __restrict__ out, long long n4)
{
    long long stride = (long long)gridDim.x * blockDim.x;
    for (long long i = blockIdx.x * 256LL + threadIdx.x; i < n4; i += stride) {
        float4 v = ((const float4*)in)[i];
        ushort4 o;
        o.x = f2bf(v.x); o.y = f2bf(v.y); o.z = f2bf(v.z); o.w = f2bf(v.w);
        ((ushort4*)out)[i] = o;
    }
}

// -------- convert W1,W2 f32 -> bf16 in MFMA FRAGMENT ORDER --------------------
// wt layout: [m][c][kk][lane][e]  (m = layer*2 + {0:W1,1:W2})
// element = W_m[k = kk*32 + (lane>>4)*8 + e][j = c*16 + (lane&15)]
__global__ __launch_bounds__(256)
void cvt_wt_kernel(const float* __restrict__ W1, const float* __restrict__ W2,
                   u16* __restrict__ wt)
{
    int idx = blockIdx.x * 256 + threadIdx.x;
    if (idx >= 4 * 128 * 128) return;
    int m    = idx >> 14;
    int f    = idx & 16383;
    int c    = (f >> 11) & 7;
    int kk   = (f >> 9) & 3;
    int lane = (f >> 3) & 63;
    int e    = f & 7;
    int k = kk * 32 + ((lane >> 4) << 3) + e;
    int j = c * 16 + (lane & 15);
    const float* src = (m & 1) ? W2 : W1;
    src += (m >> 1) * 128 * 128;
    wt[idx] = f2bf(src[k * 128 + j]);
}

// ---------------- bucket histogram (LDS-staged) -------------------------------
__global__ __launch_bounds__(256)
void bucket_hist(const int* __restrict__ dst, int* __restrict__ bucketCnt)
{
    __shared__ int cnt[NBUCK];
    int t = threadIdx.x;
    if (t < NBUCK) cnt[t] = 0;
    __syncthreads();
    int stride = gridDim.x * blockDim.x;
    for (int e = blockIdx.x * 256 + t; e < N_EDGES; e += stride)
        atomicAdd(&cnt[dst[e] >> 8], 1);
    __syncthreads();
    if (t < NBUCK && cnt[t] > 0) atomicAdd(&bucketCnt[t], cnt[t]);
}

// ---------------- bucket scan: exclusive -> bucketStart, gCursor --------------
__global__ __launch_bounds__(256)
void bucket_scan(const int* __restrict__ bucketCnt, int* __restrict__ bucketStart,
                 int* __restrict__ gCursor)
{
    __shared__ int s[256];
    int t = threadIdx.x;
    int v = (t < NBUCK) ? bucketCnt[t] : 0;
    s[t] = v;
    __syncthreads();
    for (int off = 1; off < 256; off <<= 1) {
        int x = (t >= off) ? s[t - off] : 0;
        __syncthreads();
        s[t] += x;
        __syncthreads();
    }
    int excl = s[t] - v;
    if (t <= NBUCK) bucketStart[t] = excl;     // bucketStart[NBUCK] = total
    if (t < NBUCK)  gCursor[t] = excl;
}

// ------- partition A: tile-compacted scatter into bucket regions (8B recs) ----
__global__ __launch_bounds__(256)
void partitionA(const int* __restrict__ src, const int* __restrict__ dst,
                const float* __restrict__ ew, int* __restrict__ gCursor,
                uint2* __restrict__ ed2)
{
    __shared__ int cnt[NBUCK];
    __shared__ int off[NBUCK];
    __shared__ int gb[NBUCK];
    __shared__ u32 stg_sw[TILE];
    __shared__ u32 stg_d[TILE];
    __shared__ int scanb[256];

    const int t = threadIdx.x;
    const int base = blockIdx.x * TILE;
    const int tcnt = min(TILE, N_EDGES - base);

    if (t < NBUCK) cnt[t] = 0;
    __syncthreads();

    u32 swv[8], dv[8];
    int rk[8], bk[8];
    #pragma unroll
    for (int j = 0; j < 8; ++j) {
        int e = base + j * 256 + t;
        if (e < N_EDGES) {
            int d = dst[e];
            swv[j] = ((u32)f2bf(ew[e]) << 16) | (u32)src[e];
            dv[j]  = (u32)d;
            bk[j]  = d >> 8;
            rk[j]  = atomicAdd(&cnt[bk[j]], 1);
        } else bk[j] = -1;
    }
    __syncthreads();

    // exclusive scan of cnt -> off
    {
        int v = (t < NBUCK) ? cnt[t] : 0;
        scanb[t] = v;
        __syncthreads();
        for (int o = 1; o < 256; o <<= 1) {
            int x = (t >= o) ? scanb[t - o] : 0;
            __syncthreads();
            scanb[t] += x;
            __syncthreads();
        }
        if (t < NBUCK) off[t] = scanb[t] - v;
    }
    __syncthreads();

    #pragma unroll
    for (int j = 0; j < 8; ++j) {
        if (bk[j] >= 0) {
            int idx = off[bk[j]] + rk[j];
            stg_sw[idx] = swv[j];
            stg_d[idx]  = dv[j];
        }
    }
    if (t < NBUCK && cnt[t] > 0) gb[t] = atomicAdd(&gCursor[t], cnt[t]);
    __syncthreads();

    for (int j = t; j < tcnt; j += 256) {
        u32 d = stg_d[j];
        int b = (int)(d >> 8);
        int pos = gb[b] + (j - off[b]);
        ed2[pos] = make_uint2(stg_sw[j], d);
    }
}

// ------- partition B: exact CSR within bucket (windowed writes) + rowptr ------
__global__ __launch_bounds__(256)
void partitionB(const uint2* __restrict__ ed2, const int* __restrict__ bucketStart,
                int* __restrict__ rowptr, u32* __restrict__ ed)
{
    __shared__ int hist[256];
    __shared__ int sc[256];
    __shared__ int cur[256];

    const int b = blockIdx.x;
    const int t = threadIdx.x;
    const int s = bucketStart[b];
    const int n = bucketStart[b + 1] - s;

    hist[t] = 0;
    __syncthreads();
    for (int j = t; j < n; j += 256)
        atomicAdd(&hist[ed2[s + j].y & 255u], 1);
    __syncthreads();

    int v = hist[t];
    sc[t] = v;
    __syncthreads();
    for (int o = 1; o < 256; o <<= 1) {
        int x = (t >= o) ? sc[t - o] : 0;
        __syncthreads();
        sc[t] += x;
        __syncthreads();
    }
    int excl = sc[t] - v;
    rowptr[b * 256 + t] = s + excl;
    cur[t] = s + excl;
    __syncthreads();

    for (int j = t; j < n; j += 256) {
        uint2 r = ed2[s + j];
        int d = (int)(r.y & 255u);
        int p = atomicAdd(&cur[d], 1);
        ed[p] = r.x;
    }
}

// ------------- pull-gather SpMM: 16 lanes/node, bf16x8 rows, opt. fused BN ---
template<bool BN>
__global__ __launch_bounds__(256)
void gather_spmm(const u16* __restrict__ h, const u32* __restrict__ ed,
                 const int* __restrict__ rowptr, u16* __restrict__ pooled,
                 const float* __restrict__ stats, const float* __restrict__ gamma,
                 const float* __restrict__ beta)
{
    __shared__ float scs[128];
    __shared__ float shs[128];
    if (BN) {
        if (threadIdx.x < 128) {
            int c = threadIdx.x;
            float mu  = stats[c] * (1.f / N_NODES);
            float var = stats[128 + c] * (1.f / N_NODES) - mu * mu;
            float s   = gamma[c] * rsqrtf(var + BN_EPS);
            scs[c] = s;
            shs[c] = beta[c] - mu * s;
        }
        __syncthreads();
    }

    int node = blockIdx.x * 16 + (threadIdx.x >> 4);  // 16 nodes per block
    int lane = threadIdx.x & 15;                      // 16 threads per node
    int beg = rowptr[node];
    int end = rowptr[node + 1];

    float sc8[8], sh8[8];
    if (BN) {
        #pragma unroll
        for (int q = 0; q < 8; ++q) {
            sc8[q] = scs[lane * 8 + q];
            sh8[q] = shs[lane * 8 + q];
        }
    }

    float acc[8];
    #pragma unroll
    for (int q = 0; q < 8; ++q) acc[q] = 0.f;

    for (int base = beg; base < end; base += 16) {
        int e = base + lane;
        u32 sw = (e < end) ? ed[e] : 0u;
        int cnt = min(16, end - base);
        #pragma unroll 4
        for (int i = 0; i < cnt; ++i) {
            u32 rec = __shfl(sw, i, 16);
            int   s = (int)(rec & 0xFFFFu);
            float w = bf2f((u16)(rec >> 16));
            bf16x8 hv = *((const bf16x8*)(h + (long long)s * DIM) + lane);
            #pragma unroll
            for (int q = 0; q < 8; ++q) {
                float v = bf2f((u16)hv[q]);
                if (BN) v = fmaxf(v * sc8[q] + sh8[q], 0.f);
                acc[q] += w * v;
            }
        }
    }
    bf16x8 o;
    #pragma unroll
    for (int q = 0; q < 8; ++q) o[q] = (short)f2bf(acc[q]);
    *((bf16x8*)(pooled + (long long)node * DIM) + lane) = o;
}

// ---------------- fused MFMA MLP v3 ------------------------------------------
// wtL: both weight matrices of this layer in fragment order (32768 u16).
// LDS: wfrag 64KB (wt1 [0,16384) u16, wt2 [16384,32768)); after GEMM1 the wt1
// region is overlaid with swizzled bf16 hid (wave-local), then with z staging.
// 3 barriers total; all hid/z LDS traffic is wave-local.
__global__ __launch_bounds__(512)
void fused_mlp(const u16* __restrict__ A, const u16* __restrict__ wtL,
               const float* __restrict__ b1, const float* __restrict__ b2,
               u16* __restrict__ Z, float* __restrict__ stats)
{
    __shared__ __align__(16) u16 wfrag[32768];   // 64 KB
    __shared__ float ssum[128];
    __shared__ float ssq[128];

    const int tid  = threadIdx.x;
    const int lane = tid & 63;
    const int wave = tid >> 6;             // 0..7
    const int l15  = lane & 15;
    const int lk   = lane >> 4;            // 0..3
    const int row0 = blockIdx.x * MLP_ROWS;
    const int wrow = wave * 16;

    // stage BOTH weight matrices, coalesced fragment order (4096 x 16B)
    #pragma unroll
    for (int i = 0; i < 8; ++i) {
        int idx = tid + i * 512;
        *(bf16x8*)&wfrag[idx * 8] = *(const bf16x8*)(wtL + idx * 8);
    }
    if (tid < 128) { ssum[tid] = 0.f; ssq[tid] = 0.f; }

    // A-fragments from global
    bf16x8 afr[4];
    {
        int rg = row0 + wrow + l15;
        bool ok = rg < N_NODES;
        const u16* ap = A + (long long)rg * 128 + lk * 8;
        bf16x8 zero = {};
        #pragma unroll
        for (int kk = 0; kk < 4; ++kk)
            afr[kk] = ok ? *(const bf16x8*)(ap + kk * 32) : zero;
    }
    __syncthreads();                       // (1) weights staged

    // GEMM1: all 8 c-blocks accumulated in registers
    f32x4 acc1[8];
    #pragma unroll
    for (int c = 0; c < 8; ++c) {
        float bv = b1[c * 16 + l15];
        f32x4 a = {bv, bv, bv, bv};
        #pragma unroll
        for (int kk = 0; kk < 4; ++kk) {
            bf16x8 w = *(bf16x8*)&wfrag[((c * 4 + kk) * 64 + lane) * 8];
            a = __builtin_amdgcn_mfma_f32_16x16x32_bf16(afr[kk], w, a, 0, 0, 0);
        }
        acc1[c] = a;
    }
    __syncthreads();                       // (2) wt1 reads done -> region reusable

    // hid (relu, bf16) into overlay region, XOR-swizzled; wave-local
    #pragma unroll
    for (int c = 0; c < 8; ++c) {
        #pragma unroll
        for (int i = 0; i < 4; ++i) {
            int row = wrow + lk * 4 + i;
            int col = c * 16 + l15;
            wfrag[row * 128 + (col ^ ((row & 15) << 3))] = f2bf(fmaxf(acc1[c][i], 0.f));
        }
    }

    // GEMM2 A-fragments from own wave's hid rows (wave-local, no barrier)
    bf16x8 afr2[4];
    {
        int row = wrow + l15;
        #pragma unroll
        for (int kk = 0; kk < 4; ++kk)
            afr2[kk] = *(bf16x8*)&wfrag[row * 128 + ((kk * 32 + lk * 8) ^ ((row & 15) << 3))];
    }

    // GEMM2 + stats; z (bf16) back into own hid rows for coalesced store
    #pragma unroll
    for (int c = 0; c < 8; ++c) {
        float bv = b2[c * 16 + l15];
        f32x4 a = {bv, bv, bv, bv};
        #pragma unroll
        for (int kk = 0; kk < 4; ++kk) {
            bf16x8 w = *(bf16x8*)&wfrag[16384 + ((c * 4 + kk) * 64 + lane) * 8];
            a = __builtin_amdgcn_mfma_f32_16x16x32_bf16(afr2[kk], w, a, 0, 0, 0);
        }
        float s = 0.f, sq = 0.f;
        #pragma unroll
        for (int i = 0; i < 4; ++i) {
            int row = wrow + lk * 4 + i;
            int rg  = row0 + row;
            float v = a[i];
            bool ok = rg < N_NODES;
            if (ok) { s += v; sq += v * v; }
            wfrag[row * 128 + ((c * 16 + l15) ^ ((row & 15) << 3))] = ok ? f2bf(v) : (u16)0;
        }
        // combine the 4 lk-lanes holding the same column, then one LDS atomic
        s  += __shfl_xor(s, 16);  s  += __shfl_xor(s, 32);
        sq += __shfl_xor(sq, 16); sq += __shfl_xor(sq, 32);
        if (lk == 0) {
            atomicAdd(&ssum[c * 16 + l15], s);
            atomicAdd(&ssq[c * 16 + l15], sq);
        }
    }

    // wave-local coalesced z store (own 16 rows, 4 x b128 per lane)
    #pragma unroll
    for (int j = 0; j < 4; ++j) {
        int chunk = j * 64 + lane;         // 0..255
        int rl  = chunk >> 4;              // 0..15
        int c8  = chunk & 15;
        int row = wrow + rl;
        int rg  = row0 + row;
        if (rg < N_NODES) {
            bf16x8 v = *(bf16x8*)&wfrag[row * 128 + ((c8 * 8) ^ ((row & 15) << 3))];
            *(bf16x8*)(Z + (long long)rg * 128 + c8 * 8) = v;
        }
    }
    __syncthreads();                       // (3) all LDS stat adds done
    if (tid < 128) {
        atomicAdd(&stats[tid], ssum[tid]);
        atomicAdd(&stats[128 + tid], ssq[tid]);
    }
}

// --------- graph pooling fused with BN+relu of layer-1 z ----------------------
__global__ __launch_bounds__(256)
void graph_pool_bn(const u16* __restrict__ z, const float* __restrict__ stats,
                   const float* __restrict__ gamma, const float* __restrict__ beta,
                   const int* __restrict__ gid, const float* __restrict__ pw,
                   float* __restrict__ out_nodes, float* __restrict__ out_pool)
{
    __shared__ float scs[128];
    __shared__ float shs[128];
    if (threadIdx.x < 128) {
        int c = threadIdx.x;
        float mu  = stats[c] * (1.f / N_NODES);
        float var = stats[128 + c] * (1.f / N_NODES) - mu * mu;
        float s   = gamma[c] * rsqrtf(var + BN_EPS);
        scs[c] = s;
        shs[c] = beta[c] - mu * s;
    }
    __syncthreads();

    int g    = blockIdx.x >> 1;            // POOL_SPLIT = 2
    int half = blockIdx.x & 1;

    int lo = 0, hi = N_NODES;
    while (lo < hi) { int m = (lo + hi) >> 1; if (gid[m] < g) lo = m + 1; else hi = m; }
    int start = lo;
    hi = N_NODES;
    while (lo < hi) { int m = (lo + hi) >> 1; if (gid[m] < g + 1) lo = m + 1; else hi = m; }
    int end = lo;

    int len = end - start;
    int hlen = (len + 1) >> 1;
    int s = start + half * hlen;
    int e = min(end, s + hlen);

    const int t  = threadIdx.x;
    const int rg = t >> 5;                 // 0..7: row group
    const int c4 = t & 31;                 // float4 column
    float4 sc4 = *(float4*)&scs[c4 * 4];
    float4 sh4 = *(float4*)&shs[c4 * 4];

    float4 acc = make_float4(0.f, 0.f, 0.f, 0.f);
    for (int r = s + rg; r < e; r += 8) {
        float w = pw[r];
        ushort4 hv = *((const ushort4*)(z + (long long)r * DIM) + c4);
        float4 v;
        v.x = fmaxf(bf2f(hv.x) * sc4.x + sh4.x, 0.f);
        v.y = fmaxf(bf2f(hv.y) * sc4.y + sh4.y, 0.f);
        v.z = fmaxf(bf2f(hv.z) * sc4.z + sh4.z, 0.f);
        v.w = fmaxf(bf2f(hv.w) * sc4.w + sh4.w, 0.f);
        *((float4*)(out_nodes + (long long)r * DIM) + c4) = v;
        acc.x += w * v.x; acc.y += w * v.y;
        acc.z += w * v.z; acc.w += w * v.w;
    }

    __shared__ float4 sd[256];
    sd[t] = acc;
    __syncthreads();
    if (t < 32) {
        float4 tot = sd[t];
        #pragma unroll
        for (int i = 1; i < 8; ++i) {
            float4 v = sd[i * 32 + t];
            tot.x += v.x; tot.y += v.y; tot.z += v.z; tot.w += v.w;
        }
        float* op = out_pool + g * DIM + t * 4;
        atomicAdd(op + 0, tot.x);
        atomicAdd(op + 1, tot.y);
        atomicAdd(op + 2, tot.z);
        atomicAdd(op + 3, tot.w);
    }
}

extern "C" void kernel_launch(void* const* d_in, const int* in_sizes, int n_in,
                              void* d_out, int out_size, void* d_ws, size_t ws_size,
                              hipStream_t stream)
{
    const float* x    = (const float*)d_in[0];
    const int*   esrc = (const int*)d_in[1];
    const int*   edst = (const int*)d_in[2];
    const float* ew   = (const float*)d_in[3];
    const int*   gid  = (const int*)d_in[4];
    const float* pw   = (const float*)d_in[5];
    const float* W1   = (const float*)d_in[6];
    const float* b1   = (const float*)d_in[7];
    const float* W2   = (const float*)d_in[8];
    const float* b2   = (const float*)d_in[9];
    const float* gam  = (const float*)d_in[10];
    const float* bet  = (const float*)d_in[11];

    float* out_pool  = (float*)d_out;                      // [512,128]
    float* out_nodes = (float*)d_out + NUM_GRAPHS * DIM;   // [50000,128]

    // ---- workspace layout ----
    const size_t NF = (size_t)N_NODES * DIM;
    char* w = (char*)d_ws;
    uint2* ed2      = (uint2*)w;      w += (size_t)N_EDGES * sizeof(uint2);
    u32*   ed       = (u32*)w;        w += (size_t)N_EDGES * sizeof(u32);
    u16*   pooledBf = (u16*)w;        w += NF * sizeof(u16);
    u16*   zBf      = (u16*)w;        w += NF * sizeof(u16);
    u16*   hx       = (u16*)w;        w += NF * sizeof(u16);
    u16*   wt       = (u16*)w;        w += (size_t)4 * 128 * 128 * sizeof(u16);
    // contiguous zero region: stats0 | stats1 | bucketCnt
    float* stats0   = (float*)w;      w += 256 * sizeof(float);
    float* stats1   = (float*)w;      w += 256 * sizeof(float);
    int*   bucketCnt= (int*)w;        w += 256 * sizeof(int);
    int*   bucketStart=(int*)w;       w += 256 * sizeof(int);
    int*   gCursor  = (int*)w;        w += 256 * sizeof(int);
    int*   rowptr   = (int*)w;        w += (NBUCK * 256 + 64) * sizeof(int);

    const int mlpGrid    = (N_NODES + MLP_ROWS - 1) / MLP_ROWS;  // 391
    const int gatherGrid = (N_NODES + 15) / 16;          // 3125
    const int partGrid   = (N_EDGES + TILE - 1) / TILE;  // 391

    // ---- CSR build via bucketed counting sort + converts ----
    fill_zero_kernel<<<1, 256, 0, stream>>>(stats0, 768);   // stats0|stats1|bucketCnt
    fill_zero_kernel<<<64, 256, 0, stream>>>(out_pool, NUM_GRAPHS * DIM); // atomic target
    bucket_hist<<<512, 256, 0, stream>>>(edst, bucketCnt);
    cvt_bf16_kernel<<<1024, 256, 0, stream>>>(x, hx, (long long)(NF / 4));
    cvt_wt_kernel<<<256, 256, 0, stream>>>(W1, W2, wt);
    bucket_scan<<<1, 256, 0, stream>>>(bucketCnt, bucketStart, gCursor);
    partitionA<<<partGrid, 256, 0, stream>>>(esrc, edst, ew, gCursor, ed2);
    partitionB<<<NBUCK, 256, 0, stream>>>(ed2, bucketStart, rowptr, ed);

    // ---- layer 0 ----
    gather_spmm<false><<<gatherGrid, 256, 0, stream>>>(hx, ed, rowptr, pooledBf,
                                                       nullptr, nullptr, nullptr);
    fused_mlp<<<mlpGrid, 512, 0, stream>>>(pooledBf, wt, b1, b2, zBf, stats0);

    // ---- layer 1 (BN of layer-0 z fused into the gather) ----
    gather_spmm<true><<<gatherGrid, 256, 0, stream>>>(zBf, ed, rowptr, pooledBf,
                                                      stats0, gam, bet);
    fused_mlp<<<mlpGrid, 512, 0, stream>>>(pooledBf, wt + 32768,
                                           b1 + DIM, b2 + DIM, zBf, stats1);

    // ---- BN(layer-1) + node output + graph pooling, all fused ----
    graph_pool_bn<<<NUM_GRAPHS * POOL_SPLIT, 256, 0, stream>>>(
        zBf, stats1, gam + DIM, bet + DIM, gid, pw, out_nodes, out_pool);
}

// Round 10
// 173.541 us; speedup vs baseline: 16.9326x; 1.0582x over previous
//
#include <hip/hip_runtime.h>

#define N_NODES    50000
#define N_EDGES    800000
#define DIM        128
#define NUM_GRAPHS 512
#define BN_EPS     1e-5f

#define NBUCK      196                // buckets of 256 nodes: dst >> 8
#define TILE       4096               // edges per partitionA block (512 threads)
#define MLP_ROWS   128                // rows per fused_mlp block (512 threads, 8 waves)
#define POOL_SPLIT 4                  // blocks per graph in graph_pool

typedef unsigned int u32;
typedef unsigned short u16;
typedef __attribute__((ext_vector_type(8))) short bf16x8;
typedef __attribute__((ext_vector_type(4))) float f32x4;

__device__ __forceinline__ u16 f2bf(float f) {
    u32 u = __float_as_uint(f);
    u += 0x7FFF + ((u >> 16) & 1);    // round-to-nearest-even
    return (u16)(u >> 16);
}
__device__ __forceinline__ float bf2f(u16 h) {
    return __uint_as_float((u32)h << 16);
}

// ------------- merged zero fill: stats/bucketCnt region + out_pool -----------
__global__ __launch_bounds__(256)
void fill_zero2_kernel(float* __restrict__ p1, int n1, float* __restrict__ p2, int n2)
{
    int stride = gridDim.x * blockDim.x;
    for (int i = blockIdx.x * 256 + threadIdx.x; i < n1 + n2; i += stride) {
        if (i < n1) p1[i] = 0.f;
        else        p2[i - n1] = 0.f;
    }
}

// ---------------- f32 -> bf16 convert (x table) -------------------------------
__global__ __launch_bounds__(256)
void cvt_bf16_kernel(const float* __restrict__ in, u16* __restrict__ out, long long n4)
{
    long long stride = (long long)gridDim.x * blockDim.x;
    for (long long i = blockIdx.x * 256LL + threadIdx.x; i < n4; i += stride) {
        float4 v = ((const float4*)in)[i];
        ushort4 o;
        o.x = f2bf(v.x); o.y = f2bf(v.y); o.z = f2bf(v.z); o.w = f2bf(v.w);
        ((ushort4*)out)[i] = o;
    }
}

// -------- convert W1,W2 f32 -> bf16 in MFMA FRAGMENT ORDER --------------------
__global__ __launch_bounds__(256)
void cvt_wt_kernel(const float* __restrict__ W1, const float* __restrict__ W2,
                   u16* __restrict__ wt)
{
    int idx = blockIdx.x * 256 + threadIdx.x;
    if (idx >= 4 * 128 * 128) return;
    int m    = idx >> 14;
    int f    = idx & 16383;
    int c    = (f >> 11) & 7;
    int kk   = (f >> 9) & 3;
    int lane = (f >> 3) & 63;
    int e    = f & 7;
    int k = kk * 32 + ((lane >> 4) << 3) + e;
    int j = c * 16 + (lane & 15);
    const float* src = (m & 1) ? W2 : W1;
    src += (m >> 1) * 128 * 128;
    wt[idx] = f2bf(src[k * 128 + j]);
}

// ---------------- bucket histogram (LDS-staged, int4 loads) -------------------
__global__ __launch_bounds__(256)
void bucket_hist(const int* __restrict__ dst, int* __restrict__ bucketCnt)
{
    __shared__ int cnt[NBUCK];
    int t = threadIdx.x;
    if (t < NBUCK) cnt[t] = 0;
    __syncthreads();
    int stride = gridDim.x * blockDim.x;
    for (int i = blockIdx.x * 256 + t; i < N_EDGES / 4; i += stride) {
        int4 d = ((const int4*)dst)[i];
        atomicAdd(&cnt[d.x >> 8], 1);
        atomicAdd(&cnt[d.y >> 8], 1);
        atomicAdd(&cnt[d.z >> 8], 1);
        atomicAdd(&cnt[d.w >> 8], 1);
    }
    __syncthreads();
    if (t < NBUCK && cnt[t] > 0) atomicAdd(&bucketCnt[t], cnt[t]);
}

// ---------------- bucket scan: exclusive -> bucketStart, gCursor --------------
__global__ __launch_bounds__(256)
void bucket_scan(const int* __restrict__ bucketCnt, int* __restrict__ bucketStart,
                 int* __restrict__ gCursor)
{
    __shared__ int s[256];
    int t = threadIdx.x;
    int v = (t < NBUCK) ? bucketCnt[t] : 0;
    s[t] = v;
    __syncthreads();
    for (int off = 1; off < 256; off <<= 1) {
        int x = (t >= off) ? s[t - off] : 0;
        __syncthreads();
        s[t] += x;
        __syncthreads();
    }
    int excl = s[t] - v;
    if (t <= NBUCK) bucketStart[t] = excl;     // bucketStart[NBUCK] = total
    if (t < NBUCK)  gCursor[t] = excl;
}

// ------- partition A: 512 thr, tile-compacted scatter into bucket regions ----
__global__ __launch_bounds__(512)
void partitionA(const int* __restrict__ src, const int* __restrict__ dst,
                const float* __restrict__ ew, int* __restrict__ gCursor,
                uint2* __restrict__ ed2)
{
    __shared__ int cnt[NBUCK];
    __shared__ int off[NBUCK];
    __shared__ int gb[NBUCK];
    __shared__ u32 stg_sw[TILE];
    __shared__ u32 stg_d[TILE];
    __shared__ int scanb[256];

    const int t = threadIdx.x;
    const int base = blockIdx.x * TILE;
    const int tcnt = min(TILE, N_EDGES - base);

    if (t < NBUCK) cnt[t] = 0;
    __syncthreads();

    u32 swv[8], dv[8];
    int rk[8], bk[8];
    #pragma unroll
    for (int j = 0; j < 8; ++j) {
        int e = base + j * 512 + t;
        if (e < N_EDGES) {
            int d = dst[e];
            swv[j] = ((u32)f2bf(ew[e]) << 16) | (u32)src[e];
            dv[j]  = (u32)d;
            bk[j]  = d >> 8;
            rk[j]  = atomicAdd(&cnt[bk[j]], 1);
        } else bk[j] = -1;
    }
    __syncthreads();

    // exclusive scan of cnt -> off (first 256 threads)
    {
        int v = (t < NBUCK) ? cnt[t] : 0;
        if (t < 256) scanb[t] = v;
        __syncthreads();
        for (int o = 1; o < 256; o <<= 1) {
            int x = (t < 256 && t >= o) ? scanb[t - o] : 0;
            __syncthreads();
            if (t < 256) scanb[t] += x;
            __syncthreads();
        }
        if (t < NBUCK) off[t] = scanb[t] - v;
    }
    __syncthreads();

    #pragma unroll
    for (int j = 0; j < 8; ++j) {
        if (bk[j] >= 0) {
            int idx = off[bk[j]] + rk[j];
            stg_sw[idx] = swv[j];
            stg_d[idx]  = dv[j];
        }
    }
    if (t < NBUCK && cnt[t] > 0) gb[t] = atomicAdd(&gCursor[t], cnt[t]);
    __syncthreads();

    for (int j = t; j < tcnt; j += 512) {
        u32 d = stg_d[j];
        int b = (int)(d >> 8);
        int pos = gb[b] + (j - off[b]);
        ed2[pos] = make_uint2(stg_sw[j], d);
    }
}

// ------- partition B: exact CSR within bucket (windowed writes) + rowptr ------
__global__ __launch_bounds__(256)
void partitionB(const uint2* __restrict__ ed2, const int* __restrict__ bucketStart,
                int* __restrict__ rowptr, u32* __restrict__ ed)
{
    __shared__ int hist[256];
    __shared__ int sc[256];
    __shared__ int cur[256];

    const int b = blockIdx.x;
    const int t = threadIdx.x;
    const int s = bucketStart[b];
    const int n = bucketStart[b + 1] - s;

    hist[t] = 0;
    __syncthreads();
    for (int j = t; j < n; j += 256)
        atomicAdd(&hist[ed2[s + j].y & 255u], 1);
    __syncthreads();

    int v = hist[t];
    sc[t] = v;
    __syncthreads();
    for (int o = 1; o < 256; o <<= 1) {
        int x = (t >= o) ? sc[t - o] : 0;
        __syncthreads();
        sc[t] += x;
        __syncthreads();
    }
    int excl = sc[t] - v;
    rowptr[b * 256 + t] = s + excl;
    cur[t] = s + excl;
    __syncthreads();

    for (int j = t; j < n; j += 256) {
        uint2 r = ed2[s + j];
        int d = (int)(r.y & 255u);
        int p = atomicAdd(&cur[d], 1);
        ed[p] = r.x;
    }
}

// ------------- pull-gather SpMM: 16 lanes/node, prefetched edge batches ------
template<bool BN>
__global__ __launch_bounds__(256)
void gather_spmm(const u16* __restrict__ h, const u32* __restrict__ ed,
                 const int* __restrict__ rowptr, u16* __restrict__ pooled,
                 const float* __restrict__ stats, const float* __restrict__ gamma,
                 const float* __restrict__ beta)
{
    __shared__ float scs[128];
    __shared__ float shs[128];
    if (BN) {
        if (threadIdx.x < 128) {
            int c = threadIdx.x;
            float mu  = stats[c] * (1.f / N_NODES);
            float var = stats[128 + c] * (1.f / N_NODES) - mu * mu;
            float s   = gamma[c] * rsqrtf(var + BN_EPS);
            scs[c] = s;
            shs[c] = beta[c] - mu * s;
        }
        __syncthreads();
    }

    int node = blockIdx.x * 16 + (threadIdx.x >> 4);  // 16 nodes per block
    int lane = threadIdx.x & 15;                      // 16 threads per node
    int beg = rowptr[node];
    int end = rowptr[node + 1];

    float sc8[8], sh8[8];
    if (BN) {
        #pragma unroll
        for (int q = 0; q < 8; ++q) {
            sc8[q] = scs[lane * 8 + q];
            sh8[q] = shs[lane * 8 + q];
        }
    }

    float acc[8];
    #pragma unroll
    for (int q = 0; q < 8; ++q) acc[q] = 0.f;

    u32 sw_cur = (beg + lane < end) ? ed[beg + lane] : 0u;
    for (int base = beg; base < end; base += 16) {
        // prefetch next batch while this one is consumed
        u32 sw_next = (base + 16 + lane < end) ? ed[base + 16 + lane] : 0u;
        int cnt = min(16, end - base);
        #pragma unroll 4
        for (int i = 0; i < cnt; ++i) {
            u32 rec = __shfl(sw_cur, i, 16);
            long long s = (long long)(rec & 0xFFFFu);
            float w = bf2f((u16)(rec >> 16));
            bf16x8 hv = *((const bf16x8*)(h + (s << 7)) + lane);
            #pragma unroll
            for (int q = 0; q < 8; ++q) {
                float v = bf2f((u16)hv[q]);
                if (BN) v = fmaxf(v * sc8[q] + sh8[q], 0.f);
                acc[q] += w * v;
            }
        }
        sw_cur = sw_next;
    }
    bf16x8 o;
    #pragma unroll
    for (int q = 0; q < 8; ++q) o[q] = (short)f2bf(acc[q]);
    *((bf16x8*)(pooled + ((long long)node << 7)) + lane) = o;
}

// ---------------- fused MFMA MLP v3 (3 barriers, fragment-order weights) ------
__global__ __launch_bounds__(512)
void fused_mlp(const u16* __restrict__ A, const u16* __restrict__ wtL,
               const float* __restrict__ b1, const float* __restrict__ b2,
               u16* __restrict__ Z, float* __restrict__ stats)
{
    __shared__ __align__(16) u16 wfrag[32768];   // 64 KB
    __shared__ float ssum[128];
    __shared__ float ssq[128];

    const int tid  = threadIdx.x;
    const int lane = tid & 63;
    const int wave = tid >> 6;             // 0..7
    const int l15  = lane & 15;
    const int lk   = lane >> 4;            // 0..3
    const int row0 = blockIdx.x * MLP_ROWS;
    const int wrow = wave * 16;

    // stage BOTH weight matrices, coalesced fragment order (4096 x 16B)
    #pragma unroll
    for (int i = 0; i < 8; ++i) {
        int idx = tid + i * 512;
        *(bf16x8*)&wfrag[idx * 8] = *(const bf16x8*)(wtL + idx * 8);
    }
    if (tid < 128) { ssum[tid] = 0.f; ssq[tid] = 0.f; }

    // A-fragments from global
    bf16x8 afr[4];
    {
        int rg = row0 + wrow + l15;
        bool ok = rg < N_NODES;
        const u16* ap = A + (long long)rg * 128 + lk * 8;
        bf16x8 zero = {};
        #pragma unroll
        for (int kk = 0; kk < 4; ++kk)
            afr[kk] = ok ? *(const bf16x8*)(ap + kk * 32) : zero;
    }
    __syncthreads();                       // (1) weights staged

    // GEMM1: all 8 c-blocks accumulated in registers
    f32x4 acc1[8];
    #pragma unroll
    for (int c = 0; c < 8; ++c) {
        float bv = b1[c * 16 + l15];
        f32x4 a = {bv, bv, bv, bv};
        #pragma unroll
        for (int kk = 0; kk < 4; ++kk) {
            bf16x8 w = *(bf16x8*)&wfrag[((c * 4 + kk) * 64 + lane) * 8];
            a = __builtin_amdgcn_mfma_f32_16x16x32_bf16(afr[kk], w, a, 0, 0, 0);
        }
        acc1[c] = a;
    }
    __syncthreads();                       // (2) wt1 reads done -> region reusable

    // hid (relu, bf16) into overlay region, XOR-swizzled; wave-local
    #pragma unroll
    for (int c = 0; c < 8; ++c) {
        #pragma unroll
        for (int i = 0; i < 4; ++i) {
            int row = wrow + lk * 4 + i;
            int col = c * 16 + l15;
            wfrag[row * 128 + (col ^ ((row & 15) << 3))] = f2bf(fmaxf(acc1[c][i], 0.f));
        }
    }

    // GEMM2 A-fragments from own wave's hid rows (wave-local, no barrier)
    bf16x8 afr2[4];
    {
        int row = wrow + l15;
        #pragma unroll
        for (int kk = 0; kk < 4; ++kk)
            afr2[kk] = *(bf16x8*)&wfrag[row * 128 + ((kk * 32 + lk * 8) ^ ((row & 15) << 3))];
    }

    // GEMM2 + stats; z (bf16) back into own hid rows for coalesced store
    #pragma unroll
    for (int c = 0; c < 8; ++c) {
        float bv = b2[c * 16 + l15];
        f32x4 a = {bv, bv, bv, bv};
        #pragma unroll
        for (int kk = 0; kk < 4; ++kk) {
            bf16x8 w = *(bf16x8*)&wfrag[16384 + ((c * 4 + kk) * 64 + lane) * 8];
            a = __builtin_amdgcn_mfma_f32_16x16x32_bf16(afr2[kk], w, a, 0, 0, 0);
        }
        float s = 0.f, sq = 0.f;
        #pragma unroll
        for (int i = 0; i < 4; ++i) {
            int row = wrow + lk * 4 + i;
            int rg  = row0 + row;
            float v = a[i];
            bool ok = rg < N_NODES;
            if (ok) { s += v; sq += v * v; }
            wfrag[row * 128 + ((c * 16 + l15) ^ ((row & 15) << 3))] = ok ? f2bf(v) : (u16)0;
        }
        // combine the 4 lk-lanes holding the same column, then one LDS atomic
        s  += __shfl_xor(s, 16);  s  += __shfl_xor(s, 32);
        sq += __shfl_xor(sq, 16); sq += __shfl_xor(sq, 32);
        if (lk == 0) {
            atomicAdd(&ssum[c * 16 + l15], s);
            atomicAdd(&ssq[c * 16 + l15], sq);
        }
    }

    // wave-local coalesced z store (own 16 rows, 4 x b128 per lane)
    #pragma unroll
    for (int j = 0; j < 4; ++j) {
        int chunk = j * 64 + lane;         // 0..255
        int rl  = chunk >> 4;              // 0..15
        int c8  = chunk & 15;
        int row = wrow + rl;
        int rg  = row0 + row;
        if (rg < N_NODES) {
            bf16x8 v = *(bf16x8*)&wfrag[row * 128 + ((c8 * 8) ^ ((row & 15) << 3))];
            *(bf16x8*)(Z + (long long)rg * 128 + c8 * 8) = v;
        }
    }
    __syncthreads();                       // (3) all LDS stat adds done
    if (tid < 128) {
        atomicAdd(&stats[tid], ssum[tid]);
        atomicAdd(&stats[128 + tid], ssq[tid]);
    }
}

// --------- graph pooling fused with BN+relu of layer-1 z ----------------------
__global__ __launch_bounds__(256)
void graph_pool_bn(const u16* __restrict__ z, const float* __restrict__ stats,
                   const float* __restrict__ gamma, const float* __restrict__ beta,
                   const int* __restrict__ gid, const float* __restrict__ pw,
                   float* __restrict__ out_nodes, float* __restrict__ out_pool)
{
    __shared__ float scs[128];
    __shared__ float shs[128];
    if (threadIdx.x < 128) {
        int c = threadIdx.x;
        float mu  = stats[c] * (1.f / N_NODES);
        float var = stats[128 + c] * (1.f / N_NODES) - mu * mu;
        float s   = gamma[c] * rsqrtf(var + BN_EPS);
        scs[c] = s;
        shs[c] = beta[c] - mu * s;
    }
    __syncthreads();

    int g    = blockIdx.x >> 2;            // POOL_SPLIT = 4
    int part = blockIdx.x & 3;

    int lo = 0, hi = N_NODES;
    while (lo < hi) { int m = (lo + hi) >> 1; if (gid[m] < g) lo = m + 1; else hi = m; }
    int start = lo;
    hi = N_NODES;
    while (lo < hi) { int m = (lo + hi) >> 1; if (gid[m] < g + 1) lo = m + 1; else hi = m; }
    int end = lo;

    int len  = end - start;
    int qlen = (len + 3) >> 2;
    int s = start + part * qlen;
    int e = min(end, s + qlen);

    const int t  = threadIdx.x;
    const int rg = t >> 5;                 // 0..7: row group
    const int c4 = t & 31;                 // float4 column
    float4 sc4 = *(float4*)&scs[c4 * 4];
    float4 sh4 = *(float4*)&shs[c4 * 4];

    float4 acc = make_float4(0.f, 0.f, 0.f, 0.f);
    for (int r = s + rg; r < e; r += 8) {
        float w = pw[r];
        ushort4 hv = *((const ushort4*)(z + (long long)r * DIM) + c4);
        float4 v;
        v.x = fmaxf(bf2f(hv.x) * sc4.x + sh4.x, 0.f);
        v.y = fmaxf(bf2f(hv.y) * sc4.y + sh4.y, 0.f);
        v.z = fmaxf(bf2f(hv.z) * sc4.z + sh4.z, 0.f);
        v.w = fmaxf(bf2f(hv.w) * sc4.w + sh4.w, 0.f);
        *((float4*)(out_nodes + (long long)r * DIM) + c4) = v;
        acc.x += w * v.x; acc.y += w * v.y;
        acc.z += w * v.z; acc.w += w * v.w;
    }

    __shared__ float4 sd[256];
    sd[t] = acc;
    __syncthreads();
    if (t < 32) {
        float4 tot = sd[t];
        #pragma unroll
        for (int i = 1; i < 8; ++i) {
            float4 v = sd[i * 32 + t];
            tot.x += v.x; tot.y += v.y; tot.z += v.z; tot.w += v.w;
        }
        float* op = out_pool + g * DIM + t * 4;
        atomicAdd(op + 0, tot.x);
        atomicAdd(op + 1, tot.y);
        atomicAdd(op + 2, tot.z);
        atomicAdd(op + 3, tot.w);
    }
}

extern "C" void kernel_launch(void* const* d_in, const int* in_sizes, int n_in,
                              void* d_out, int out_size, void* d_ws, size_t ws_size,
                              hipStream_t stream)
{
    const float* x    = (const float*)d_in[0];
    const int*   esrc = (const int*)d_in[1];
    const int*   edst = (const int*)d_in[2];
    const float* ew   = (const float*)d_in[3];
    const int*   gid  = (const int*)d_in[4];
    const float* pw   = (const float*)d_in[5];
    const float* W1   = (const float*)d_in[6];
    const float* b1   = (const float*)d_in[7];
    const float* W2   = (const float*)d_in[8];
    const float* b2   = (const float*)d_in[9];
    const float* gam  = (const float*)d_in[10];
    const float* bet  = (const float*)d_in[11];

    float* out_pool  = (float*)d_out;                      // [512,128]
    float* out_nodes = (float*)d_out + NUM_GRAPHS * DIM;   // [50000,128]

    // ---- workspace layout ----
    const size_t NF = (size_t)N_NODES * DIM;
    char* w = (char*)d_ws;
    uint2* ed2      = (uint2*)w;      w += (size_t)N_EDGES * sizeof(uint2);
    u32*   ed       = (u32*)w;        w += (size_t)N_EDGES * sizeof(u32);
    u16*   pooledBf = (u16*)w;        w += NF * sizeof(u16);
    u16*   zBf      = (u16*)w;        w += NF * sizeof(u16);
    u16*   hx       = (u16*)w;        w += NF * sizeof(u16);
    u16*   wt       = (u16*)w;        w += (size_t)4 * 128 * 128 * sizeof(u16);
    // contiguous zero region: stats0 | stats1 | bucketCnt
    float* stats0   = (float*)w;      w += 256 * sizeof(float);
    float* stats1   = (float*)w;      w += 256 * sizeof(float);
    int*   bucketCnt= (int*)w;        w += 256 * sizeof(int);
    int*   bucketStart=(int*)w;       w += 256 * sizeof(int);
    int*   gCursor  = (int*)w;        w += 256 * sizeof(int);
    int*   rowptr   = (int*)w;        w += (NBUCK * 256 + 64) * sizeof(int);

    const int mlpGrid    = (N_NODES + MLP_ROWS - 1) / MLP_ROWS;  // 391
    const int gatherGrid = (N_NODES + 15) / 16;          // 3125
    const int partGrid   = (N_EDGES + TILE - 1) / TILE;  // 196

    // ---- CSR build via bucketed counting sort + converts ----
    fill_zero2_kernel<<<64, 256, 0, stream>>>(stats0, 768,
                                              out_pool, NUM_GRAPHS * DIM);
    bucket_hist<<<256, 256, 0, stream>>>(edst, bucketCnt);
    cvt_bf16_kernel<<<1024, 256, 0, stream>>>(x, hx, (long long)(NF / 4));
    cvt_wt_kernel<<<256, 256, 0, stream>>>(W1, W2, wt);
    bucket_scan<<<1, 256, 0, stream>>>(bucketCnt, bucketStart, gCursor);
    partitionA<<<partGrid, 512, 0, stream>>>(esrc, edst, ew, gCursor, ed2);
    partitionB<<<NBUCK, 256, 0, stream>>>(ed2, bucketStart, rowptr, ed);

    // ---- layer 0 ----
    gather_spmm<false><<<gatherGrid, 256, 0, stream>>>(hx, ed, rowptr, pooledBf,
                                                       nullptr, nullptr, nullptr);
    fused_mlp<<<mlpGrid, 512, 0, stream>>>(pooledBf, wt, b1, b2, zBf, stats0);

    // ---- layer 1 (BN of layer-0 z fused into the gather) ----
    gather_spmm<true><<<gatherGrid, 256, 0, stream>>>(zBf, ed, rowptr, pooledBf,
                                                      stats0, gam, bet);
    fused_mlp<<<mlpGrid, 512, 0, stream>>>(pooledBf, wt + 32768,
                                           b1 + DIM, b2 + DIM, zBf, stats1);

    // ---- BN(layer-1) + node output + graph pooling, all fused ----
    graph_pool_bn<<<NUM_GRAPHS * POOL_SPLIT, 256, 0, stream>>>(
        zBf, stats1, gam + DIM, bet + DIM, gid, pw, out_nodes, out_pool);
}